// Round 1
// baseline (4602.016 us; speedup 1.0000x reference)
//
#include <hip/hip_runtime.h>
#include <math.h>

#define HS 1024      // hidden size
#define IS 2048      // intermediate size
#define NHEAD 16
#define HDIM 64
#define NEXP 8
#define BATCH 2
#define SEQ 1024
#define NTOK (BATCH*SEQ)   // 2048 tokens

// ---------------------------------------------------------------- rmsnorm
__global__ void rmsnorm_kernel(const float* __restrict__ x, const float* __restrict__ w,
                               float* __restrict__ out) {
    int t = blockIdx.x;
    int tid = threadIdx.x;
    const float* row = x + (size_t)t * HS;
    float ss = 0.f;
    for (int i = tid; i < HS; i += 256) { float v = row[i]; ss += v * v; }
    for (int off = 32; off > 0; off >>= 1) ss += __shfl_down(ss, off);
    __shared__ float red[4];
    if ((tid & 63) == 0) red[tid >> 6] = ss;
    __syncthreads();
    float tot = red[0] + red[1] + red[2] + red[3];
    float rr = rsqrtf(tot / (float)HS + 1e-6f);
    float* orow = out + (size_t)t * HS;
    for (int i = tid; i < HS; i += 256) orow[i] = w[i] * row[i] * rr;
}

// ---------------------------------------------------------------- generic fp32 GEMM
// C[M,N] = A[M,K] @ B[K,N], all row-major. M,N multiples of 64; K multiple of 16.
__global__ __launch_bounds__(256) void gemm_f32(const float* __restrict__ A,
                                                const float* __restrict__ B,
                                                float* __restrict__ C,
                                                int M, int N, int K) {
    __shared__ float As[16][64];
    __shared__ float Bs[16][64];
    int bm = blockIdx.y * 64;
    int bn = blockIdx.x * 64;
    int t = threadIdx.x;
    int tx = t & 15, ty = t >> 4;
    float acc[4][4] = {};
    for (int k0 = 0; k0 < K; k0 += 16) {
        {
            int m  = t >> 2;
            int kq = (t & 3) << 2;
            float4 av = *(const float4*)(A + (size_t)(bm + m) * K + k0 + kq);
            As[kq + 0][m] = av.x; As[kq + 1][m] = av.y;
            As[kq + 2][m] = av.z; As[kq + 3][m] = av.w;
        }
        {
            int kk = t >> 4;
            int nq = (t & 15) << 2;
            float4 bv = *(const float4*)(B + (size_t)(k0 + kk) * N + bn + nq);
            Bs[kk][nq + 0] = bv.x; Bs[kk][nq + 1] = bv.y;
            Bs[kk][nq + 2] = bv.z; Bs[kk][nq + 3] = bv.w;
        }
        __syncthreads();
        #pragma unroll
        for (int kk = 0; kk < 16; kk++) {
            float a[4], b[4];
            #pragma unroll
            for (int i = 0; i < 4; i++) a[i] = As[kk][ty * 4 + i];
            #pragma unroll
            for (int j = 0; j < 4; j++) b[j] = Bs[kk][tx * 4 + j];
            #pragma unroll
            for (int i = 0; i < 4; i++)
                #pragma unroll
                for (int j = 0; j < 4; j++) acc[i][j] += a[i] * b[j];
        }
        __syncthreads();
    }
    #pragma unroll
    for (int i = 0; i < 4; i++) {
        float4 cv = make_float4(acc[i][0], acc[i][1], acc[i][2], acc[i][3]);
        *(float4*)(C + (size_t)(bm + ty * 4 + i) * N + bn + tx * 4) = cv;
    }
}

// ---------------------------------------------------------------- RoPE (in-place on q and k)
// faithful to ref: pair j uses freqs row elements (2j, 2j+1) as (cr, ci)
__global__ void rope_kernel(float* __restrict__ q, float* __restrict__ k,
                            const float* __restrict__ fc) {
    int idx = blockIdx.x * 256 + threadIdx.x;   // NTOK*NHEAD*32 = 1048576 exactly
    int j    = idx & 31;
    int rest = idx >> 5;
    int h = rest & (NHEAD - 1);
    int t = rest >> 4;
    int s = t & (SEQ - 1);
    float cr = fc[s * HDIM + 2 * j];
    float ci = fc[s * HDIM + 2 * j + 1];
    size_t base = (size_t)t * HS + h * HDIM + 2 * j;
    float a = q[base], b = q[base + 1];
    q[base]     = a * cr - b * ci;
    q[base + 1] = a * ci + b * cr;
    a = k[base]; b = k[base + 1];
    k[base]     = a * cr - b * ci;
    k[base + 1] = a * ci + b * cr;
}

// ---------------------------------------------------------------- attention (one block per (b,h,qrow))
__global__ __launch_bounds__(256) void attn_kernel(const float* __restrict__ q,
                                                   const float* __restrict__ k,
                                                   const float* __restrict__ v,
                                                   float* __restrict__ ctx) {
    int qi = blockIdx.x;
    int h  = blockIdx.y;
    int b  = blockIdx.z;
    int tid = threadIdx.x;
    __shared__ float qv[HDIM];
    __shared__ float sc[SEQ];
    __shared__ float red[4];
    __shared__ float oacc[4][HDIM];

    const size_t hoff = (size_t)h * HDIM;
    const float* qrow = q + (size_t)(b * SEQ + qi) * HS + hoff;
    if (tid < HDIM) qv[tid] = qrow[tid];
    __syncthreads();

    float lmax = -1e30f;
    for (int kk = tid; kk < SEQ; kk += 256) {
        float val = -1e9f;
        if (kk <= qi) {
            const float* krow = k + (size_t)(b * SEQ + kk) * HS + hoff;
            float dt = 0.f;
            #pragma unroll
            for (int x = 0; x < HDIM; x++) dt += qv[x] * krow[x];
            val = dt * 0.125f;   // 1/sqrt(64)
        }
        sc[kk] = val;
        lmax = fmaxf(lmax, val);
    }
    for (int off = 32; off > 0; off >>= 1) lmax = fmaxf(lmax, __shfl_down(lmax, off));
    if ((tid & 63) == 0) red[tid >> 6] = lmax;
    __syncthreads();
    float gmax = fmaxf(fmaxf(red[0], red[1]), fmaxf(red[2], red[3]));
    __syncthreads();

    float lsum = 0.f;
    for (int kk = tid; kk < SEQ; kk += 256) {
        float p = __expf(sc[kk] - gmax);
        sc[kk] = p;
        lsum += p;
    }
    for (int off = 32; off > 0; off >>= 1) lsum += __shfl_down(lsum, off);
    if ((tid & 63) == 0) red[tid >> 6] = lsum;
    __syncthreads();
    float gsum = red[0] + red[1] + red[2] + red[3];

    int d = tid & (HDIM - 1);
    int c = tid >> 6;   // 0..3
    float acc = 0.f;
    for (int kk = c; kk <= qi; kk += 4)
        acc += sc[kk] * v[(size_t)(b * SEQ + kk) * HS + hoff + d];
    oacc[c][d] = acc;
    __syncthreads();
    if (tid < HDIM) {
        float s = oacc[0][tid] + oacc[1][tid] + oacc[2][tid] + oacc[3][tid];
        ctx[(size_t)(b * SEQ + qi) * HS + hoff + tid] = s / gsum;
    }
}

// ---------------------------------------------------------------- h = x + proj; out = h
__global__ void add2_kernel(const float* __restrict__ a, const float* __restrict__ b,
                            float* __restrict__ h, float* __restrict__ out) {
    int i = blockIdx.x * 256 + threadIdx.x;
    float vv = a[i] + b[i];
    h[i] = vv;
    out[i] = vv;
}

// ---------------------------------------------------------------- router: softmax + top2 + renorm -> combine[T,E]
__global__ void router_kernel(const float* __restrict__ hn, const float* __restrict__ rw,
                              float* __restrict__ comb) {
    int t = blockIdx.x;
    int lane = threadIdx.x;   // 64 threads = 1 wave
    float acc[NEXP];
    #pragma unroll
    for (int e = 0; e < NEXP; e++) acc[e] = 0.f;
    const float* row = hn + (size_t)t * HS;
    for (int kk = lane; kk < HS; kk += 64) {
        float xv = row[kk];
        const float* r = rw + (size_t)kk * NEXP;
        #pragma unroll
        for (int e = 0; e < NEXP; e++) acc[e] += xv * r[e];
    }
    #pragma unroll
    for (int e = 0; e < NEXP; e++)
        for (int off = 32; off > 0; off >>= 1) acc[e] += __shfl_down(acc[e], off);
    if (lane == 0) {
        float m = acc[0];
        #pragma unroll
        for (int e = 1; e < NEXP; e++) m = fmaxf(m, acc[e]);
        float p[NEXP]; float s = 0.f;
        #pragma unroll
        for (int e = 0; e < NEXP; e++) { p[e] = __expf(acc[e] - m); s += p[e]; }
        #pragma unroll
        for (int e = 0; e < NEXP; e++) p[e] /= s;
        int i0 = 0;
        #pragma unroll
        for (int e = 1; e < NEXP; e++) if (p[e] > p[i0]) i0 = e;   // first max (jax tie-break)
        int i1 = (i0 == 0) ? 1 : 0;
        #pragma unroll
        for (int e = 0; e < NEXP; e++) if (e != i0 && p[e] > p[i1]) i1 = e;
        float v0 = p[i0], v1 = p[i1], sn = v0 + v1;
        float* c = comb + (size_t)t * NEXP;
        #pragma unroll
        for (int e = 0; e < NEXP; e++) c[e] = 0.f;
        c[i0] = v0 / sn;
        c[i1] = v1 / sn;
    }
}

// ---------------------------------------------------------------- g = silu(g) * h3 (in place on g)
__global__ void silu_mul_kernel(float* __restrict__ g, const float* __restrict__ h3, int n) {
    int i = blockIdx.x * 256 + threadIdx.x;
    if (i < n) {
        float a = g[i];
        float sg = a / (1.f + __expf(-a));
        g[i] = sg * h3[i];
    }
}

// ---------------------------------------------------------------- out += combine[:,e] * ye
__global__ void moe_acc_kernel(float* __restrict__ out, const float* __restrict__ ye,
                               const float* __restrict__ comb, int e) {
    int i = blockIdx.x * 256 + threadIdx.x;   // NTOK*HS
    int t = i >> 10;                          // HS = 1024
    float w = comb[(size_t)t * NEXP + e];
    if (w != 0.f) out[i] += w * ye[i];
}

// ---------------------------------------------------------------- launch
extern "C" void kernel_launch(void* const* d_in, const int* in_sizes, int n_in,
                              void* d_out, int out_size, void* d_ws, size_t ws_size,
                              hipStream_t stream) {
    const float* x   = (const float*)d_in[0];
    const float* anw = (const float*)d_in[1];
    const float* fnw = (const float*)d_in[2];
    const float* wq  = (const float*)d_in[3];
    const float* wk  = (const float*)d_in[4];
    const float* wv  = (const float*)d_in[5];
    const float* wo  = (const float*)d_in[6];
    const float* rw  = (const float*)d_in[7];
    const float* w1  = (const float*)d_in[8];
    const float* w3  = (const float*)d_in[9];
    const float* w2  = (const float*)d_in[10];
    const float* fc  = (const float*)d_in[11];
    float* out = (float*)d_out;

    const size_t TH = (size_t)NTOK * HS;   // 2,097,152 floats
    float* ws = (float*)d_ws;
    // arena (8*TH floats = 64 MB total), with aliasing:
    float* xn   = ws;            // [TH] attn-norm out; later ctx; later ye
    float* q    = ws + TH;       // [TH] q; later h
    float* k    = ws + 2 * TH;   // [TH] k; later hn
    float* v    = ws + 3 * TH;   // [TH] v; later combine
    float* big1 = ws + 4 * TH;   // [2*TH] attn proj tmp; then h1/g
    float* big2 = ws + 6 * TH;   // [2*TH] h3
    float* ctx  = xn;
    float* h    = q;
    float* hn   = k;
    float* comb = v;
    float* ye   = xn;

    // 1. attention rmsnorm
    rmsnorm_kernel<<<NTOK, 256, 0, stream>>>(x, anw, xn);

    // 2. QKV projections
    dim3 gqkv(HS / 64, NTOK / 64);
    gemm_f32<<<gqkv, 256, 0, stream>>>(xn, wq, q, NTOK, HS, HS);
    gemm_f32<<<gqkv, 256, 0, stream>>>(xn, wk, k, NTOK, HS, HS);
    gemm_f32<<<gqkv, 256, 0, stream>>>(xn, wv, v, NTOK, HS, HS);

    // 3. RoPE in-place
    rope_kernel<<<(NTOK * NHEAD * (HDIM / 2)) / 256, 256, 0, stream>>>(q, k, fc);

    // 4. attention
    dim3 ga(SEQ, NHEAD, BATCH);
    attn_kernel<<<ga, 256, 0, stream>>>(q, k, v, ctx);

    // 5. output projection
    gemm_f32<<<gqkv, 256, 0, stream>>>(ctx, wo, big1, NTOK, HS, HS);

    // 6. h = x + proj; out initialized to h
    add2_kernel<<<(int)(TH / 256), 256, 0, stream>>>(x, big1, h, out);

    // 7. ffn rmsnorm
    rmsnorm_kernel<<<NTOK, 256, 0, stream>>>(h, fnw, hn);

    // 8. router -> combine weights [T, E] (zeros except renormalized top-2)
    router_kernel<<<NTOK, 64, 0, stream>>>(hn, rw, comb);

    // 9. experts (dense over experts == routed top-2, combine weights are 0 elsewhere)
    dim3 gup(IS / 64, NTOK / 64);
    dim3 gdn(HS / 64, NTOK / 64);
    for (int e = 0; e < NEXP; e++) {
        const float* w1e = w1 + (size_t)e * HS * IS;
        const float* w3e = w3 + (size_t)e * HS * IS;
        const float* w2e = w2 + (size_t)e * IS * HS;
        gemm_f32<<<gup, 256, 0, stream>>>(hn, w1e, big1, NTOK, IS, HS);
        gemm_f32<<<gup, 256, 0, stream>>>(hn, w3e, big2, NTOK, IS, HS);
        silu_mul_kernel<<<(NTOK * IS) / 256, 256, 0, stream>>>(big1, big2, NTOK * IS);
        gemm_f32<<<gdn, 256, 0, stream>>>(big1, w2e, ye, NTOK, HS, IS);
        moe_acc_kernel<<<(int)(TH / 256), 256, 0, stream>>>(out, ye, comb, e);
    }
}

// Round 2
// 1524.133 us; speedup vs baseline: 3.0194x; 3.0194x over previous
//
#include <hip/hip_runtime.h>
#include <math.h>

#define HS 1024      // hidden size
#define IS 2048      // intermediate size
#define NHEAD 16
#define HDIM 64
#define NEXP 8
#define BATCH 2
#define SEQ 1024
#define NTOK (BATCH*SEQ)     // 2048 tokens
#define NASSIGN (NTOK*2)     // 4096 (token, expert) assignments, exact

// ---------------------------------------------------------------- rmsnorm
__global__ void rmsnorm_kernel(const float* __restrict__ x, const float* __restrict__ w,
                               float* __restrict__ out) {
    int t = blockIdx.x;
    int tid = threadIdx.x;
    const float* row = x + (size_t)t * HS;
    float ss = 0.f;
    for (int i = tid; i < HS; i += 256) { float v = row[i]; ss += v * v; }
    for (int off = 32; off > 0; off >>= 1) ss += __shfl_down(ss, off);
    __shared__ float red[4];
    if ((tid & 63) == 0) red[tid >> 6] = ss;
    __syncthreads();
    float tot = red[0] + red[1] + red[2] + red[3];
    float rr = rsqrtf(tot / (float)HS + 1e-6f);
    float* orow = out + (size_t)t * HS;
    for (int i = tid; i < HS; i += 256) orow[i] = w[i] * row[i] * rr;
}

// ---------------------------------------------------------------- generic fp32 GEMM
// C[M,N] = A[M,K] @ B[K,N], row-major. M,N mult of 64; K mult of 16.
__global__ __launch_bounds__(256) void gemm_f32(const float* __restrict__ A,
                                                const float* __restrict__ B,
                                                float* __restrict__ C,
                                                int M, int N, int K) {
    __shared__ float As[16][64];
    __shared__ float Bs[16][64];
    int bm = blockIdx.y * 64;
    int bn = blockIdx.x * 64;
    int t = threadIdx.x;
    int tx = t & 15, ty = t >> 4;
    float acc[4][4] = {};
    for (int k0 = 0; k0 < K; k0 += 16) {
        {
            int m  = t >> 2;
            int kq = (t & 3) << 2;
            float4 av = *(const float4*)(A + (size_t)(bm + m) * K + k0 + kq);
            As[kq + 0][m] = av.x; As[kq + 1][m] = av.y;
            As[kq + 2][m] = av.z; As[kq + 3][m] = av.w;
        }
        {
            int kk = t >> 4;
            int nq = (t & 15) << 2;
            float4 bv = *(const float4*)(B + (size_t)(k0 + kk) * N + bn + nq);
            Bs[kk][nq + 0] = bv.x; Bs[kk][nq + 1] = bv.y;
            Bs[kk][nq + 2] = bv.z; Bs[kk][nq + 3] = bv.w;
        }
        __syncthreads();
        #pragma unroll
        for (int kk = 0; kk < 16; kk++) {
            float a[4], b[4];
            #pragma unroll
            for (int i = 0; i < 4; i++) a[i] = As[kk][ty * 4 + i];
            #pragma unroll
            for (int j = 0; j < 4; j++) b[j] = Bs[kk][tx * 4 + j];
            #pragma unroll
            for (int i = 0; i < 4; i++)
                #pragma unroll
                for (int j = 0; j < 4; j++) acc[i][j] += a[i] * b[j];
        }
        __syncthreads();
    }
    #pragma unroll
    for (int i = 0; i < 4; i++) {
        float4 cv = make_float4(acc[i][0], acc[i][1], acc[i][2], acc[i][3]);
        *(float4*)(C + (size_t)(bm + ty * 4 + i) * N + bn + tx * 4) = cv;
    }
}

// ---------------------------------------------------------------- RoPE (in-place q,k)
__global__ void rope_kernel(float* __restrict__ q, float* __restrict__ k,
                            const float* __restrict__ fc) {
    int idx = blockIdx.x * 256 + threadIdx.x;   // NTOK*NHEAD*32
    int j    = idx & 31;
    int rest = idx >> 5;
    int h = rest & (NHEAD - 1);
    int t = rest >> 4;
    int s = t & (SEQ - 1);
    float cr = fc[s * HDIM + 2 * j];
    float ci = fc[s * HDIM + 2 * j + 1];
    size_t base = (size_t)t * HS + h * HDIM + 2 * j;
    float a = q[base], b = q[base + 1];
    q[base]     = a * cr - b * ci;
    q[base + 1] = a * ci + b * cr;
    a = k[base]; b = k[base + 1];
    k[base]     = a * cr - b * ci;
    k[base + 1] = a * ci + b * cr;
}

// ---------------------------------------------------------------- flash attention
// block = (qtile, head, batch); 256 threads; 64x64 tiles, online softmax.
__global__ __launch_bounds__(256) void attn_flash(const float* __restrict__ q,
                                                  const float* __restrict__ k,
                                                  const float* __restrict__ v,
                                                  float* __restrict__ ctx) {
    int qt = gridDim.x - 1 - blockIdx.x;     // heavy tiles first
    int h  = blockIdx.y;
    int b  = blockIdx.z;
    int tid = threadIdx.x;
    int tx = tid & 15, ty = tid >> 4;
    __shared__ float Qs[64][68];   // [d][q] transposed
    __shared__ float KV[64][68];   // K phase: [d][k]; V phase: [k][d]
    __shared__ float Ps[64][68];   // [q][k]
    const int qbase = qt * 64;
    const size_t hoff = (size_t)h * HDIM;

    #pragma unroll
    for (int it = 0; it < 4; it++) {
        int idx = it * 256 + tid;
        int r = idx >> 4, g = idx & 15;
        float4 qv = *(const float4*)(q + (size_t)(b * SEQ + qbase + r) * HS + hoff + g * 4);
        Qs[g * 4 + 0][r] = qv.x; Qs[g * 4 + 1][r] = qv.y;
        Qs[g * 4 + 2][r] = qv.z; Qs[g * 4 + 3][r] = qv.w;
    }

    float o[4][4] = {};
    float m[4], l[4];
    #pragma unroll
    for (int i = 0; i < 4; i++) { m[i] = -1e30f; l[i] = 0.f; }

    for (int kt = 0; kt <= qt; kt++) {
        int kbase = kt * 64;
        __syncthreads();   // prev PV done reading KV/Ps; Q tile visible (first iter)
        #pragma unroll
        for (int it = 0; it < 4; it++) {
            int idx = it * 256 + tid;
            int r = idx >> 4, g = idx & 15;
            float4 kv4 = *(const float4*)(k + (size_t)(b * SEQ + kbase + r) * HS + hoff + g * 4);
            KV[g * 4 + 0][r] = kv4.x; KV[g * 4 + 1][r] = kv4.y;
            KV[g * 4 + 2][r] = kv4.z; KV[g * 4 + 3][r] = kv4.w;
        }
        __syncthreads();

        // S = Q K^T (64x64), this thread owns rows ty*4+i, cols tx*4+j
        float s[4][4] = {};
        #pragma unroll 8
        for (int kk = 0; kk < 64; kk++) {
            float4 av = *(const float4*)&Qs[kk][ty * 4];
            float4 bv = *(const float4*)&KV[kk][tx * 4];
            float a[4] = {av.x, av.y, av.z, av.w};
            float bb[4] = {bv.x, bv.y, bv.z, bv.w};
            #pragma unroll
            for (int i = 0; i < 4; i++)
                #pragma unroll
                for (int j = 0; j < 4; j++) s[i][j] += a[i] * bb[j];
        }
        // scale + causal mask
        if (kt == qt) {
            #pragma unroll
            for (int i = 0; i < 4; i++)
                #pragma unroll
                for (int j = 0; j < 4; j++)
                    s[i][j] = (tx * 4 + j > ty * 4 + i) ? -1e9f : s[i][j] * 0.125f;
        } else {
            #pragma unroll
            for (int i = 0; i < 4; i++)
                #pragma unroll
                for (int j = 0; j < 4; j++) s[i][j] *= 0.125f;
        }
        // online softmax update (row stats shared by the 16 lanes of each ty group)
        #pragma unroll
        for (int i = 0; i < 4; i++) {
            float mx = fmaxf(fmaxf(s[i][0], s[i][1]), fmaxf(s[i][2], s[i][3]));
            #pragma unroll
            for (int w = 1; w < 16; w <<= 1) mx = fmaxf(mx, __shfl_xor(mx, w));
            float nm = fmaxf(m[i], mx);
            float alpha = __expf(m[i] - nm);
            float rs = 0.f;
            #pragma unroll
            for (int j = 0; j < 4; j++) { s[i][j] = __expf(s[i][j] - nm); rs += s[i][j]; }
            #pragma unroll
            for (int w = 1; w < 16; w <<= 1) rs += __shfl_xor(rs, w);
            l[i] = l[i] * alpha + rs;
            m[i] = nm;
            #pragma unroll
            for (int j = 0; j < 4; j++) o[i][j] *= alpha;
        }
        __syncthreads();   // done reading KV as K
        // load V (natural [k][d]) and publish P
        #pragma unroll
        for (int it = 0; it < 4; it++) {
            int idx = it * 256 + tid;
            int r = idx >> 4, g = idx & 15;
            *(float4*)&KV[r][g * 4] =
                *(const float4*)(v + (size_t)(b * SEQ + kbase + r) * HS + hoff + g * 4);
        }
        #pragma unroll
        for (int i = 0; i < 4; i++)
            *(float4*)&Ps[ty * 4 + i][tx * 4] = make_float4(s[i][0], s[i][1], s[i][2], s[i][3]);
        __syncthreads();
        // O += P V ; this thread owns rows ty*4+i, d-cols tx*4+j
        #pragma unroll 8
        for (int kk = 0; kk < 64; kk++) {
            float4 bv = *(const float4*)&KV[kk][tx * 4];
            #pragma unroll
            for (int i = 0; i < 4; i++) {
                float a = Ps[ty * 4 + i][kk];
                o[i][0] += a * bv.x; o[i][1] += a * bv.y;
                o[i][2] += a * bv.z; o[i][3] += a * bv.w;
            }
        }
    }
    #pragma unroll
    for (int i = 0; i < 4; i++) {
        float inv = 1.f / l[i];
        float4 r = make_float4(o[i][0] * inv, o[i][1] * inv, o[i][2] * inv, o[i][3] * inv);
        *(float4*)(ctx + (size_t)(b * SEQ + qbase + ty * 4 + i) * HS + hoff + tx * 4) = r;
    }
}

// ---------------------------------------------------------------- h = x + proj; out = h
__global__ void add2_kernel(const float* __restrict__ a, const float* __restrict__ b,
                            float* __restrict__ h, float* __restrict__ out) {
    int i = blockIdx.x * 256 + threadIdx.x;
    float vv = a[i] + b[i];
    h[i] = vv;
    out[i] = vv;
}

// ---------------------------------------------------------------- router (per-token top2)
__global__ void router_kernel(const float* __restrict__ hn, const float* __restrict__ rw,
                              int* __restrict__ cnt, int* __restrict__ topEk,
                              float* __restrict__ topW) {
    int t = blockIdx.x;
    int lane = threadIdx.x;   // 64 = 1 wave
    float acc[NEXP];
    #pragma unroll
    for (int e = 0; e < NEXP; e++) acc[e] = 0.f;
    const float* row = hn + (size_t)t * HS;
    for (int kk = lane; kk < HS; kk += 64) {
        float xv = row[kk];
        const float* r = rw + (size_t)kk * NEXP;
        #pragma unroll
        for (int e = 0; e < NEXP; e++) acc[e] += xv * r[e];
    }
    #pragma unroll
    for (int e = 0; e < NEXP; e++)
        for (int off = 32; off > 0; off >>= 1) acc[e] += __shfl_down(acc[e], off);
    if (lane == 0) {
        float mx = acc[0];
        #pragma unroll
        for (int e = 1; e < NEXP; e++) mx = fmaxf(mx, acc[e]);
        float p[NEXP]; float s = 0.f;
        #pragma unroll
        for (int e = 0; e < NEXP; e++) { p[e] = __expf(acc[e] - mx); s += p[e]; }
        int i0 = 0;
        #pragma unroll
        for (int e = 1; e < NEXP; e++) if (p[e] > p[i0]) i0 = e;   // first-max tie-break
        int i1 = (i0 == 0) ? 1 : 0;
        #pragma unroll
        for (int e = 0; e < NEXP; e++) if (e != i0 && p[e] > p[i1]) i1 = e;
        float v0 = p[i0], v1 = p[i1], sn = v0 + v1;
        topEk[2 * t]     = i0; topW[2 * t]     = v0 / sn;
        topEk[2 * t + 1] = i1; topW[2 * t + 1] = v1 / sn;
        atomicAdd(&cnt[i0], 1);
        atomicAdd(&cnt[i1], 1);
    }
}

__global__ void offsets_kernel(const int* __restrict__ cnt, int* __restrict__ off) {
    if (threadIdx.x == 0) {
        int o = 0;
        for (int e = 0; e < NEXP; e++) { off[e] = o; o += cnt[e]; }
    }
}

__global__ void scatter_kernel(const int* __restrict__ topEk, int* __restrict__ fill,
                               const int* __restrict__ off, int* __restrict__ tok_list,
                               int* __restrict__ topR) {
    int idx = blockIdx.x * 256 + threadIdx.x;   // NASSIGN
    int e = topEk[idx];
    int slot = atomicAdd(&fill[e], 1);
    int gidx = off[e] + slot;
    tok_list[gidx] = idx >> 1;
    topR[idx] = gidx;
}

// ---------------------------------------------------------------- fused up-proj (w1 & w3), routed
// act[row, :] = silu(xg@w1) * (xg@w3), rows gathered via tok_list
__global__ __launch_bounds__(256) void gemm_up_fused(const float* __restrict__ A,
                                                     const float* __restrict__ w1,
                                                     const float* __restrict__ w3,
                                                     float* __restrict__ g,
                                                     const int* __restrict__ cnt,
                                                     const int* __restrict__ off,
                                                     const int* __restrict__ tok_list) {
    int e = blockIdx.z;
    int ce = cnt[e];
    int bm = blockIdx.y * 64;
    if (bm >= ce) return;
    int oe = off[e];
    int bn = blockIdx.x * 64;
    const float* B1 = w1 + (size_t)e * HS * IS;
    const float* B3 = w3 + (size_t)e * HS * IS;
    __shared__ float As[16][64];
    __shared__ float Bs1[16][64];
    __shared__ float Bs3[16][64];
    __shared__ int toks[64];
    int t = threadIdx.x;
    int tx = t & 15, ty = t >> 4;
    if (t < 64) {
        int gidx = oe + bm + t;
        if (gidx >= NASSIGN) gidx = NASSIGN - 1;
        toks[t] = tok_list[gidx];   // rows beyond ce compute garbage, never stored
    }
    __syncthreads();
    float acc1[4][4] = {}, acc2[4][4] = {};
    for (int k0 = 0; k0 < HS; k0 += 16) {
        {
            int m  = t >> 2;
            int kq = (t & 3) << 2;
            float4 av = *(const float4*)(A + (size_t)toks[m] * HS + k0 + kq);
            As[kq + 0][m] = av.x; As[kq + 1][m] = av.y;
            As[kq + 2][m] = av.z; As[kq + 3][m] = av.w;
        }
        {
            int kk = t >> 4;
            int nq = (t & 15) << 2;
            float4 b1 = *(const float4*)(B1 + (size_t)(k0 + kk) * IS + bn + nq);
            Bs1[kk][nq + 0] = b1.x; Bs1[kk][nq + 1] = b1.y;
            Bs1[kk][nq + 2] = b1.z; Bs1[kk][nq + 3] = b1.w;
            float4 b3 = *(const float4*)(B3 + (size_t)(k0 + kk) * IS + bn + nq);
            Bs3[kk][nq + 0] = b3.x; Bs3[kk][nq + 1] = b3.y;
            Bs3[kk][nq + 2] = b3.z; Bs3[kk][nq + 3] = b3.w;
        }
        __syncthreads();
        #pragma unroll
        for (int kk = 0; kk < 16; kk++) {
            float a[4], b1v[4], b3v[4];
            #pragma unroll
            for (int i = 0; i < 4; i++) a[i] = As[kk][ty * 4 + i];
            #pragma unroll
            for (int j = 0; j < 4; j++) { b1v[j] = Bs1[kk][tx * 4 + j]; b3v[j] = Bs3[kk][tx * 4 + j]; }
            #pragma unroll
            for (int i = 0; i < 4; i++)
                #pragma unroll
                for (int j = 0; j < 4; j++) {
                    acc1[i][j] += a[i] * b1v[j];
                    acc2[i][j] += a[i] * b3v[j];
                }
        }
        __syncthreads();
    }
    #pragma unroll
    for (int i = 0; i < 4; i++) {
        int slot = bm + ty * 4 + i;
        if (slot < ce) {
            float r[4];
            #pragma unroll
            for (int j = 0; j < 4; j++) {
                float x1 = acc1[i][j];
                r[j] = (x1 / (1.f + __expf(-x1))) * acc2[i][j];
            }
            *(float4*)(g + (size_t)(oe + slot) * IS + bn + tx * 4) =
                make_float4(r[0], r[1], r[2], r[3]);
        }
    }
}

// ---------------------------------------------------------------- down-proj, routed
__global__ __launch_bounds__(256) void gemm_down(const float* __restrict__ g,
                                                 const float* __restrict__ w2,
                                                 float* __restrict__ ye,
                                                 const int* __restrict__ cnt,
                                                 const int* __restrict__ off) {
    int e = blockIdx.z;
    int ce = cnt[e];
    int bm = blockIdx.y * 64;
    if (bm >= ce) return;
    int oe = off[e];
    int bn = blockIdx.x * 64;
    const float* B = w2 + (size_t)e * IS * HS;
    __shared__ float As[16][64];
    __shared__ float Bs[16][64];
    int t = threadIdx.x;
    int tx = t & 15, ty = t >> 4;
    float acc[4][4] = {};
    for (int k0 = 0; k0 < IS; k0 += 16) {
        {
            int m  = t >> 2;
            int kq = (t & 3) << 2;
            int gidx = oe + bm + m;
            if (gidx >= NASSIGN) gidx = NASSIGN - 1;
            float4 av = *(const float4*)(g + (size_t)gidx * IS + k0 + kq);
            As[kq + 0][m] = av.x; As[kq + 1][m] = av.y;
            As[kq + 2][m] = av.z; As[kq + 3][m] = av.w;
        }
        {
            int kk = t >> 4;
            int nq = (t & 15) << 2;
            float4 bv = *(const float4*)(B + (size_t)(k0 + kk) * HS + bn + nq);
            Bs[kk][nq + 0] = bv.x; Bs[kk][nq + 1] = bv.y;
            Bs[kk][nq + 2] = bv.z; Bs[kk][nq + 3] = bv.w;
        }
        __syncthreads();
        #pragma unroll
        for (int kk = 0; kk < 16; kk++) {
            float a[4], b[4];
            #pragma unroll
            for (int i = 0; i < 4; i++) a[i] = As[kk][ty * 4 + i];
            #pragma unroll
            for (int j = 0; j < 4; j++) b[j] = Bs[kk][tx * 4 + j];
            #pragma unroll
            for (int i = 0; i < 4; i++)
                #pragma unroll
                for (int j = 0; j < 4; j++) acc[i][j] += a[i] * b[j];
        }
        __syncthreads();
    }
    #pragma unroll
    for (int i = 0; i < 4; i++) {
        int slot = bm + ty * 4 + i;
        if (slot < ce)
            *(float4*)(ye + (size_t)(oe + slot) * HS + bn + tx * 4) =
                make_float4(acc[i][0], acc[i][1], acc[i][2], acc[i][3]);
    }
}

// ---------------------------------------------------------------- out[t] += w0*ye[r0] + w1*ye[r1]
__global__ void gather_kernel(float* __restrict__ out, const float* __restrict__ ye,
                              const float* __restrict__ topW, const int* __restrict__ topR) {
    int i = blockIdx.x * 256 + threadIdx.x;   // NTOK*HS
    int tk = i >> 10;
    int col = i & (HS - 1);
    out[i] += topW[2 * tk]     * ye[(size_t)topR[2 * tk]     * HS + col]
            + topW[2 * tk + 1] * ye[(size_t)topR[2 * tk + 1] * HS + col];
}

// ---------------------------------------------------------------- launch
extern "C" void kernel_launch(void* const* d_in, const int* in_sizes, int n_in,
                              void* d_out, int out_size, void* d_ws, size_t ws_size,
                              hipStream_t stream) {
    const float* x   = (const float*)d_in[0];
    const float* anw = (const float*)d_in[1];
    const float* fnw = (const float*)d_in[2];
    const float* wq  = (const float*)d_in[3];
    const float* wk  = (const float*)d_in[4];
    const float* wv  = (const float*)d_in[5];
    const float* wo  = (const float*)d_in[6];
    const float* rw  = (const float*)d_in[7];
    const float* w1  = (const float*)d_in[8];
    const float* w3  = (const float*)d_in[9];
    const float* w2  = (const float*)d_in[10];
    const float* fc  = (const float*)d_in[11];
    float* out = (float*)d_out;

    const size_t TH = (size_t)NTOK * HS;   // 2M floats
    float* ws = (float*)d_ws;
    // Phase A: xn[0,TH) q[TH,2TH) k[2TH,3TH) v[3TH,4TH) ctx[4TH,5TH) proj[5TH,6TH)
    // Phase B: h[0,TH) hn[TH,2TH) g[2TH,6TH)  then  ye[0,2TH)
    float* xn   = ws;
    float* qb   = ws + TH;
    float* kb   = ws + 2 * TH;
    float* vb   = ws + 3 * TH;
    float* ctx  = ws + 4 * TH;
    float* proj = ws + 5 * TH;
    float* h    = ws;
    float* hn   = ws + TH;
    float* g    = ws + 2 * TH;   // 4*TH floats (4096 x 2048)
    float* ye   = ws;            // 2*TH floats (4096 x 1024)
    int* ibase    = (int*)(ws + 6 * TH);
    int* cnt      = ibase;            // 8
    int* fill     = ibase + 8;        // 8
    int* off      = ibase + 16;       // 8
    int* topEk    = ibase + 32;       // 4096
    int* tok_list = ibase + 32 + NASSIGN;
    int* topR     = ibase + 32 + 2 * NASSIGN;
    float* topW   = (float*)(ibase + 32 + 3 * NASSIGN);

    // ---- attention half ----
    rmsnorm_kernel<<<NTOK, 256, 0, stream>>>(x, anw, xn);
    dim3 gqkv(HS / 64, NTOK / 64);
    gemm_f32<<<gqkv, 256, 0, stream>>>(xn, wq, qb, NTOK, HS, HS);
    gemm_f32<<<gqkv, 256, 0, stream>>>(xn, wk, kb, NTOK, HS, HS);
    gemm_f32<<<gqkv, 256, 0, stream>>>(xn, wv, vb, NTOK, HS, HS);
    rope_kernel<<<(NTOK * NHEAD * (HDIM / 2)) / 256, 256, 0, stream>>>(qb, kb, fc);
    dim3 ga(SEQ / 64, NHEAD, BATCH);
    attn_flash<<<ga, 256, 0, stream>>>(qb, kb, vb, ctx);
    gemm_f32<<<gqkv, 256, 0, stream>>>(ctx, wo, proj, NTOK, HS, HS);
    add2_kernel<<<(int)(TH / 256), 256, 0, stream>>>(x, proj, h, out);

    // ---- MoE half (routed top-2) ----
    rmsnorm_kernel<<<NTOK, 256, 0, stream>>>(h, fnw, hn);
    hipMemsetAsync(cnt, 0, 16 * sizeof(int), stream);   // cnt + fill
    router_kernel<<<NTOK, 64, 0, stream>>>(hn, rw, cnt, topEk, topW);
    offsets_kernel<<<1, 64, 0, stream>>>(cnt, off);
    scatter_kernel<<<NASSIGN / 256, 256, 0, stream>>>(topEk, fill, off, tok_list, topR);
    dim3 gup(IS / 64, NTOK / 64, NEXP);
    gemm_up_fused<<<gup, 256, 0, stream>>>(hn, w1, w3, g, cnt, off, tok_list);
    dim3 gdn(HS / 64, NTOK / 64, NEXP);
    gemm_down<<<gdn, 256, 0, stream>>>(g, w2, ye, cnt, off);
    gather_kernel<<<(int)(TH / 256), 256, 0, stream>>>(out, ye, topW, topR);
}

// Round 3
// 991.097 us; speedup vs baseline: 4.6434x; 1.5378x over previous
//
#include <hip/hip_runtime.h>
#include <hip/hip_bf16.h>
#include <math.h>

#define HS 1024      // hidden size
#define IS 2048      // intermediate size
#define NHEAD 16
#define HDIM 64
#define NEXP 8
#define BATCH 2
#define SEQ 1024
#define NTOK (BATCH*SEQ)     // 2048 tokens
#define NASSIGN (NTOK*2)     // 4096 (token, expert) assignments

typedef short bf16x8 __attribute__((ext_vector_type(8)));
typedef float f32x4  __attribute__((ext_vector_type(4)));

// ---------------------------------------------------------------- rmsnorm (fp32 out)
__global__ void rmsnorm_kernel(const float* __restrict__ x, const float* __restrict__ w,
                               float* __restrict__ out) {
    int t = blockIdx.x;
    int tid = threadIdx.x;
    const float* row = x + (size_t)t * HS;
    float ss = 0.f;
    for (int i = tid; i < HS; i += 256) { float v = row[i]; ss += v * v; }
    for (int off = 32; off > 0; off >>= 1) ss += __shfl_down(ss, off);
    __shared__ float red[4];
    if ((tid & 63) == 0) red[tid >> 6] = ss;
    __syncthreads();
    float tot = red[0] + red[1] + red[2] + red[3];
    float rr = rsqrtf(tot / (float)HS + 1e-6f);
    float* orow = out + (size_t)t * HS;
    for (int i = tid; i < HS; i += 256) orow[i] = w[i] * row[i] * rr;
}

// ---------------------------------------------------------------- rmsnorm dual (fp32 + bf16)
__global__ void rmsnorm_dual(const float* __restrict__ x, const float* __restrict__ w,
                             float* __restrict__ outf, __hip_bfloat16* __restrict__ outb) {
    int t = blockIdx.x;
    int tid = threadIdx.x;
    const float* row = x + (size_t)t * HS;
    float ss = 0.f;
    for (int i = tid; i < HS; i += 256) { float v = row[i]; ss += v * v; }
    for (int off = 32; off > 0; off >>= 1) ss += __shfl_down(ss, off);
    __shared__ float red[4];
    if ((tid & 63) == 0) red[tid >> 6] = ss;
    __syncthreads();
    float tot = red[0] + red[1] + red[2] + red[3];
    float rr = rsqrtf(tot / (float)HS + 1e-6f);
    for (int i = tid; i < HS; i += 256) {
        float v = w[i] * row[i] * rr;
        outf[(size_t)t * HS + i] = v;
        outb[(size_t)t * HS + i] = __float2bfloat16(v);
    }
}

// ---------------------------------------------------------------- fp32 GEMM (QKV)
__global__ __launch_bounds__(256) void gemm_f32(const float* __restrict__ A,
                                                const float* __restrict__ B,
                                                float* __restrict__ C,
                                                int M, int N, int K) {
    __shared__ float As[16][64];
    __shared__ float Bs[16][64];
    int bm = blockIdx.y * 64;
    int bn = blockIdx.x * 64;
    int t = threadIdx.x;
    int tx = t & 15, ty = t >> 4;
    float acc[4][4] = {};
    for (int k0 = 0; k0 < K; k0 += 16) {
        {
            int m  = t >> 2;
            int kq = (t & 3) << 2;
            float4 av = *(const float4*)(A + (size_t)(bm + m) * K + k0 + kq);
            As[kq + 0][m] = av.x; As[kq + 1][m] = av.y;
            As[kq + 2][m] = av.z; As[kq + 3][m] = av.w;
        }
        {
            int kk = t >> 4;
            int nq = (t & 15) << 2;
            float4 bv = *(const float4*)(B + (size_t)(k0 + kk) * N + bn + nq);
            Bs[kk][nq + 0] = bv.x; Bs[kk][nq + 1] = bv.y;
            Bs[kk][nq + 2] = bv.z; Bs[kk][nq + 3] = bv.w;
        }
        __syncthreads();
        #pragma unroll
        for (int kk = 0; kk < 16; kk++) {
            float a[4], b[4];
            #pragma unroll
            for (int i = 0; i < 4; i++) a[i] = As[kk][ty * 4 + i];
            #pragma unroll
            for (int j = 0; j < 4; j++) b[j] = Bs[kk][tx * 4 + j];
            #pragma unroll
            for (int i = 0; i < 4; i++)
                #pragma unroll
                for (int j = 0; j < 4; j++) acc[i][j] += a[i] * b[j];
        }
        __syncthreads();
    }
    #pragma unroll
    for (int i = 0; i < 4; i++) {
        float4 cv = make_float4(acc[i][0], acc[i][1], acc[i][2], acc[i][3]);
        *(float4*)(C + (size_t)(bm + ty * 4 + i) * N + bn + tx * 4) = cv;
    }
}

// ---------------------------------------------------------------- fp32 GEMM + residual (O-proj)
__global__ __launch_bounds__(256) void gemm_f32_res(const float* __restrict__ A,
                                                    const float* __restrict__ B,
                                                    const float* __restrict__ X,
                                                    float* __restrict__ C,
                                                    int M, int N, int K) {
    __shared__ float As[16][64];
    __shared__ float Bs[16][64];
    int bm = blockIdx.y * 64;
    int bn = blockIdx.x * 64;
    int t = threadIdx.x;
    int tx = t & 15, ty = t >> 4;
    float acc[4][4] = {};
    for (int k0 = 0; k0 < K; k0 += 16) {
        {
            int m  = t >> 2;
            int kq = (t & 3) << 2;
            float4 av = *(const float4*)(A + (size_t)(bm + m) * K + k0 + kq);
            As[kq + 0][m] = av.x; As[kq + 1][m] = av.y;
            As[kq + 2][m] = av.z; As[kq + 3][m] = av.w;
        }
        {
            int kk = t >> 4;
            int nq = (t & 15) << 2;
            float4 bv = *(const float4*)(B + (size_t)(k0 + kk) * N + bn + nq);
            Bs[kk][nq + 0] = bv.x; Bs[kk][nq + 1] = bv.y;
            Bs[kk][nq + 2] = bv.z; Bs[kk][nq + 3] = bv.w;
        }
        __syncthreads();
        #pragma unroll
        for (int kk = 0; kk < 16; kk++) {
            float a[4], b[4];
            #pragma unroll
            for (int i = 0; i < 4; i++) a[i] = As[kk][ty * 4 + i];
            #pragma unroll
            for (int j = 0; j < 4; j++) b[j] = Bs[kk][tx * 4 + j];
            #pragma unroll
            for (int i = 0; i < 4; i++)
                #pragma unroll
                for (int j = 0; j < 4; j++) acc[i][j] += a[i] * b[j];
        }
        __syncthreads();
    }
    #pragma unroll
    for (int i = 0; i < 4; i++) {
        size_t ro = (size_t)(bm + ty * 4 + i) * N + bn + tx * 4;
        float4 xv = *(const float4*)(X + ro);
        float4 cv = make_float4(acc[i][0] + xv.x, acc[i][1] + xv.y,
                                acc[i][2] + xv.z, acc[i][3] + xv.w);
        *(float4*)(C + ro) = cv;
    }
}

// ---------------------------------------------------------------- RoPE (in-place q,k)
__global__ void rope_kernel(float* __restrict__ q, float* __restrict__ k,
                            const float* __restrict__ fc) {
    int idx = blockIdx.x * 256 + threadIdx.x;   // NTOK*NHEAD*32
    int j    = idx & 31;
    int rest = idx >> 5;
    int h = rest & (NHEAD - 1);
    int t = rest >> 4;
    int s = t & (SEQ - 1);
    float cr = fc[s * HDIM + 2 * j];
    float ci = fc[s * HDIM + 2 * j + 1];
    size_t base = (size_t)t * HS + h * HDIM + 2 * j;
    float a = q[base], b = q[base + 1];
    q[base]     = a * cr - b * ci;
    q[base + 1] = a * ci + b * cr;
    a = k[base]; b = k[base + 1];
    k[base]     = a * cr - b * ci;
    k[base + 1] = a * ci + b * cr;
}

// ---------------------------------------------------------------- flash attention (fp32)
__global__ __launch_bounds__(256) void attn_flash(const float* __restrict__ q,
                                                  const float* __restrict__ k,
                                                  const float* __restrict__ v,
                                                  float* __restrict__ ctx) {
    int qt = gridDim.x - 1 - blockIdx.x;     // heavy tiles first
    int h  = blockIdx.y;
    int b  = blockIdx.z;
    int tid = threadIdx.x;
    int tx = tid & 15, ty = tid >> 4;
    __shared__ float Qs[64][68];   // [d][q]
    __shared__ float KV[64][68];
    __shared__ float Ps[64][68];
    const int qbase = qt * 64;
    const size_t hoff = (size_t)h * HDIM;

    #pragma unroll
    for (int it = 0; it < 4; it++) {
        int idx = it * 256 + tid;
        int r = idx >> 4, g = idx & 15;
        float4 qv = *(const float4*)(q + (size_t)(b * SEQ + qbase + r) * HS + hoff + g * 4);
        Qs[g * 4 + 0][r] = qv.x; Qs[g * 4 + 1][r] = qv.y;
        Qs[g * 4 + 2][r] = qv.z; Qs[g * 4 + 3][r] = qv.w;
    }

    float o[4][4] = {};
    float m[4], l[4];
    #pragma unroll
    for (int i = 0; i < 4; i++) { m[i] = -1e30f; l[i] = 0.f; }

    for (int kt = 0; kt <= qt; kt++) {
        int kbase = kt * 64;
        __syncthreads();
        #pragma unroll
        for (int it = 0; it < 4; it++) {
            int idx = it * 256 + tid;
            int r = idx >> 4, g = idx & 15;
            float4 kv4 = *(const float4*)(k + (size_t)(b * SEQ + kbase + r) * HS + hoff + g * 4);
            KV[g * 4 + 0][r] = kv4.x; KV[g * 4 + 1][r] = kv4.y;
            KV[g * 4 + 2][r] = kv4.z; KV[g * 4 + 3][r] = kv4.w;
        }
        __syncthreads();

        float s[4][4] = {};
        #pragma unroll 8
        for (int kk = 0; kk < 64; kk++) {
            float4 av = *(const float4*)&Qs[kk][ty * 4];
            float4 bv = *(const float4*)&KV[kk][tx * 4];
            float a[4] = {av.x, av.y, av.z, av.w};
            float bb[4] = {bv.x, bv.y, bv.z, bv.w};
            #pragma unroll
            for (int i = 0; i < 4; i++)
                #pragma unroll
                for (int j = 0; j < 4; j++) s[i][j] += a[i] * bb[j];
        }
        if (kt == qt) {
            #pragma unroll
            for (int i = 0; i < 4; i++)
                #pragma unroll
                for (int j = 0; j < 4; j++)
                    s[i][j] = (tx * 4 + j > ty * 4 + i) ? -1e9f : s[i][j] * 0.125f;
        } else {
            #pragma unroll
            for (int i = 0; i < 4; i++)
                #pragma unroll
                for (int j = 0; j < 4; j++) s[i][j] *= 0.125f;
        }
        #pragma unroll
        for (int i = 0; i < 4; i++) {
            float mx = fmaxf(fmaxf(s[i][0], s[i][1]), fmaxf(s[i][2], s[i][3]));
            #pragma unroll
            for (int w = 1; w < 16; w <<= 1) mx = fmaxf(mx, __shfl_xor(mx, w));
            float nm = fmaxf(m[i], mx);
            float alpha = __expf(m[i] - nm);
            float rs = 0.f;
            #pragma unroll
            for (int j = 0; j < 4; j++) { s[i][j] = __expf(s[i][j] - nm); rs += s[i][j]; }
            #pragma unroll
            for (int w = 1; w < 16; w <<= 1) rs += __shfl_xor(rs, w);
            l[i] = l[i] * alpha + rs;
            m[i] = nm;
            #pragma unroll
            for (int j = 0; j < 4; j++) o[i][j] *= alpha;
        }
        __syncthreads();
        #pragma unroll
        for (int it = 0; it < 4; it++) {
            int idx = it * 256 + tid;
            int r = idx >> 4, g = idx & 15;
            *(float4*)&KV[r][g * 4] =
                *(const float4*)(v + (size_t)(b * SEQ + kbase + r) * HS + hoff + g * 4);
        }
        #pragma unroll
        for (int i = 0; i < 4; i++)
            *(float4*)&Ps[ty * 4 + i][tx * 4] = make_float4(s[i][0], s[i][1], s[i][2], s[i][3]);
        __syncthreads();
        #pragma unroll 8
        for (int kk = 0; kk < 64; kk++) {
            float4 bv = *(const float4*)&KV[kk][tx * 4];
            #pragma unroll
            for (int i = 0; i < 4; i++) {
                float a = Ps[ty * 4 + i][kk];
                o[i][0] += a * bv.x; o[i][1] += a * bv.y;
                o[i][2] += a * bv.z; o[i][3] += a * bv.w;
            }
        }
    }
    #pragma unroll
    for (int i = 0; i < 4; i++) {
        float inv = 1.f / l[i];
        float4 r = make_float4(o[i][0] * inv, o[i][1] * inv, o[i][2] * inv, o[i][3] * inv);
        *(float4*)(ctx + (size_t)(b * SEQ + qbase + ty * 4 + i) * HS + hoff + tx * 4) = r;
    }
}

// ---------------------------------------------------------------- transpose fp32 [R][C] -> bf16 [C][R], per expert z
__global__ void transpose_bf16(const float* __restrict__ in, __hip_bfloat16* __restrict__ outp,
                               int R, int C) {
    __shared__ float tile[32][33];
    int e = blockIdx.z;
    const float* src = in + (size_t)e * R * C;
    __hip_bfloat16* dst = outp + (size_t)e * R * C;
    int c0 = blockIdx.x * 32, r0 = blockIdx.y * 32;
    int tx = threadIdx.x & 31, ty = threadIdx.x >> 5;  // 0..7
    #pragma unroll
    for (int i = 0; i < 4; i++) {
        int r = ty + i * 8;
        tile[r][tx] = src[(size_t)(r0 + r) * C + c0 + tx];
    }
    __syncthreads();
    #pragma unroll
    for (int i = 0; i < 4; i++) {
        int c = ty + i * 8;
        dst[(size_t)(c0 + c) * R + r0 + tx] = __float2bfloat16(tile[tx][c]);
    }
}

// ---------------------------------------------------------------- router (per-token top2)
__global__ void router_kernel(const float* __restrict__ hn, const float* __restrict__ rw,
                              int* __restrict__ cnt, int* __restrict__ topEk,
                              float* __restrict__ topW) {
    int t = blockIdx.x;
    int lane = threadIdx.x;   // 64 = 1 wave
    float acc[NEXP];
    #pragma unroll
    for (int e = 0; e < NEXP; e++) acc[e] = 0.f;
    const float* row = hn + (size_t)t * HS;
    for (int kk = lane; kk < HS; kk += 64) {
        float xv = row[kk];
        const float* r = rw + (size_t)kk * NEXP;
        #pragma unroll
        for (int e = 0; e < NEXP; e++) acc[e] += xv * r[e];
    }
    #pragma unroll
    for (int e = 0; e < NEXP; e++)
        for (int off = 32; off > 0; off >>= 1) acc[e] += __shfl_down(acc[e], off);
    if (lane == 0) {
        float mx = acc[0];
        #pragma unroll
        for (int e = 1; e < NEXP; e++) mx = fmaxf(mx, acc[e]);
        float p[NEXP]; float s = 0.f;
        #pragma unroll
        for (int e = 0; e < NEXP; e++) { p[e] = __expf(acc[e] - mx); s += p[e]; }
        int i0 = 0;
        #pragma unroll
        for (int e = 1; e < NEXP; e++) if (p[e] > p[i0]) i0 = e;
        int i1 = (i0 == 0) ? 1 : 0;
        #pragma unroll
        for (int e = 0; e < NEXP; e++) if (e != i0 && p[e] > p[i1]) i1 = e;
        float v0 = p[i0], v1 = p[i1], sn = v0 + v1;
        topEk[2 * t]     = i0; topW[2 * t]     = v0 / sn;
        topEk[2 * t + 1] = i1; topW[2 * t + 1] = v1 / sn;
        atomicAdd(&cnt[i0], 1);
        atomicAdd(&cnt[i1], 1);
    }
}

__global__ void offsets_kernel(const int* __restrict__ cnt, int* __restrict__ off) {
    if (threadIdx.x == 0) {
        int o = 0;
        for (int e = 0; e < NEXP; e++) { off[e] = o; o += cnt[e]; }
    }
}

__global__ void scatter_kernel(const int* __restrict__ topEk, int* __restrict__ fill,
                               const int* __restrict__ off, const float* __restrict__ topW,
                               int* __restrict__ tok_list, float* __restrict__ wA) {
    int idx = blockIdx.x * 256 + threadIdx.x;   // NASSIGN
    int e = topEk[idx];
    int slot = atomicAdd(&fill[e], 1);
    int gidx = off[e] + slot;
    tok_list[gidx] = idx >> 1;
    wA[gidx] = topW[idx];
}

// ---------------------------------------------------------------- MoE up-proj, bf16 MFMA
// g[row,:] = silu(hn@w1) * (hn@w3), rows gathered. 128x128 tile, BK=32.
__global__ __launch_bounds__(256) void moe_up_mfma(const __hip_bfloat16* __restrict__ Abf,
                                                   const __hip_bfloat16* __restrict__ B1T,
                                                   const __hip_bfloat16* __restrict__ B3T,
                                                   __hip_bfloat16* __restrict__ g,
                                                   const int* __restrict__ cnt,
                                                   const int* __restrict__ off,
                                                   const int* __restrict__ tok_list) {
    int e = blockIdx.z;
    int ce = cnt[e];
    int bm = blockIdx.y * 128;
    if (bm >= ce) return;
    int oe = off[e];
    int bn = blockIdx.x * 128;
    const __hip_bfloat16* b1 = B1T + (size_t)e * IS * HS;   // [IS][HS]
    const __hip_bfloat16* b3 = B3T + (size_t)e * IS * HS;

    __shared__ __align__(16) short As[128][40];
    __shared__ __align__(16) short B1s[128][40];
    __shared__ __align__(16) short B3s[128][40];
    __shared__ int toks[128];

    int t = threadIdx.x;
    int wave = t >> 6, lane = t & 63;
    int wm = (wave & 1) * 64, wn = (wave >> 1) * 64;
    int fr = lane & 15;
    int kh = (lane >> 4) * 8;

    if (t < 128) {
        int gidx = oe + bm + t;
        if (gidx > NASSIGN - 1) gidx = NASSIGN - 1;
        toks[t] = tok_list[gidx];
    }
    __syncthreads();
    int srow = t >> 2;            // 0..63
    int scol = (t & 3) * 8;       // bf16 elems
    const __hip_bfloat16* rowA0 = Abf + (size_t)toks[srow] * HS + scol;
    const __hip_bfloat16* rowA1 = Abf + (size_t)toks[64 + srow] * HS + scol;
    const __hip_bfloat16* rowB1a = b1 + (size_t)(bn + srow) * HS + scol;
    const __hip_bfloat16* rowB1b = b1 + (size_t)(bn + 64 + srow) * HS + scol;
    const __hip_bfloat16* rowB3a = b3 + (size_t)(bn + srow) * HS + scol;
    const __hip_bfloat16* rowB3b = b3 + (size_t)(bn + 64 + srow) * HS + scol;

    f32x4 acc1[4][4] = {};
    f32x4 acc3[4][4] = {};

    for (int k0 = 0; k0 < HS; k0 += 32) {
        *(uint4*)&As[srow][scol]       = *(const uint4*)(rowA0 + k0);
        *(uint4*)&As[64 + srow][scol]  = *(const uint4*)(rowA1 + k0);
        *(uint4*)&B1s[srow][scol]      = *(const uint4*)(rowB1a + k0);
        *(uint4*)&B1s[64 + srow][scol] = *(const uint4*)(rowB1b + k0);
        *(uint4*)&B3s[srow][scol]      = *(const uint4*)(rowB3a + k0);
        *(uint4*)&B3s[64 + srow][scol] = *(const uint4*)(rowB3b + k0);
        __syncthreads();
        bf16x8 a[4], f1[4], f3[4];
        #pragma unroll
        for (int i = 0; i < 4; i++) {
            a[i]  = *(const bf16x8*)&As[wm + i * 16 + fr][kh];
            f1[i] = *(const bf16x8*)&B1s[wn + i * 16 + fr][kh];
            f3[i] = *(const bf16x8*)&B3s[wn + i * 16 + fr][kh];
        }
        #pragma unroll
        for (int mi = 0; mi < 4; mi++)
            #pragma unroll
            for (int ni = 0; ni < 4; ni++) {
                acc1[mi][ni] = __builtin_amdgcn_mfma_f32_16x16x32_bf16(a[mi], f1[ni], acc1[mi][ni], 0, 0, 0);
                acc3[mi][ni] = __builtin_amdgcn_mfma_f32_16x16x32_bf16(a[mi], f3[ni], acc3[mi][ni], 0, 0, 0);
            }
        __syncthreads();
    }
    // epilogue: C row = (lane>>4)*4 + reg, col = lane&15
    int rq = (lane >> 4) * 4;
    #pragma unroll
    for (int mi = 0; mi < 4; mi++) {
        #pragma unroll
        for (int r = 0; r < 4; r++) {
            int slot = bm + wm + mi * 16 + rq + r;
            if (slot < ce) {
                size_t rowo = (size_t)(oe + slot) * IS + bn + wn;
                #pragma unroll
                for (int ni = 0; ni < 4; ni++) {
                    float x1 = acc1[mi][ni][r];
                    float x3 = acc3[mi][ni][r];
                    float sv = (x1 / (1.f + __expf(-x1))) * x3;
                    g[rowo + ni * 16 + (lane & 15)] = __float2bfloat16(sv);
                }
            }
        }
    }
}

// ---------------------------------------------------------------- MoE down-proj, bf16 MFMA, fused combine+residual
__global__ __launch_bounds__(256) void moe_down_mfma(const __hip_bfloat16* __restrict__ g,
                                                     const __hip_bfloat16* __restrict__ B2T,
                                                     float* __restrict__ out,
                                                     const int* __restrict__ cnt,
                                                     const int* __restrict__ off,
                                                     const int* __restrict__ tok_list,
                                                     const float* __restrict__ wA) {
    int e = blockIdx.z;
    int ce = cnt[e];
    int bm = blockIdx.y * 128;
    if (bm >= ce) return;
    int oe = off[e];
    int bn = blockIdx.x * 128;
    const __hip_bfloat16* b2 = B2T + (size_t)e * HS * IS;   // [HS][IS]

    __shared__ __align__(16) short As[128][40];
    __shared__ __align__(16) short Bs[128][40];

    int t = threadIdx.x;
    int wave = t >> 6, lane = t & 63;
    int wm = (wave & 1) * 64, wn = (wave >> 1) * 64;
    int fr = lane & 15;
    int kh = (lane >> 4) * 8;

    int srow = t >> 2;
    int scol = (t & 3) * 8;
    int ga0 = oe + bm + srow;       if (ga0 > NASSIGN - 1) ga0 = NASSIGN - 1;
    int ga1 = oe + bm + 64 + srow;  if (ga1 > NASSIGN - 1) ga1 = NASSIGN - 1;
    const __hip_bfloat16* rowA0 = g + (size_t)ga0 * IS + scol;
    const __hip_bfloat16* rowA1 = g + (size_t)ga1 * IS + scol;
    const __hip_bfloat16* rowBa = b2 + (size_t)(bn + srow) * IS + scol;
    const __hip_bfloat16* rowBb = b2 + (size_t)(bn + 64 + srow) * IS + scol;

    f32x4 acc[4][4] = {};

    for (int k0 = 0; k0 < IS; k0 += 32) {
        *(uint4*)&As[srow][scol]      = *(const uint4*)(rowA0 + k0);
        *(uint4*)&As[64 + srow][scol] = *(const uint4*)(rowA1 + k0);
        *(uint4*)&Bs[srow][scol]      = *(const uint4*)(rowBa + k0);
        *(uint4*)&Bs[64 + srow][scol] = *(const uint4*)(rowBb + k0);
        __syncthreads();
        bf16x8 a[4], f[4];
        #pragma unroll
        for (int i = 0; i < 4; i++) {
            a[i] = *(const bf16x8*)&As[wm + i * 16 + fr][kh];
            f[i] = *(const bf16x8*)&Bs[wn + i * 16 + fr][kh];
        }
        #pragma unroll
        for (int mi = 0; mi < 4; mi++)
            #pragma unroll
            for (int ni = 0; ni < 4; ni++)
                acc[mi][ni] = __builtin_amdgcn_mfma_f32_16x16x32_bf16(a[mi], f[ni], acc[mi][ni], 0, 0, 0);
        __syncthreads();
    }
    int rq = (lane >> 4) * 4;
    #pragma unroll
    for (int mi = 0; mi < 4; mi++) {
        #pragma unroll
        for (int r = 0; r < 4; r++) {
            int slot = bm + wm + mi * 16 + rq + r;
            if (slot < ce) {
                int gidx = oe + slot;
                int tok = tok_list[gidx];
                float wgt = wA[gidx];
                size_t rowo = (size_t)tok * HS + bn + wn;
                #pragma unroll
                for (int ni = 0; ni < 4; ni++)
                    atomicAdd(out + rowo + ni * 16 + (lane & 15), wgt * acc[mi][ni][r]);
            }
        }
    }
}

// ---------------------------------------------------------------- launch
extern "C" void kernel_launch(void* const* d_in, const int* in_sizes, int n_in,
                              void* d_out, int out_size, void* d_ws, size_t ws_size,
                              hipStream_t stream) {
    const float* x   = (const float*)d_in[0];
    const float* anw = (const float*)d_in[1];
    const float* fnw = (const float*)d_in[2];
    const float* wq  = (const float*)d_in[3];
    const float* wk  = (const float*)d_in[4];
    const float* wv  = (const float*)d_in[5];
    const float* wo  = (const float*)d_in[6];
    const float* rw  = (const float*)d_in[7];
    const float* w1  = (const float*)d_in[8];
    const float* w3  = (const float*)d_in[9];
    const float* w2  = (const float*)d_in[10];
    const float* fc  = (const float*)d_in[11];
    float* out = (float*)d_out;

    char* ws = (char*)d_ws;
    const size_t MB = 1024 * 1024;
    // Phase A (fp32): xn[0,8) qb[8,16) kb[16,24) vb[24,32) ctx[32,40)
    float* xn  = (float*)(ws + 0 * MB);
    float* qb  = (float*)(ws + 8 * MB);
    float* kb  = (float*)(ws + 16 * MB);
    float* vb  = (float*)(ws + 24 * MB);
    float* ctx = (float*)(ws + 32 * MB);
    // Phase B overlay: hn[0,8) hn_bf[8,12) w1T[12,44) w3T[44,76) w2T[76,108) g[108,124) ints[124,..)
    float*          hn    = (float*)(ws + 0 * MB);
    __hip_bfloat16* hn_bf = (__hip_bfloat16*)(ws + 8 * MB);
    __hip_bfloat16* w1T   = (__hip_bfloat16*)(ws + 12 * MB);
    __hip_bfloat16* w3T   = (__hip_bfloat16*)(ws + 44 * MB);
    __hip_bfloat16* w2T   = (__hip_bfloat16*)(ws + 76 * MB);
    __hip_bfloat16* gact  = (__hip_bfloat16*)(ws + 108 * MB);
    int* ibase    = (int*)(ws + 124 * MB);
    int* cnt      = ibase;
    int* fill     = ibase + 8;
    int* off      = ibase + 16;
    int* topEk    = ibase + 32;                       // 4096
    int* tok_list = ibase + 32 + NASSIGN;             // 4096
    float* topW   = (float*)(ibase + 32 + 2 * NASSIGN);
    float* wA     = (float*)(ibase + 32 + 3 * NASSIGN);

    // ---- attention half (fp32 — keeps router inputs at fp32 accuracy) ----
    rmsnorm_kernel<<<NTOK, 256, 0, stream>>>(x, anw, xn);
    dim3 gqkv(HS / 64, NTOK / 64);
    gemm_f32<<<gqkv, 256, 0, stream>>>(xn, wq, qb, NTOK, HS, HS);
    gemm_f32<<<gqkv, 256, 0, stream>>>(xn, wk, kb, NTOK, HS, HS);
    gemm_f32<<<gqkv, 256, 0, stream>>>(xn, wv, vb, NTOK, HS, HS);
    rope_kernel<<<(NTOK * NHEAD * (HDIM / 2)) / 256, 256, 0, stream>>>(qb, kb, fc);
    dim3 ga(SEQ / 64, NHEAD, BATCH);
    attn_flash<<<ga, 256, 0, stream>>>(qb, kb, vb, ctx);
    gemm_f32_res<<<gqkv, 256, 0, stream>>>(ctx, wo, x, out, NTOK, HS, HS);   // out = h

    // ---- MoE half (routed top-2, bf16 MFMA experts) ----
    rmsnorm_dual<<<NTOK, 256, 0, stream>>>(out, fnw, hn, hn_bf);
    // weight transposes fp32[K][N] -> bf16[N][K] (after phase-A buffers are dead)
    transpose_bf16<<<dim3(IS / 32, HS / 32, NEXP), 256, 0, stream>>>(w1, w1T, HS, IS);
    transpose_bf16<<<dim3(IS / 32, HS / 32, NEXP), 256, 0, stream>>>(w3, w3T, HS, IS);
    transpose_bf16<<<dim3(HS / 32, IS / 32, NEXP), 256, 0, stream>>>(w2, w2T, IS, HS);

    hipMemsetAsync(cnt, 0, 16 * sizeof(int), stream);   // cnt + fill
    router_kernel<<<NTOK, 64, 0, stream>>>(hn, rw, cnt, topEk, topW);
    offsets_kernel<<<1, 64, 0, stream>>>(cnt, off);
    scatter_kernel<<<NASSIGN / 256, 256, 0, stream>>>(topEk, fill, off, topW, tok_list, wA);

    dim3 gup(IS / 128, NASSIGN / 128, NEXP);
    moe_up_mfma<<<gup, 256, 0, stream>>>(hn_bf, w1T, w3T, gact, cnt, off, tok_list);
    dim3 gdn(HS / 128, NASSIGN / 128, NEXP);
    moe_down_mfma<<<gdn, 256, 0, stream>>>(gact, w2T, out, cnt, off, tok_list, wA);
}

// Round 4
// 820.382 us; speedup vs baseline: 5.6096x; 1.2081x over previous
//
#include <hip/hip_runtime.h>
#include <hip/hip_bf16.h>
#include <math.h>

#define HS 1024      // hidden size
#define IS 2048      // intermediate size
#define NHEAD 16
#define HDIM 64
#define NEXP 8
#define BATCH 2
#define SEQ 1024
#define NTOK (BATCH*SEQ)     // 2048 tokens
#define NASSIGN (NTOK*2)     // 4096 (token, expert) assignments
#define QKVW 3072            // fused qkv row width

typedef short bf16x8 __attribute__((ext_vector_type(8)));
typedef float f32x4  __attribute__((ext_vector_type(4)));

// ---------------------------------------------------------------- rmsnorm -> split bf16 (hi+lo)
__global__ void rmsnorm_split(const float* __restrict__ x, const float* __restrict__ w,
                              __hip_bfloat16* __restrict__ oh, __hip_bfloat16* __restrict__ ol) {
    int t = blockIdx.x;
    int tid = threadIdx.x;
    const float* row = x + (size_t)t * HS;
    float ss = 0.f;
    for (int i = tid; i < HS; i += 256) { float v = row[i]; ss += v * v; }
    for (int off = 32; off > 0; off >>= 1) ss += __shfl_down(ss, off);
    __shared__ float red[4];
    if ((tid & 63) == 0) red[tid >> 6] = ss;
    __syncthreads();
    float tot = red[0] + red[1] + red[2] + red[3];
    float rr = rsqrtf(tot / (float)HS + 1e-6f);
    for (int i = tid; i < HS; i += 256) {
        float v = w[i] * row[i] * rr;
        __hip_bfloat16 hi = __float2bfloat16(v);
        oh[(size_t)t * HS + i] = hi;
        ol[(size_t)t * HS + i] = __float2bfloat16(v - __bfloat162float(hi));
    }
}

// ---------------------------------------------------------------- rmsnorm dual (fp32 + bf16)
__global__ void rmsnorm_dual(const float* __restrict__ x, const float* __restrict__ w,
                             float* __restrict__ outf, __hip_bfloat16* __restrict__ outb) {
    int t = blockIdx.x;
    int tid = threadIdx.x;
    const float* row = x + (size_t)t * HS;
    float ss = 0.f;
    for (int i = tid; i < HS; i += 256) { float v = row[i]; ss += v * v; }
    for (int off = 32; off > 0; off >>= 1) ss += __shfl_down(ss, off);
    __shared__ float red[4];
    if ((tid & 63) == 0) red[tid >> 6] = ss;
    __syncthreads();
    float tot = red[0] + red[1] + red[2] + red[3];
    float rr = rsqrtf(tot / (float)HS + 1e-6f);
    for (int i = tid; i < HS; i += 256) {
        float v = w[i] * row[i] * rr;
        outf[(size_t)t * HS + i] = v;
        outb[(size_t)t * HS + i] = __float2bfloat16(v);
    }
}

// ---------------------------------------------------------------- transpose fp32 [R][C] -> split bf16 [C][R]
// dst row (rowOff + c) has stride R
__global__ void transpose_split(const float* __restrict__ src,
                                __hip_bfloat16* __restrict__ dh, __hip_bfloat16* __restrict__ dl,
                                int R, int C, int rowOff) {
    __shared__ float tile[32][33];
    int c0 = blockIdx.x * 32, r0 = blockIdx.y * 32;
    int tx = threadIdx.x & 31, ty = threadIdx.x >> 5;  // 0..7
    #pragma unroll
    for (int i = 0; i < 4; i++) {
        int r = ty + i * 8;
        tile[r][tx] = src[(size_t)(r0 + r) * C + c0 + tx];
    }
    __syncthreads();
    #pragma unroll
    for (int i = 0; i < 4; i++) {
        int c = ty + i * 8;
        float v = tile[tx][c];
        __hip_bfloat16 hi = __float2bfloat16(v);
        size_t o = (size_t)(rowOff + c0 + c) * R + r0 + tx;
        dh[o] = hi;
        dl[o] = __float2bfloat16(v - __bfloat162float(hi));
    }
}

// ---------------------------------------------------------------- transpose fp32 [R][C] -> bf16 [C][R], per expert z
__global__ void transpose_bf16(const float* __restrict__ in, __hip_bfloat16* __restrict__ outp,
                               int R, int C) {
    __shared__ float tile[32][33];
    int e = blockIdx.z;
    const float* src = in + (size_t)e * R * C;
    __hip_bfloat16* dst = outp + (size_t)e * R * C;
    int c0 = blockIdx.x * 32, r0 = blockIdx.y * 32;
    int tx = threadIdx.x & 31, ty = threadIdx.x >> 5;
    #pragma unroll
    for (int i = 0; i < 4; i++) {
        int r = ty + i * 8;
        tile[r][tx] = src[(size_t)(r0 + r) * C + c0 + tx];
    }
    __syncthreads();
    #pragma unroll
    for (int i = 0; i < 4; i++) {
        int c = ty + i * 8;
        dst[(size_t)(c0 + c) * R + r0 + tx] = __float2bfloat16(tile[tx][c]);
    }
}

// ---------------------------------------------------------------- split-bf16 GEMM (fp32-grade precision)
// C[M][N] = (Ah+Al)[M][K] @ (Bh+Bl)[N][K]^T (+ resid), via Ah@Bh + Ah@Bl + Al@Bh
__global__ __launch_bounds__(256) void gemm_bf16x3(const __hip_bfloat16* __restrict__ Ah,
                                                   const __hip_bfloat16* __restrict__ Al,
                                                   const __hip_bfloat16* __restrict__ Bh,
                                                   const __hip_bfloat16* __restrict__ Bl,
                                                   const float* __restrict__ resid,
                                                   float* __restrict__ C,
                                                   int M, int N, int K) {
    __shared__ __align__(16) short Ahs[128][40];
    __shared__ __align__(16) short Als[128][40];
    __shared__ __align__(16) short Bhs[128][40];
    __shared__ __align__(16) short Bls[128][40];
    int bm = blockIdx.y * 128, bn = blockIdx.x * 128;
    int t = threadIdx.x;
    int wave = t >> 6, lane = t & 63;
    int wm = (wave & 1) * 64, wn = (wave >> 1) * 64;
    int fr = lane & 15;
    int kh = (lane >> 4) * 8;
    int srow = t >> 2;            // 0..63
    int scol = (t & 3) * 8;
    const __hip_bfloat16* a0h = Ah + (size_t)(bm + srow) * K + scol;
    const __hip_bfloat16* a1h = Ah + (size_t)(bm + 64 + srow) * K + scol;
    const __hip_bfloat16* a0l = Al + (size_t)(bm + srow) * K + scol;
    const __hip_bfloat16* a1l = Al + (size_t)(bm + 64 + srow) * K + scol;
    const __hip_bfloat16* b0h = Bh + (size_t)(bn + srow) * K + scol;
    const __hip_bfloat16* b1h = Bh + (size_t)(bn + 64 + srow) * K + scol;
    const __hip_bfloat16* b0l = Bl + (size_t)(bn + srow) * K + scol;
    const __hip_bfloat16* b1l = Bl + (size_t)(bn + 64 + srow) * K + scol;

    f32x4 acc[4][4] = {};
    for (int k0 = 0; k0 < K; k0 += 32) {
        *(uint4*)&Ahs[srow][scol]      = *(const uint4*)(a0h + k0);
        *(uint4*)&Ahs[64 + srow][scol] = *(const uint4*)(a1h + k0);
        *(uint4*)&Als[srow][scol]      = *(const uint4*)(a0l + k0);
        *(uint4*)&Als[64 + srow][scol] = *(const uint4*)(a1l + k0);
        *(uint4*)&Bhs[srow][scol]      = *(const uint4*)(b0h + k0);
        *(uint4*)&Bhs[64 + srow][scol] = *(const uint4*)(b1h + k0);
        *(uint4*)&Bls[srow][scol]      = *(const uint4*)(b0l + k0);
        *(uint4*)&Bls[64 + srow][scol] = *(const uint4*)(b1l + k0);
        __syncthreads();
        bf16x8 ah[4], bh[4], x[4];
        #pragma unroll
        for (int i = 0; i < 4; i++) {
            ah[i] = *(const bf16x8*)&Ahs[wm + i * 16 + fr][kh];
            bh[i] = *(const bf16x8*)&Bhs[wn + i * 16 + fr][kh];
        }
        #pragma unroll
        for (int mi = 0; mi < 4; mi++)
            #pragma unroll
            for (int ni = 0; ni < 4; ni++)
                acc[mi][ni] = __builtin_amdgcn_mfma_f32_16x16x32_bf16(ah[mi], bh[ni], acc[mi][ni], 0, 0, 0);
        #pragma unroll
        for (int i = 0; i < 4; i++) x[i] = *(const bf16x8*)&Bls[wn + i * 16 + fr][kh];
        #pragma unroll
        for (int mi = 0; mi < 4; mi++)
            #pragma unroll
            for (int ni = 0; ni < 4; ni++)
                acc[mi][ni] = __builtin_amdgcn_mfma_f32_16x16x32_bf16(ah[mi], x[ni], acc[mi][ni], 0, 0, 0);
        #pragma unroll
        for (int i = 0; i < 4; i++) x[i] = *(const bf16x8*)&Als[wm + i * 16 + fr][kh];
        #pragma unroll
        for (int mi = 0; mi < 4; mi++)
            #pragma unroll
            for (int ni = 0; ni < 4; ni++)
                acc[mi][ni] = __builtin_amdgcn_mfma_f32_16x16x32_bf16(x[mi], bh[ni], acc[mi][ni], 0, 0, 0);
        __syncthreads();
    }
    int rq = (lane >> 4) * 4;
    #pragma unroll
    for (int mi = 0; mi < 4; mi++) {
        #pragma unroll
        for (int r = 0; r < 4; r++) {
            size_t rowo = (size_t)(bm + wm + mi * 16 + rq + r) * N + bn + wn;
            #pragma unroll
            for (int ni = 0; ni < 4; ni++) {
                float v = acc[mi][ni][r];
                size_t o = rowo + ni * 16 + fr;
                if (resid) v += resid[o];
                C[o] = v;
            }
        }
    }
}

// ---------------------------------------------------------------- RoPE (in-place on fused qkv)
__global__ void rope_kernel(float* __restrict__ qkv, const float* __restrict__ fc) {
    int idx = blockIdx.x * 256 + threadIdx.x;   // NTOK*NHEAD*32
    int j    = idx & 31;
    int rest = idx >> 5;
    int h = rest & (NHEAD - 1);
    int t = rest >> 4;
    int s = t & (SEQ - 1);
    float cr = fc[s * HDIM + 2 * j];
    float ci = fc[s * HDIM + 2 * j + 1];
    size_t base = (size_t)t * QKVW + h * HDIM + 2 * j;   // q
    float a = qkv[base], b = qkv[base + 1];
    qkv[base]     = a * cr - b * ci;
    qkv[base + 1] = a * ci + b * cr;
    a = qkv[base + 1024]; b = qkv[base + 1025];          // k
    qkv[base + 1024] = a * cr - b * ci;
    qkv[base + 1025] = a * ci + b * cr;
}

// ---------------------------------------------------------------- split-K flash attention: partials
// grid: x=chunk(4), y=qt(16), z=b*16+h(32). Chunk covers k-tiles [4c, min(4c+4,qt+1)).
__global__ __launch_bounds__(256) void attn_partial(const float* __restrict__ qkv,
                                                    float* __restrict__ po,
                                                    float* __restrict__ pm,
                                                    float* __restrict__ pl) {
    int c  = blockIdx.x;
    int qt = blockIdx.y;
    int nc = (qt + 4) >> 2;
    if (c >= nc) return;
    int bh = blockIdx.z;
    int b = bh >> 4, h = bh & 15;
    int t0 = c * 4;
    int t1 = min(t0 + 4, qt + 1);
    int tid = threadIdx.x;
    int tx = tid & 15, ty = tid >> 4;
    __shared__ float Qs[64][68];   // [d][q]
    __shared__ float KV[64][68];
    __shared__ float Ps[64][68];
    const int qbase = qt * 64;
    const float* qp = qkv + (size_t)(b * SEQ + qbase) * QKVW + h * HDIM;

    #pragma unroll
    for (int it = 0; it < 4; it++) {
        int idx = it * 256 + tid;
        int r = idx >> 4, g = idx & 15;
        float4 qv = *(const float4*)(qp + (size_t)r * QKVW + g * 4);
        Qs[g * 4 + 0][r] = qv.x; Qs[g * 4 + 1][r] = qv.y;
        Qs[g * 4 + 2][r] = qv.z; Qs[g * 4 + 3][r] = qv.w;
    }

    float o[4][4] = {};
    float m[4], l[4];
    #pragma unroll
    for (int i = 0; i < 4; i++) { m[i] = -1e30f; l[i] = 0.f; }

    for (int kt = t0; kt < t1; kt++) {
        const float* kp = qkv + (size_t)(b * SEQ + kt * 64) * QKVW + 1024 + h * HDIM;
        const float* vp = kp + 1024;
        __syncthreads();
        #pragma unroll
        for (int it = 0; it < 4; it++) {
            int idx = it * 256 + tid;
            int r = idx >> 4, g = idx & 15;
            float4 kv4 = *(const float4*)(kp + (size_t)r * QKVW + g * 4);
            KV[g * 4 + 0][r] = kv4.x; KV[g * 4 + 1][r] = kv4.y;
            KV[g * 4 + 2][r] = kv4.z; KV[g * 4 + 3][r] = kv4.w;
        }
        __syncthreads();

        float s[4][4] = {};
        #pragma unroll 8
        for (int kk = 0; kk < 64; kk++) {
            float4 av = *(const float4*)&Qs[kk][ty * 4];
            float4 bv = *(const float4*)&KV[kk][tx * 4];
            float a[4] = {av.x, av.y, av.z, av.w};
            float bb[4] = {bv.x, bv.y, bv.z, bv.w};
            #pragma unroll
            for (int i = 0; i < 4; i++)
                #pragma unroll
                for (int j = 0; j < 4; j++) s[i][j] += a[i] * bb[j];
        }
        if (kt == qt) {
            #pragma unroll
            for (int i = 0; i < 4; i++)
                #pragma unroll
                for (int j = 0; j < 4; j++)
                    s[i][j] = (tx * 4 + j > ty * 4 + i) ? -1e9f : s[i][j] * 0.125f;
        } else {
            #pragma unroll
            for (int i = 0; i < 4; i++)
                #pragma unroll
                for (int j = 0; j < 4; j++) s[i][j] *= 0.125f;
        }
        #pragma unroll
        for (int i = 0; i < 4; i++) {
            float mx = fmaxf(fmaxf(s[i][0], s[i][1]), fmaxf(s[i][2], s[i][3]));
            #pragma unroll
            for (int w = 1; w < 16; w <<= 1) mx = fmaxf(mx, __shfl_xor(mx, w));
            float nm = fmaxf(m[i], mx);
            float alpha = __expf(m[i] - nm);
            float rs = 0.f;
            #pragma unroll
            for (int j = 0; j < 4; j++) { s[i][j] = __expf(s[i][j] - nm); rs += s[i][j]; }
            #pragma unroll
            for (int w = 1; w < 16; w <<= 1) rs += __shfl_xor(rs, w);
            l[i] = l[i] * alpha + rs;
            m[i] = nm;
            #pragma unroll
            for (int j = 0; j < 4; j++) o[i][j] *= alpha;
        }
        __syncthreads();
        #pragma unroll
        for (int it = 0; it < 4; it++) {
            int idx = it * 256 + tid;
            int r = idx >> 4, g = idx & 15;
            *(float4*)&KV[r][g * 4] = *(const float4*)(vp + (size_t)r * QKVW + g * 4);
        }
        #pragma unroll
        for (int i = 0; i < 4; i++)
            *(float4*)&Ps[ty * 4 + i][tx * 4] = make_float4(s[i][0], s[i][1], s[i][2], s[i][3]);
        __syncthreads();
        #pragma unroll 8
        for (int kk = 0; kk < 64; kk++) {
            float4 bv = *(const float4*)&KV[kk][tx * 4];
            #pragma unroll
            for (int i = 0; i < 4; i++) {
                float a = Ps[ty * 4 + i][kk];
                o[i][0] += a * bv.x; o[i][1] += a * bv.y;
                o[i][2] += a * bv.z; o[i][3] += a * bv.w;
            }
        }
    }
    int pidx = (bh * 16 + qt) * 4 + c;
    float* pob = po + (size_t)pidx * 4096;
    #pragma unroll
    for (int i = 0; i < 4; i++)
        *(float4*)(pob + (ty * 4 + i) * 64 + tx * 4) = make_float4(o[i][0], o[i][1], o[i][2], o[i][3]);
    if (tx == 0) {
        #pragma unroll
        for (int i = 0; i < 4; i++) {
            pm[pidx * 64 + ty * 4 + i] = m[i];
            pl[pidx * 64 + ty * 4 + i] = l[i];
        }
    }
}

// ---------------------------------------------------------------- merge partials -> ctx as split bf16
__global__ void attn_merge(const float* __restrict__ po, const float* __restrict__ pm,
                           const float* __restrict__ pl,
                           __hip_bfloat16* __restrict__ ch, __hip_bfloat16* __restrict__ cl) {
    int qt = blockIdx.x, h = blockIdx.y, b = blockIdx.z;
    int bh = b * 16 + h;
    int nc = (qt + 4) >> 2;
    int base = (bh * 16 + qt) * 4;
    int tid = threadIdx.x;
    int r  = tid >> 2;          // 0..63
    int d0 = (tid & 3) * 16;
    float mstar = -1e30f;
    for (int c = 0; c < nc; c++) mstar = fmaxf(mstar, pm[(base + c) * 64 + r]);
    float a[4];
    float lsum = 0.f;
    for (int c = 0; c < nc; c++) {
        a[c] = __expf(pm[(base + c) * 64 + r] - mstar);
        lsum += a[c] * pl[(base + c) * 64 + r];
    }
    float inv = 1.f / lsum;
    size_t crow = (size_t)(b * SEQ + qt * 64 + r) * HS + h * HDIM;
    for (int dd = 0; dd < 16; dd += 4) {
        float4 acc = make_float4(0.f, 0.f, 0.f, 0.f);
        for (int c = 0; c < nc; c++) {
            float4 v = *(const float4*)(po + (size_t)(base + c) * 4096 + r * 64 + d0 + dd);
            acc.x += a[c] * v.x; acc.y += a[c] * v.y;
            acc.z += a[c] * v.z; acc.w += a[c] * v.w;
        }
        float vs[4] = {acc.x * inv, acc.y * inv, acc.z * inv, acc.w * inv};
        #pragma unroll
        for (int j = 0; j < 4; j++) {
            __hip_bfloat16 hi = __float2bfloat16(vs[j]);
            ch[crow + d0 + dd + j] = hi;
            cl[crow + d0 + dd + j] = __float2bfloat16(vs[j] - __bfloat162float(hi));
        }
    }
}

// ---------------------------------------------------------------- router (per-token top2)
__global__ void router_kernel(const float* __restrict__ hn, const float* __restrict__ rw,
                              int* __restrict__ cnt, int* __restrict__ topEk,
                              float* __restrict__ topW) {
    int t = blockIdx.x;
    int lane = threadIdx.x;   // 64 = 1 wave
    float acc[NEXP];
    #pragma unroll
    for (int e = 0; e < NEXP; e++) acc[e] = 0.f;
    const float* row = hn + (size_t)t * HS;
    for (int kk = lane; kk < HS; kk += 64) {
        float xv = row[kk];
        const float* r = rw + (size_t)kk * NEXP;
        #pragma unroll
        for (int e = 0; e < NEXP; e++) acc[e] += xv * r[e];
    }
    #pragma unroll
    for (int e = 0; e < NEXP; e++)
        for (int off = 32; off > 0; off >>= 1) acc[e] += __shfl_down(acc[e], off);
    if (lane == 0) {
        float mx = acc[0];
        #pragma unroll
        for (int e = 1; e < NEXP; e++) mx = fmaxf(mx, acc[e]);
        float p[NEXP]; float s = 0.f;
        #pragma unroll
        for (int e = 0; e < NEXP; e++) { p[e] = __expf(acc[e] - mx); s += p[e]; }
        int i0 = 0;
        #pragma unroll
        for (int e = 1; e < NEXP; e++) if (p[e] > p[i0]) i0 = e;
        int i1 = (i0 == 0) ? 1 : 0;
        #pragma unroll
        for (int e = 0; e < NEXP; e++) if (e != i0 && p[e] > p[i1]) i1 = e;
        float v0 = p[i0], v1 = p[i1], sn = v0 + v1;
        topEk[2 * t]     = i0; topW[2 * t]     = v0 / sn;
        topEk[2 * t + 1] = i1; topW[2 * t + 1] = v1 / sn;
        atomicAdd(&cnt[i0], 1);
        atomicAdd(&cnt[i1], 1);
    }
}

__global__ void offsets_kernel(const int* __restrict__ cnt, int* __restrict__ off) {
    if (threadIdx.x == 0) {
        int o = 0;
        for (int e = 0; e < NEXP; e++) { off[e] = o; o += cnt[e]; }
    }
}

__global__ void scatter_kernel(const int* __restrict__ topEk, int* __restrict__ fill,
                               const int* __restrict__ off, const float* __restrict__ topW,
                               int* __restrict__ tok_list, float* __restrict__ wA) {
    int idx = blockIdx.x * 256 + threadIdx.x;   // NASSIGN
    int e = topEk[idx];
    int slot = atomicAdd(&fill[e], 1);
    int gidx = off[e] + slot;
    tok_list[gidx] = idx >> 1;
    wA[gidx] = topW[idx];
}

// ---------------------------------------------------------------- MoE up-proj, bf16 MFMA
__global__ __launch_bounds__(256) void moe_up_mfma(const __hip_bfloat16* __restrict__ Abf,
                                                   const __hip_bfloat16* __restrict__ B1T,
                                                   const __hip_bfloat16* __restrict__ B3T,
                                                   __hip_bfloat16* __restrict__ g,
                                                   const int* __restrict__ cnt,
                                                   const int* __restrict__ off,
                                                   const int* __restrict__ tok_list) {
    int e = blockIdx.z;
    int ce = cnt[e];
    int bm = blockIdx.y * 128;
    if (bm >= ce) return;
    int oe = off[e];
    int bn = blockIdx.x * 128;
    const __hip_bfloat16* b1 = B1T + (size_t)e * IS * HS;   // [IS][HS]
    const __hip_bfloat16* b3 = B3T + (size_t)e * IS * HS;

    __shared__ __align__(16) short As[128][40];
    __shared__ __align__(16) short B1s[128][40];
    __shared__ __align__(16) short B3s[128][40];
    __shared__ int toks[128];

    int t = threadIdx.x;
    int wave = t >> 6, lane = t & 63;
    int wm = (wave & 1) * 64, wn = (wave >> 1) * 64;
    int fr = lane & 15;
    int kh = (lane >> 4) * 8;

    if (t < 128) {
        int gidx = oe + bm + t;
        if (gidx > NASSIGN - 1) gidx = NASSIGN - 1;
        toks[t] = tok_list[gidx];
    }
    __syncthreads();
    int srow = t >> 2;
    int scol = (t & 3) * 8;
    const __hip_bfloat16* rowA0 = Abf + (size_t)toks[srow] * HS + scol;
    const __hip_bfloat16* rowA1 = Abf + (size_t)toks[64 + srow] * HS + scol;
    const __hip_bfloat16* rowB1a = b1 + (size_t)(bn + srow) * HS + scol;
    const __hip_bfloat16* rowB1b = b1 + (size_t)(bn + 64 + srow) * HS + scol;
    const __hip_bfloat16* rowB3a = b3 + (size_t)(bn + srow) * HS + scol;
    const __hip_bfloat16* rowB3b = b3 + (size_t)(bn + 64 + srow) * HS + scol;

    f32x4 acc1[4][4] = {};
    f32x4 acc3[4][4] = {};

    for (int k0 = 0; k0 < HS; k0 += 32) {
        *(uint4*)&As[srow][scol]       = *(const uint4*)(rowA0 + k0);
        *(uint4*)&As[64 + srow][scol]  = *(const uint4*)(rowA1 + k0);
        *(uint4*)&B1s[srow][scol]      = *(const uint4*)(rowB1a + k0);
        *(uint4*)&B1s[64 + srow][scol] = *(const uint4*)(rowB1b + k0);
        *(uint4*)&B3s[srow][scol]      = *(const uint4*)(rowB3a + k0);
        *(uint4*)&B3s[64 + srow][scol] = *(const uint4*)(rowB3b + k0);
        __syncthreads();
        bf16x8 a[4], f1[4], f3[4];
        #pragma unroll
        for (int i = 0; i < 4; i++) {
            a[i]  = *(const bf16x8*)&As[wm + i * 16 + fr][kh];
            f1[i] = *(const bf16x8*)&B1s[wn + i * 16 + fr][kh];
            f3[i] = *(const bf16x8*)&B3s[wn + i * 16 + fr][kh];
        }
        #pragma unroll
        for (int mi = 0; mi < 4; mi++)
            #pragma unroll
            for (int ni = 0; ni < 4; ni++) {
                acc1[mi][ni] = __builtin_amdgcn_mfma_f32_16x16x32_bf16(a[mi], f1[ni], acc1[mi][ni], 0, 0, 0);
                acc3[mi][ni] = __builtin_amdgcn_mfma_f32_16x16x32_bf16(a[mi], f3[ni], acc3[mi][ni], 0, 0, 0);
            }
        __syncthreads();
    }
    int rq = (lane >> 4) * 4;
    #pragma unroll
    for (int mi = 0; mi < 4; mi++) {
        #pragma unroll
        for (int r = 0; r < 4; r++) {
            int slot = bm + wm + mi * 16 + rq + r;
            if (slot < ce) {
                size_t rowo = (size_t)(oe + slot) * IS + bn + wn;
                #pragma unroll
                for (int ni = 0; ni < 4; ni++) {
                    float x1 = acc1[mi][ni][r];
                    float x3 = acc3[mi][ni][r];
                    float sv = (x1 / (1.f + __expf(-x1))) * x3;
                    g[rowo + ni * 16 + fr] = __float2bfloat16(sv);
                }
            }
        }
    }
}

// ---------------------------------------------------------------- MoE down-proj, bf16 MFMA, fused combine+residual
__global__ __launch_bounds__(256) void moe_down_mfma(const __hip_bfloat16* __restrict__ g,
                                                     const __hip_bfloat16* __restrict__ B2T,
                                                     float* __restrict__ out,
                                                     const int* __restrict__ cnt,
                                                     const int* __restrict__ off,
                                                     const int* __restrict__ tok_list,
                                                     const float* __restrict__ wA) {
    int e = blockIdx.z;
    int ce = cnt[e];
    int bm = blockIdx.y * 128;
    if (bm >= ce) return;
    int oe = off[e];
    int bn = blockIdx.x * 128;
    const __hip_bfloat16* b2 = B2T + (size_t)e * HS * IS;   // [HS][IS]

    __shared__ __align__(16) short As[128][40];
    __shared__ __align__(16) short Bs[128][40];

    int t = threadIdx.x;
    int wave = t >> 6, lane = t & 63;
    int wm = (wave & 1) * 64, wn = (wave >> 1) * 64;
    int fr = lane & 15;
    int kh = (lane >> 4) * 8;

    int srow = t >> 2;
    int scol = (t & 3) * 8;
    int ga0 = oe + bm + srow;       if (ga0 > NASSIGN - 1) ga0 = NASSIGN - 1;
    int ga1 = oe + bm + 64 + srow;  if (ga1 > NASSIGN - 1) ga1 = NASSIGN - 1;
    const __hip_bfloat16* rowA0 = g + (size_t)ga0 * IS + scol;
    const __hip_bfloat16* rowA1 = g + (size_t)ga1 * IS + scol;
    const __hip_bfloat16* rowBa = b2 + (size_t)(bn + srow) * IS + scol;
    const __hip_bfloat16* rowBb = b2 + (size_t)(bn + 64 + srow) * IS + scol;

    f32x4 acc[4][4] = {};

    for (int k0 = 0; k0 < IS; k0 += 32) {
        *(uint4*)&As[srow][scol]      = *(const uint4*)(rowA0 + k0);
        *(uint4*)&As[64 + srow][scol] = *(const uint4*)(rowA1 + k0);
        *(uint4*)&Bs[srow][scol]      = *(const uint4*)(rowBa + k0);
        *(uint4*)&Bs[64 + srow][scol] = *(const uint4*)(rowBb + k0);
        __syncthreads();
        bf16x8 a[4], f[4];
        #pragma unroll
        for (int i = 0; i < 4; i++) {
            a[i] = *(const bf16x8*)&As[wm + i * 16 + fr][kh];
            f[i] = *(const bf16x8*)&Bs[wn + i * 16 + fr][kh];
        }
        #pragma unroll
        for (int mi = 0; mi < 4; mi++)
            #pragma unroll
            for (int ni = 0; ni < 4; ni++)
                acc[mi][ni] = __builtin_amdgcn_mfma_f32_16x16x32_bf16(a[mi], f[ni], acc[mi][ni], 0, 0, 0);
        __syncthreads();
    }
    int rq = (lane >> 4) * 4;
    #pragma unroll
    for (int mi = 0; mi < 4; mi++) {
        #pragma unroll
        for (int r = 0; r < 4; r++) {
            int slot = bm + wm + mi * 16 + rq + r;
            if (slot < ce) {
                int gidx = oe + slot;
                int tok = tok_list[gidx];
                float wgt = wA[gidx];
                size_t rowo = (size_t)tok * HS + bn + wn;
                #pragma unroll
                for (int ni = 0; ni < 4; ni++)
                    atomicAdd(out + rowo + ni * 16 + fr, wgt * acc[mi][ni][r]);
            }
        }
    }
}

// ---------------------------------------------------------------- launch
extern "C" void kernel_launch(void* const* d_in, const int* in_sizes, int n_in,
                              void* d_out, int out_size, void* d_ws, size_t ws_size,
                              hipStream_t stream) {
    const float* x   = (const float*)d_in[0];
    const float* anw = (const float*)d_in[1];
    const float* fnw = (const float*)d_in[2];
    const float* wq  = (const float*)d_in[3];
    const float* wk  = (const float*)d_in[4];
    const float* wv  = (const float*)d_in[5];
    const float* wo  = (const float*)d_in[6];
    const float* rw  = (const float*)d_in[7];
    const float* w1  = (const float*)d_in[8];
    const float* w3  = (const float*)d_in[9];
    const float* w2  = (const float*)d_in[10];
    const float* fc  = (const float*)d_in[11];
    float* out = (float*)d_out;

    char* ws = (char*)d_ws;
    const size_t MB = 1024 * 1024;
    // Phase A: xn_h@0(4) xn_l@4(4) qkv@8(24) WqkvT_h@32(6) WqkvT_l@38(6)
    //          woT_h@44(2) woT_l@46(2) po@48(33.6) pm@82 pl@83 ctx_h@84(4) ctx_l@88(4)
    __hip_bfloat16* xn_h  = (__hip_bfloat16*)(ws + 0 * MB);
    __hip_bfloat16* xn_l  = (__hip_bfloat16*)(ws + 4 * MB);
    float*          qkv   = (float*)(ws + 8 * MB);
    __hip_bfloat16* WqT_h = (__hip_bfloat16*)(ws + 32 * MB);
    __hip_bfloat16* WqT_l = (__hip_bfloat16*)(ws + 38 * MB);
    __hip_bfloat16* woT_h = (__hip_bfloat16*)(ws + 44 * MB);
    __hip_bfloat16* woT_l = (__hip_bfloat16*)(ws + 46 * MB);
    float*          po    = (float*)(ws + 48 * MB);
    float*          pm    = (float*)(ws + 82 * MB);
    float*          pl    = (float*)(ws + 83 * MB);
    __hip_bfloat16* ctx_h = (__hip_bfloat16*)(ws + 84 * MB);
    __hip_bfloat16* ctx_l = (__hip_bfloat16*)(ws + 88 * MB);
    // Phase B overlay: hn@0(8) hn_bf@8(4) w1T@12(32) w3T@44(32) w2T@76(32) gact@108(16) ints@124
    float*          hn    = (float*)(ws + 0 * MB);
    __hip_bfloat16* hn_bf = (__hip_bfloat16*)(ws + 8 * MB);
    __hip_bfloat16* w1T   = (__hip_bfloat16*)(ws + 12 * MB);
    __hip_bfloat16* w3T   = (__hip_bfloat16*)(ws + 44 * MB);
    __hip_bfloat16* w2T   = (__hip_bfloat16*)(ws + 76 * MB);
    __hip_bfloat16* gact  = (__hip_bfloat16*)(ws + 108 * MB);
    int* ibase    = (int*)(ws + 124 * MB);
    int* cnt      = ibase;
    int* fill     = ibase + 8;
    int* off      = ibase + 16;
    int* topEk    = ibase + 32;                       // 4096
    int* tok_list = ibase + 32 + NASSIGN;             // 4096
    float* topW   = (float*)(ibase + 32 + 2 * NASSIGN);
    float* wA     = (float*)(ibase + 32 + 3 * NASSIGN);

    // ---- attention half (split-bf16 GEMMs ~ fp32-grade; attention fp32) ----
    dim3 tg(HS / 32, HS / 32);
    transpose_split<<<tg, 256, 0, stream>>>(wq, WqT_h, WqT_l, HS, HS, 0);
    transpose_split<<<tg, 256, 0, stream>>>(wk, WqT_h, WqT_l, HS, HS, 1024);
    transpose_split<<<tg, 256, 0, stream>>>(wv, WqT_h, WqT_l, HS, HS, 2048);
    transpose_split<<<tg, 256, 0, stream>>>(wo, woT_h, woT_l, HS, HS, 0);
    rmsnorm_split<<<NTOK, 256, 0, stream>>>(x, anw, xn_h, xn_l);

    gemm_bf16x3<<<dim3(QKVW / 128, NTOK / 128), 256, 0, stream>>>(
        xn_h, xn_l, WqT_h, WqT_l, nullptr, qkv, NTOK, QKVW, HS);
    rope_kernel<<<(NTOK * NHEAD * (HDIM / 2)) / 256, 256, 0, stream>>>(qkv, fc);

    attn_partial<<<dim3(4, 16, 32), 256, 0, stream>>>(qkv, po, pm, pl);
    attn_merge<<<dim3(16, 16, 2), 256, 0, stream>>>(po, pm, pl, ctx_h, ctx_l);

    gemm_bf16x3<<<dim3(HS / 128, NTOK / 128), 256, 0, stream>>>(
        ctx_h, ctx_l, woT_h, woT_l, x, out, NTOK, HS, HS);   // out = h = x + ctx@wo

    // ---- MoE half (routed top-2, bf16 MFMA experts) ----
    rmsnorm_dual<<<NTOK, 256, 0, stream>>>(out, fnw, hn, hn_bf);
    transpose_bf16<<<dim3(IS / 32, HS / 32, NEXP), 256, 0, stream>>>(w1, w1T, HS, IS);
    transpose_bf16<<<dim3(IS / 32, HS / 32, NEXP), 256, 0, stream>>>(w3, w3T, HS, IS);
    transpose_bf16<<<dim3(HS / 32, IS / 32, NEXP), 256, 0, stream>>>(w2, w2T, IS, HS);

    hipMemsetAsync(cnt, 0, 16 * sizeof(int), stream);   // cnt + fill
    router_kernel<<<NTOK, 64, 0, stream>>>(hn, rw, cnt, topEk, topW);
    offsets_kernel<<<1, 64, 0, stream>>>(cnt, off);
    scatter_kernel<<<NASSIGN / 256, 256, 0, stream>>>(topEk, fill, off, topW, tok_list, wA);

    dim3 gup(IS / 128, NASSIGN / 128, NEXP);
    moe_up_mfma<<<gup, 256, 0, stream>>>(hn_bf, w1T, w3T, gact, cnt, off, tok_list);
    dim3 gdn(HS / 128, NASSIGN / 128, NEXP);
    moe_down_mfma<<<gdn, 256, 0, stream>>>(gact, w2T, out, cnt, off, tok_list, wA);
}

// Round 5
// 732.502 us; speedup vs baseline: 6.2826x; 1.1200x over previous
//
#include <hip/hip_runtime.h>
#include <hip/hip_bf16.h>
#include <math.h>

#define HS 1024      // hidden size
#define IS 2048      // intermediate size
#define NHEAD 16
#define HDIM 64
#define NEXP 8
#define BATCH 2
#define SEQ 1024
#define NTOK (BATCH*SEQ)     // 2048 tokens
#define NASSIGN (NTOK*2)     // 4096 (token, expert) assignments
#define QKVW 3072            // fused qkv row width
#define PAD 72               // LDS row stride (bf16 elems): 144B -> 2-way-free bank rotation

typedef short bf16x8 __attribute__((ext_vector_type(8)));
typedef float f32x4  __attribute__((ext_vector_type(4)));

// ---------------------------------------------------------------- rmsnorm -> split bf16 (hi+lo)
__global__ void rmsnorm_split(const float* __restrict__ x, const float* __restrict__ w,
                              __hip_bfloat16* __restrict__ oh, __hip_bfloat16* __restrict__ ol) {
    int t = blockIdx.x;
    int tid = threadIdx.x;
    const float* row = x + (size_t)t * HS;
    float ss = 0.f;
    for (int i = tid; i < HS; i += 256) { float v = row[i]; ss += v * v; }
    for (int off = 32; off > 0; off >>= 1) ss += __shfl_down(ss, off);
    __shared__ float red[4];
    if ((tid & 63) == 0) red[tid >> 6] = ss;
    __syncthreads();
    float tot = red[0] + red[1] + red[2] + red[3];
    float rr = rsqrtf(tot / (float)HS + 1e-6f);
    for (int i = tid; i < HS; i += 256) {
        float v = w[i] * row[i] * rr;
        __hip_bfloat16 hi = __float2bfloat16(v);
        oh[(size_t)t * HS + i] = hi;
        ol[(size_t)t * HS + i] = __float2bfloat16(v - __bfloat162float(hi));
    }
}

// ---------------------------------------------------------------- rmsnorm dual (fp32 + bf16)
__global__ void rmsnorm_dual(const float* __restrict__ x, const float* __restrict__ w,
                             float* __restrict__ outf, __hip_bfloat16* __restrict__ outb) {
    int t = blockIdx.x;
    int tid = threadIdx.x;
    const float* row = x + (size_t)t * HS;
    float ss = 0.f;
    for (int i = tid; i < HS; i += 256) { float v = row[i]; ss += v * v; }
    for (int off = 32; off > 0; off >>= 1) ss += __shfl_down(ss, off);
    __shared__ float red[4];
    if ((tid & 63) == 0) red[tid >> 6] = ss;
    __syncthreads();
    float tot = red[0] + red[1] + red[2] + red[3];
    float rr = rsqrtf(tot / (float)HS + 1e-6f);
    for (int i = tid; i < HS; i += 256) {
        float v = w[i] * row[i] * rr;
        outf[(size_t)t * HS + i] = v;
        outb[(size_t)t * HS + i] = __float2bfloat16(v);
    }
}

// ---------------------------------------------------------------- transpose fp32 [R][C] -> split bf16 [C][R]
__global__ void transpose_split(const float* __restrict__ src,
                                __hip_bfloat16* __restrict__ dh, __hip_bfloat16* __restrict__ dl,
                                int R, int C, int rowOff) {
    __shared__ float tile[32][33];
    int c0 = blockIdx.x * 32, r0 = blockIdx.y * 32;
    int tx = threadIdx.x & 31, ty = threadIdx.x >> 5;  // 0..7
    #pragma unroll
    for (int i = 0; i < 4; i++) {
        int r = ty + i * 8;
        tile[r][tx] = src[(size_t)(r0 + r) * C + c0 + tx];
    }
    __syncthreads();
    #pragma unroll
    for (int i = 0; i < 4; i++) {
        int c = ty + i * 8;
        float v = tile[tx][c];
        __hip_bfloat16 hi = __float2bfloat16(v);
        size_t o = (size_t)(rowOff + c0 + c) * R + r0 + tx;
        dh[o] = hi;
        dl[o] = __float2bfloat16(v - __bfloat162float(hi));
    }
}

// ---------------------------------------------------------------- transpose fp32 [R][C] -> bf16 [C][R], per expert z
__global__ void transpose_bf16(const float* __restrict__ in, __hip_bfloat16* __restrict__ outp,
                               int R, int C) {
    __shared__ float tile[32][33];
    int e = blockIdx.z;
    const float* src = in + (size_t)e * R * C;
    __hip_bfloat16* dst = outp + (size_t)e * R * C;
    int c0 = blockIdx.x * 32, r0 = blockIdx.y * 32;
    int tx = threadIdx.x & 31, ty = threadIdx.x >> 5;
    #pragma unroll
    for (int i = 0; i < 4; i++) {
        int r = ty + i * 8;
        tile[r][tx] = src[(size_t)(r0 + r) * C + c0 + tx];
    }
    __syncthreads();
    #pragma unroll
    for (int i = 0; i < 4; i++) {
        int c = ty + i * 8;
        dst[(size_t)(c0 + c) * R + r0 + tx] = __float2bfloat16(tile[tx][c]);
    }
}

// ---------------------------------------------------------------- split-bf16 GEMM (fp32-grade precision)
__global__ __launch_bounds__(256) void gemm_bf16x3(const __hip_bfloat16* __restrict__ Ah,
                                                   const __hip_bfloat16* __restrict__ Al,
                                                   const __hip_bfloat16* __restrict__ Bh,
                                                   const __hip_bfloat16* __restrict__ Bl,
                                                   const float* __restrict__ resid,
                                                   float* __restrict__ C,
                                                   int M, int N, int K) {
    __shared__ __align__(16) short Ahs[128][40];
    __shared__ __align__(16) short Als[128][40];
    __shared__ __align__(16) short Bhs[128][40];
    __shared__ __align__(16) short Bls[128][40];
    int bm = blockIdx.y * 128, bn = blockIdx.x * 128;
    int t = threadIdx.x;
    int wave = t >> 6, lane = t & 63;
    int wm = (wave & 1) * 64, wn = (wave >> 1) * 64;
    int fr = lane & 15;
    int kh = (lane >> 4) * 8;
    int srow = t >> 2;            // 0..63
    int scol = (t & 3) * 8;
    const __hip_bfloat16* a0h = Ah + (size_t)(bm + srow) * K + scol;
    const __hip_bfloat16* a1h = Ah + (size_t)(bm + 64 + srow) * K + scol;
    const __hip_bfloat16* a0l = Al + (size_t)(bm + srow) * K + scol;
    const __hip_bfloat16* a1l = Al + (size_t)(bm + 64 + srow) * K + scol;
    const __hip_bfloat16* b0h = Bh + (size_t)(bn + srow) * K + scol;
    const __hip_bfloat16* b1h = Bh + (size_t)(bn + 64 + srow) * K + scol;
    const __hip_bfloat16* b0l = Bl + (size_t)(bn + srow) * K + scol;
    const __hip_bfloat16* b1l = Bl + (size_t)(bn + 64 + srow) * K + scol;

    f32x4 acc[4][4] = {};
    for (int k0 = 0; k0 < K; k0 += 32) {
        *(uint4*)&Ahs[srow][scol]      = *(const uint4*)(a0h + k0);
        *(uint4*)&Ahs[64 + srow][scol] = *(const uint4*)(a1h + k0);
        *(uint4*)&Als[srow][scol]      = *(const uint4*)(a0l + k0);
        *(uint4*)&Als[64 + srow][scol] = *(const uint4*)(a1l + k0);
        *(uint4*)&Bhs[srow][scol]      = *(const uint4*)(b0h + k0);
        *(uint4*)&Bhs[64 + srow][scol] = *(const uint4*)(b1h + k0);
        *(uint4*)&Bls[srow][scol]      = *(const uint4*)(b0l + k0);
        *(uint4*)&Bls[64 + srow][scol] = *(const uint4*)(b1l + k0);
        __syncthreads();
        bf16x8 ah[4], bh[4], x[4];
        #pragma unroll
        for (int i = 0; i < 4; i++) {
            ah[i] = *(const bf16x8*)&Ahs[wm + i * 16 + fr][kh];
            bh[i] = *(const bf16x8*)&Bhs[wn + i * 16 + fr][kh];
        }
        #pragma unroll
        for (int mi = 0; mi < 4; mi++)
            #pragma unroll
            for (int ni = 0; ni < 4; ni++)
                acc[mi][ni] = __builtin_amdgcn_mfma_f32_16x16x32_bf16(ah[mi], bh[ni], acc[mi][ni], 0, 0, 0);
        #pragma unroll
        for (int i = 0; i < 4; i++) x[i] = *(const bf16x8*)&Bls[wn + i * 16 + fr][kh];
        #pragma unroll
        for (int mi = 0; mi < 4; mi++)
            #pragma unroll
            for (int ni = 0; ni < 4; ni++)
                acc[mi][ni] = __builtin_amdgcn_mfma_f32_16x16x32_bf16(ah[mi], x[ni], acc[mi][ni], 0, 0, 0);
        #pragma unroll
        for (int i = 0; i < 4; i++) x[i] = *(const bf16x8*)&Als[wm + i * 16 + fr][kh];
        #pragma unroll
        for (int mi = 0; mi < 4; mi++)
            #pragma unroll
            for (int ni = 0; ni < 4; ni++)
                acc[mi][ni] = __builtin_amdgcn_mfma_f32_16x16x32_bf16(x[mi], bh[ni], acc[mi][ni], 0, 0, 0);
        __syncthreads();
    }
    int rq = (lane >> 4) * 4;
    #pragma unroll
    for (int mi = 0; mi < 4; mi++) {
        #pragma unroll
        for (int r = 0; r < 4; r++) {
            size_t rowo = (size_t)(bm + wm + mi * 16 + rq + r) * N + bn + wn;
            #pragma unroll
            for (int ni = 0; ni < 4; ni++) {
                float v = acc[mi][ni][r];
                size_t o = rowo + ni * 16 + fr;
                if (resid) v += resid[o];
                C[o] = v;
            }
        }
    }
}

// ---------------------------------------------------------------- RoPE + convert qkv fp32 -> split bf16 q,k,v
__global__ void rope_convert(const float* __restrict__ qkv, const float* __restrict__ fc,
                             __hip_bfloat16* __restrict__ qh, __hip_bfloat16* __restrict__ ql,
                             __hip_bfloat16* __restrict__ kh, __hip_bfloat16* __restrict__ kl,
                             __hip_bfloat16* __restrict__ vh, __hip_bfloat16* __restrict__ vl) {
    int t = blockIdx.x;
    int s = t & (SEQ - 1);
    const float* row = qkv + (size_t)t * QKVW;
    size_t ob = (size_t)t * HS;
    for (int p = threadIdx.x; p < 512; p += 256) {
        int hh = p >> 5, j = p & 31;
        int col = hh * 64 + 2 * j;
        float cr = fc[s * HDIM + 2 * j];
        float ci = fc[s * HDIM + 2 * j + 1];
        float a = row[col], b = row[col + 1];
        float r0 = a * cr - b * ci, r1 = a * ci + b * cr;
        __hip_bfloat16 h0 = __float2bfloat16(r0), h1 = __float2bfloat16(r1);
        qh[ob + col] = h0;     ql[ob + col]     = __float2bfloat16(r0 - __bfloat162float(h0));
        qh[ob + col + 1] = h1; ql[ob + col + 1] = __float2bfloat16(r1 - __bfloat162float(h1));
        a = row[1024 + col]; b = row[1024 + col + 1];
        r0 = a * cr - b * ci; r1 = a * ci + b * cr;
        h0 = __float2bfloat16(r0); h1 = __float2bfloat16(r1);
        kh[ob + col] = h0;     kl[ob + col]     = __float2bfloat16(r0 - __bfloat162float(h0));
        kh[ob + col + 1] = h1; kl[ob + col + 1] = __float2bfloat16(r1 - __bfloat162float(h1));
        r0 = row[2048 + col]; r1 = row[2048 + col + 1];
        h0 = __float2bfloat16(r0); h1 = __float2bfloat16(r1);
        vh[ob + col] = h0;     vl[ob + col]     = __float2bfloat16(r0 - __bfloat162float(h0));
        vh[ob + col + 1] = h1; vl[ob + col + 1] = __float2bfloat16(r1 - __bfloat162float(h1));
    }
}

// ---------------------------------------------------------------- split-K flash attention, MFMA split-bf16
// grid: x=chunk(4), y=qt(16), z=b*16+h. Online softmax; S and PV via 3-chain split-bf16 MFMA.
__global__ __launch_bounds__(256) void attn_partial(
        const __hip_bfloat16* __restrict__ qh, const __hip_bfloat16* __restrict__ ql,
        const __hip_bfloat16* __restrict__ kh, const __hip_bfloat16* __restrict__ kl,
        const __hip_bfloat16* __restrict__ vh, const __hip_bfloat16* __restrict__ vl,
        float* __restrict__ po, float* __restrict__ pm_g, float* __restrict__ pl_g) {
    int c = blockIdx.x, qt = blockIdx.y;
    int nc = (qt + 4) >> 2;
    if (c >= nc) return;
    int bh = blockIdx.z;
    int b = bh >> 4, h = bh & 15;
    int t0 = c * 4, t1 = min(t0 + 4, qt + 1);
    int tid = threadIdx.x;
    int wave = tid >> 6, lane = tid & 63;
    int fr = lane & 15, quad = lane >> 4;
    int w16 = wave * 16;
    // Q: [q][d]; KP: K-tile [key][d] then reused as P [q][key]; V: transposed [d][key]
    __shared__ __align__(16) short Qh[64][PAD], Ql[64][PAD];
    __shared__ __align__(16) short KPh[64][PAD], KPl[64][PAD];
    __shared__ __align__(16) short Vhs[64][PAD], Vls[64][PAD];
    size_t hoff = (size_t)h * HDIM;
    int sr = tid >> 2, sg = tid & 3;
    {
        const __hip_bfloat16* qp  = qh + (size_t)(b * SEQ + qt * 64 + sr) * HS + hoff;
        const __hip_bfloat16* qp2 = ql + (size_t)(b * SEQ + qt * 64 + sr) * HS + hoff;
        *(uint4*)&Qh[sr][sg * 8]       = *(const uint4*)(qp + sg * 8);
        *(uint4*)&Qh[sr][(sg + 4) * 8] = *(const uint4*)(qp + (sg + 4) * 8);
        *(uint4*)&Ql[sr][sg * 8]       = *(const uint4*)(qp2 + sg * 8);
        *(uint4*)&Ql[sr][(sg + 4) * 8] = *(const uint4*)(qp2 + (sg + 4) * 8);
    }
    f32x4 o[4] = {};
    float mrow[4], lrow[4];
    #pragma unroll
    for (int i = 0; i < 4; i++) { mrow[i] = -1e30f; lrow[i] = 0.f; }
    int key0 = (tid & 31) * 2, ds = tid >> 5;   // V transpose staging coords
    __syncthreads();

    for (int kt = t0; kt < t1; kt++) {
        int kbase = kt * 64;
        {   // K staging [key][d]
            const __hip_bfloat16* kp  = kh + (size_t)(b * SEQ + kbase + sr) * HS + hoff;
            const __hip_bfloat16* kp2 = kl + (size_t)(b * SEQ + kbase + sr) * HS + hoff;
            *(uint4*)&KPh[sr][sg * 8]       = *(const uint4*)(kp + sg * 8);
            *(uint4*)&KPh[sr][(sg + 4) * 8] = *(const uint4*)(kp + (sg + 4) * 8);
            *(uint4*)&KPl[sr][sg * 8]       = *(const uint4*)(kp2 + sg * 8);
            *(uint4*)&KPl[sr][(sg + 4) * 8] = *(const uint4*)(kp2 + (sg + 4) * 8);
        }
        {   // V staging transposed [d][key]: pack two adjacent keys into one 4B write
            const __hip_bfloat16* v0 = vh + (size_t)(b * SEQ + kbase + key0) * HS + hoff + ds * 8;
            uint4 A = *(const uint4*)v0;
            uint4 Bv = *(const uint4*)(v0 + HS);
            const unsigned short* ap = (const unsigned short*)&A;
            const unsigned short* bp = (const unsigned short*)&Bv;
            #pragma unroll
            for (int j = 0; j < 8; j++)
                *(unsigned*)&Vhs[ds * 8 + j][key0] = (unsigned)ap[j] | ((unsigned)bp[j] << 16);
            const __hip_bfloat16* v2 = vl + (size_t)(b * SEQ + kbase + key0) * HS + hoff + ds * 8;
            uint4 A2 = *(const uint4*)v2;
            uint4 B2 = *(const uint4*)(v2 + HS);
            const unsigned short* ap2 = (const unsigned short*)&A2;
            const unsigned short* bp2 = (const unsigned short*)&B2;
            #pragma unroll
            for (int j = 0; j < 8; j++)
                *(unsigned*)&Vls[ds * 8 + j][key0] = (unsigned)ap2[j] | ((unsigned)bp2[j] << 16);
        }
        __syncthreads();

        // S = Q K^T : wave owns q-rows [w16, w16+16), all 64 keys
        f32x4 s[4] = {};
        #pragma unroll
        for (int ks = 0; ks < 2; ks++) {
            bf16x8 a_h = *(const bf16x8*)&Qh[w16 + fr][quad * 8 + ks * 32];
            bf16x8 a_l = *(const bf16x8*)&Ql[w16 + fr][quad * 8 + ks * 32];
            #pragma unroll
            for (int ni = 0; ni < 4; ni++) {
                bf16x8 b_h = *(const bf16x8*)&KPh[ni * 16 + fr][quad * 8 + ks * 32];
                bf16x8 b_l = *(const bf16x8*)&KPl[ni * 16 + fr][quad * 8 + ks * 32];
                s[ni] = __builtin_amdgcn_mfma_f32_16x16x32_bf16(a_h, b_h, s[ni], 0, 0, 0);
                s[ni] = __builtin_amdgcn_mfma_f32_16x16x32_bf16(a_h, b_l, s[ni], 0, 0, 0);
                s[ni] = __builtin_amdgcn_mfma_f32_16x16x32_bf16(a_l, b_h, s[ni], 0, 0, 0);
            }
        }
        // mask + scale (C-layout: row = quad*4+r, col = ni*16+fr)
        int qg = qt * 64 + w16 + quad * 4;
        #pragma unroll
        for (int ni = 0; ni < 4; ni++) {
            int kg = kbase + ni * 16 + fr;
            #pragma unroll
            for (int r = 0; r < 4; r++)
                s[ni][r] = (kg > qg + r) ? -1e9f : s[ni][r] * 0.125f;
        }
        // online softmax (per q-row; 16 lanes of each quad share a row-set)
        #pragma unroll
        for (int r = 0; r < 4; r++) {
            float mx = fmaxf(fmaxf(s[0][r], s[1][r]), fmaxf(s[2][r], s[3][r]));
            #pragma unroll
            for (int wd = 1; wd < 16; wd <<= 1) mx = fmaxf(mx, __shfl_xor(mx, wd));
            float nm = fmaxf(mrow[r], mx);
            float alpha = __expf(mrow[r] - nm);
            float rs = 0.f;
            #pragma unroll
            for (int ni = 0; ni < 4; ni++) { float e = __expf(s[ni][r] - nm); s[ni][r] = e; rs += e; }
            #pragma unroll
            for (int wd = 1; wd < 16; wd <<= 1) rs += __shfl_xor(rs, wd);
            lrow[r] = lrow[r] * alpha + rs;
            mrow[r] = nm;
            o[0][r] *= alpha; o[1][r] *= alpha; o[2][r] *= alpha; o[3][r] *= alpha;
        }
        __syncthreads();   // all waves done reading K before P overwrites the buffer
        // write P split into KP buffers: [q][key], own 16 rows
        #pragma unroll
        for (int ni = 0; ni < 4; ni++)
            #pragma unroll
            for (int r = 0; r < 4; r++) {
                float pv = s[ni][r];
                __hip_bfloat16 hi = __float2bfloat16(pv);
                __hip_bfloat16 lo = __float2bfloat16(pv - __bfloat162float(hi));
                KPh[w16 + quad * 4 + r][ni * 16 + fr] = *(short*)&hi;
                KPl[w16 + quad * 4 + r][ni * 16 + fr] = *(short*)&lo;
            }
        // PV: A = P [q][key] (own rows), B = V^T [d][key]
        #pragma unroll
        for (int ks = 0; ks < 2; ks++) {
            bf16x8 p_h = *(const bf16x8*)&KPh[w16 + fr][quad * 8 + ks * 32];
            bf16x8 p_l = *(const bf16x8*)&KPl[w16 + fr][quad * 8 + ks * 32];
            #pragma unroll
            for (int ni = 0; ni < 4; ni++) {
                bf16x8 v_h = *(const bf16x8*)&Vhs[ni * 16 + fr][quad * 8 + ks * 32];
                bf16x8 v_l = *(const bf16x8*)&Vls[ni * 16 + fr][quad * 8 + ks * 32];
                o[ni] = __builtin_amdgcn_mfma_f32_16x16x32_bf16(p_h, v_h, o[ni], 0, 0, 0);
                o[ni] = __builtin_amdgcn_mfma_f32_16x16x32_bf16(p_h, v_l, o[ni], 0, 0, 0);
                o[ni] = __builtin_amdgcn_mfma_f32_16x16x32_bf16(p_l, v_h, o[ni], 0, 0, 0);
            }
        }
        __syncthreads();   // PV reads done before next staging
    }
    int pidx = (bh * 16 + qt) * 4 + c;
    float* pob = po + (size_t)pidx * 4096;
    #pragma unroll
    for (int ni = 0; ni < 4; ni++)
        #pragma unroll
        for (int r = 0; r < 4; r++)
            pob[(w16 + quad * 4 + r) * 64 + ni * 16 + fr] = o[ni][r];
    if (fr == 0) {
        #pragma unroll
        for (int r = 0; r < 4; r++) {
            pm_g[pidx * 64 + w16 + quad * 4 + r] = mrow[r];
            pl_g[pidx * 64 + w16 + quad * 4 + r] = lrow[r];
        }
    }
}

// ---------------------------------------------------------------- merge partials -> ctx as split bf16
__global__ void attn_merge(const float* __restrict__ po, const float* __restrict__ pm,
                           const float* __restrict__ pl,
                           __hip_bfloat16* __restrict__ ch, __hip_bfloat16* __restrict__ cl) {
    int qt = blockIdx.x, h = blockIdx.y, b = blockIdx.z;
    int bh = b * 16 + h;
    int nc = (qt + 4) >> 2;
    int base = (bh * 16 + qt) * 4;
    int tid = threadIdx.x;
    int r  = tid >> 2;          // 0..63
    int d0 = (tid & 3) * 16;
    float mstar = -1e30f;
    for (int c = 0; c < nc; c++) mstar = fmaxf(mstar, pm[(base + c) * 64 + r]);
    float a[4];
    float lsum = 0.f;
    for (int c = 0; c < nc; c++) {
        a[c] = __expf(pm[(base + c) * 64 + r] - mstar);
        lsum += a[c] * pl[(base + c) * 64 + r];
    }
    float inv = 1.f / lsum;
    size_t crow = (size_t)(b * SEQ + qt * 64 + r) * HS + h * HDIM;
    for (int dd = 0; dd < 16; dd += 4) {
        float4 acc = make_float4(0.f, 0.f, 0.f, 0.f);
        for (int c = 0; c < nc; c++) {
            float4 v = *(const float4*)(po + (size_t)(base + c) * 4096 + r * 64 + d0 + dd);
            acc.x += a[c] * v.x; acc.y += a[c] * v.y;
            acc.z += a[c] * v.z; acc.w += a[c] * v.w;
        }
        float vs[4] = {acc.x * inv, acc.y * inv, acc.z * inv, acc.w * inv};
        #pragma unroll
        for (int j = 0; j < 4; j++) {
            __hip_bfloat16 hi = __float2bfloat16(vs[j]);
            ch[crow + d0 + dd + j] = hi;
            cl[crow + d0 + dd + j] = __float2bfloat16(vs[j] - __bfloat162float(hi));
        }
    }
}

// ---------------------------------------------------------------- router (per-token top2)
__global__ void router_kernel(const float* __restrict__ hn, const float* __restrict__ rw,
                              int* __restrict__ cnt, int* __restrict__ topEk,
                              float* __restrict__ topW) {
    int t = blockIdx.x;
    int lane = threadIdx.x;   // 64 = 1 wave
    float acc[NEXP];
    #pragma unroll
    for (int e = 0; e < NEXP; e++) acc[e] = 0.f;
    const float* row = hn + (size_t)t * HS;
    for (int kk = lane; kk < HS; kk += 64) {
        float xv = row[kk];
        const float* r = rw + (size_t)kk * NEXP;
        #pragma unroll
        for (int e = 0; e < NEXP; e++) acc[e] += xv * r[e];
    }
    #pragma unroll
    for (int e = 0; e < NEXP; e++)
        for (int off = 32; off > 0; off >>= 1) acc[e] += __shfl_down(acc[e], off);
    if (lane == 0) {
        float mx = acc[0];
        #pragma unroll
        for (int e = 1; e < NEXP; e++) mx = fmaxf(mx, acc[e]);
        float p[NEXP]; float s = 0.f;
        #pragma unroll
        for (int e = 0; e < NEXP; e++) { p[e] = __expf(acc[e] - mx); s += p[e]; }
        int i0 = 0;
        #pragma unroll
        for (int e = 1; e < NEXP; e++) if (p[e] > p[i0]) i0 = e;
        int i1 = (i0 == 0) ? 1 : 0;
        #pragma unroll
        for (int e = 0; e < NEXP; e++) if (e != i0 && p[e] > p[i1]) i1 = e;
        float v0 = p[i0], v1 = p[i1], sn = v0 + v1;
        topEk[2 * t]     = i0; topW[2 * t]     = v0 / sn;
        topEk[2 * t + 1] = i1; topW[2 * t + 1] = v1 / sn;
        atomicAdd(&cnt[i0], 1);
        atomicAdd(&cnt[i1], 1);
    }
}

__global__ void offsets_kernel(const int* __restrict__ cnt, int* __restrict__ off) {
    if (threadIdx.x == 0) {
        int o = 0;
        for (int e = 0; e < NEXP; e++) { off[e] = o; o += cnt[e]; }
    }
}

__global__ void scatter_kernel(const int* __restrict__ topEk, int* __restrict__ fill,
                               const int* __restrict__ off, const float* __restrict__ topW,
                               int* __restrict__ tok_list, float* __restrict__ wA) {
    int idx = blockIdx.x * 256 + threadIdx.x;   // NASSIGN
    int e = topEk[idx];
    int slot = atomicAdd(&fill[e], 1);
    int gidx = off[e] + slot;
    tok_list[gidx] = idx >> 1;
    wA[gidx] = topW[idx];
}

// ---------------------------------------------------------------- MoE up-proj, bf16 MFMA
__global__ __launch_bounds__(256) void moe_up_mfma(const __hip_bfloat16* __restrict__ Abf,
                                                   const __hip_bfloat16* __restrict__ B1T,
                                                   const __hip_bfloat16* __restrict__ B3T,
                                                   __hip_bfloat16* __restrict__ g,
                                                   const int* __restrict__ cnt,
                                                   const int* __restrict__ off,
                                                   const int* __restrict__ tok_list) {
    int e = blockIdx.z;
    int ce = cnt[e];
    int bm = blockIdx.y * 128;
    if (bm >= ce) return;
    int oe = off[e];
    int bn = blockIdx.x * 128;
    const __hip_bfloat16* b1 = B1T + (size_t)e * IS * HS;   // [IS][HS]
    const __hip_bfloat16* b3 = B3T + (size_t)e * IS * HS;

    __shared__ __align__(16) short As[128][40];
    __shared__ __align__(16) short B1s[128][40];
    __shared__ __align__(16) short B3s[128][40];
    __shared__ int toks[128];

    int t = threadIdx.x;
    int wave = t >> 6, lane = t & 63;
    int wm = (wave & 1) * 64, wn = (wave >> 1) * 64;
    int fr = lane & 15;
    int kh = (lane >> 4) * 8;

    if (t < 128) {
        int gidx = oe + bm + t;
        if (gidx > NASSIGN - 1) gidx = NASSIGN - 1;
        toks[t] = tok_list[gidx];
    }
    __syncthreads();
    int srow = t >> 2;
    int scol = (t & 3) * 8;
    const __hip_bfloat16* rowA0 = Abf + (size_t)toks[srow] * HS + scol;
    const __hip_bfloat16* rowA1 = Abf + (size_t)toks[64 + srow] * HS + scol;
    const __hip_bfloat16* rowB1a = b1 + (size_t)(bn + srow) * HS + scol;
    const __hip_bfloat16* rowB1b = b1 + (size_t)(bn + 64 + srow) * HS + scol;
    const __hip_bfloat16* rowB3a = b3 + (size_t)(bn + srow) * HS + scol;
    const __hip_bfloat16* rowB3b = b3 + (size_t)(bn + 64 + srow) * HS + scol;

    f32x4 acc1[4][4] = {};
    f32x4 acc3[4][4] = {};

    for (int k0 = 0; k0 < HS; k0 += 32) {
        *(uint4*)&As[srow][scol]       = *(const uint4*)(rowA0 + k0);
        *(uint4*)&As[64 + srow][scol]  = *(const uint4*)(rowA1 + k0);
        *(uint4*)&B1s[srow][scol]      = *(const uint4*)(rowB1a + k0);
        *(uint4*)&B1s[64 + srow][scol] = *(const uint4*)(rowB1b + k0);
        *(uint4*)&B3s[srow][scol]      = *(const uint4*)(rowB3a + k0);
        *(uint4*)&B3s[64 + srow][scol] = *(const uint4*)(rowB3b + k0);
        __syncthreads();
        bf16x8 a[4], f1[4], f3[4];
        #pragma unroll
        for (int i = 0; i < 4; i++) {
            a[i]  = *(const bf16x8*)&As[wm + i * 16 + fr][kh];
            f1[i] = *(const bf16x8*)&B1s[wn + i * 16 + fr][kh];
            f3[i] = *(const bf16x8*)&B3s[wn + i * 16 + fr][kh];
        }
        #pragma unroll
        for (int mi = 0; mi < 4; mi++)
            #pragma unroll
            for (int ni = 0; ni < 4; ni++) {
                acc1[mi][ni] = __builtin_amdgcn_mfma_f32_16x16x32_bf16(a[mi], f1[ni], acc1[mi][ni], 0, 0, 0);
                acc3[mi][ni] = __builtin_amdgcn_mfma_f32_16x16x32_bf16(a[mi], f3[ni], acc3[mi][ni], 0, 0, 0);
            }
        __syncthreads();
    }
    int rq = (lane >> 4) * 4;
    #pragma unroll
    for (int mi = 0; mi < 4; mi++) {
        #pragma unroll
        for (int r = 0; r < 4; r++) {
            int slot = bm + wm + mi * 16 + rq + r;
            if (slot < ce) {
                size_t rowo = (size_t)(oe + slot) * IS + bn + wn;
                #pragma unroll
                for (int ni = 0; ni < 4; ni++) {
                    float x1 = acc1[mi][ni][r];
                    float x3 = acc3[mi][ni][r];
                    float sv = (x1 / (1.f + __expf(-x1))) * x3;
                    g[rowo + ni * 16 + fr] = __float2bfloat16(sv);
                }
            }
        }
    }
}

// ---------------------------------------------------------------- MoE down-proj, bf16 MFMA, fused combine+residual
__global__ __launch_bounds__(256) void moe_down_mfma(const __hip_bfloat16* __restrict__ g,
                                                     const __hip_bfloat16* __restrict__ B2T,
                                                     float* __restrict__ out,
                                                     const int* __restrict__ cnt,
                                                     const int* __restrict__ off,
                                                     const int* __restrict__ tok_list,
                                                     const float* __restrict__ wA) {
    int e = blockIdx.z;
    int ce = cnt[e];
    int bm = blockIdx.y * 128;
    if (bm >= ce) return;
    int oe = off[e];
    int bn = blockIdx.x * 128;
    const __hip_bfloat16* b2 = B2T + (size_t)e * HS * IS;   // [HS][IS]

    __shared__ __align__(16) short As[128][40];
    __shared__ __align__(16) short Bs[128][40];

    int t = threadIdx.x;
    int wave = t >> 6, lane = t & 63;
    int wm = (wave & 1) * 64, wn = (wave >> 1) * 64;
    int fr = lane & 15;
    int kh = (lane >> 4) * 8;

    int srow = t >> 2;
    int scol = (t & 3) * 8;
    int ga0 = oe + bm + srow;       if (ga0 > NASSIGN - 1) ga0 = NASSIGN - 1;
    int ga1 = oe + bm + 64 + srow;  if (ga1 > NASSIGN - 1) ga1 = NASSIGN - 1;
    const __hip_bfloat16* rowA0 = g + (size_t)ga0 * IS + scol;
    const __hip_bfloat16* rowA1 = g + (size_t)ga1 * IS + scol;
    const __hip_bfloat16* rowBa = b2 + (size_t)(bn + srow) * IS + scol;
    const __hip_bfloat16* rowBb = b2 + (size_t)(bn + 64 + srow) * IS + scol;

    f32x4 acc[4][4] = {};

    for (int k0 = 0; k0 < IS; k0 += 32) {
        *(uint4*)&As[srow][scol]      = *(const uint4*)(rowA0 + k0);
        *(uint4*)&As[64 + srow][scol] = *(const uint4*)(rowA1 + k0);
        *(uint4*)&Bs[srow][scol]      = *(const uint4*)(rowBa + k0);
        *(uint4*)&Bs[64 + srow][scol] = *(const uint4*)(rowBb + k0);
        __syncthreads();
        bf16x8 a[4], f[4];
        #pragma unroll
        for (int i = 0; i < 4; i++) {
            a[i] = *(const bf16x8*)&As[wm + i * 16 + fr][kh];
            f[i] = *(const bf16x8*)&Bs[wn + i * 16 + fr][kh];
        }
        #pragma unroll
        for (int mi = 0; mi < 4; mi++)
            #pragma unroll
            for (int ni = 0; ni < 4; ni++)
                acc[mi][ni] = __builtin_amdgcn_mfma_f32_16x16x32_bf16(a[mi], f[ni], acc[mi][ni], 0, 0, 0);
        __syncthreads();
    }
    int rq = (lane >> 4) * 4;
    #pragma unroll
    for (int mi = 0; mi < 4; mi++) {
        #pragma unroll
        for (int r = 0; r < 4; r++) {
            int slot = bm + wm + mi * 16 + rq + r;
            if (slot < ce) {
                int gidx = oe + slot;
                int tok = tok_list[gidx];
                float wgt = wA[gidx];
                size_t rowo = (size_t)tok * HS + bn + wn;
                #pragma unroll
                for (int ni = 0; ni < 4; ni++)
                    atomicAdd(out + rowo + ni * 16 + fr, wgt * acc[mi][ni][r]);
            }
        }
    }
}

// ---------------------------------------------------------------- launch
extern "C" void kernel_launch(void* const* d_in, const int* in_sizes, int n_in,
                              void* d_out, int out_size, void* d_ws, size_t ws_size,
                              hipStream_t stream) {
    const float* x   = (const float*)d_in[0];
    const float* anw = (const float*)d_in[1];
    const float* fnw = (const float*)d_in[2];
    const float* wq  = (const float*)d_in[3];
    const float* wk  = (const float*)d_in[4];
    const float* wv  = (const float*)d_in[5];
    const float* wo  = (const float*)d_in[6];
    const float* rw  = (const float*)d_in[7];
    const float* w1  = (const float*)d_in[8];
    const float* w3  = (const float*)d_in[9];
    const float* w2  = (const float*)d_in[10];
    const float* fc  = (const float*)d_in[11];
    float* out = (float*)d_out;

    char* ws = (char*)d_ws;
    const size_t MB = 1024 * 1024;
    // Phase A: xn_h@0(4) xn_l@4(4) qkv@8(24) WqT_h@32(6) WqT_l@38(6) woT_h@44(2) woT_l@46(2)
    //          po@48(33.5) pm@82 pl@83 ctx_h@84(4) ctx_l@88(4) qh@92 ql@96 kh@100 kl@104 vh@108 vl@112 (4 each)
    __hip_bfloat16* xn_h  = (__hip_bfloat16*)(ws + 0 * MB);
    __hip_bfloat16* xn_l  = (__hip_bfloat16*)(ws + 4 * MB);
    float*          qkv   = (float*)(ws + 8 * MB);
    __hip_bfloat16* WqT_h = (__hip_bfloat16*)(ws + 32 * MB);
    __hip_bfloat16* WqT_l = (__hip_bfloat16*)(ws + 38 * MB);
    __hip_bfloat16* woT_h = (__hip_bfloat16*)(ws + 44 * MB);
    __hip_bfloat16* woT_l = (__hip_bfloat16*)(ws + 46 * MB);
    float*          po    = (float*)(ws + 48 * MB);
    float*          pm    = (float*)(ws + 82 * MB);
    float*          plb   = (float*)(ws + 83 * MB);
    __hip_bfloat16* ctx_h = (__hip_bfloat16*)(ws + 84 * MB);
    __hip_bfloat16* ctx_l = (__hip_bfloat16*)(ws + 88 * MB);
    __hip_bfloat16* qhb   = (__hip_bfloat16*)(ws + 92 * MB);
    __hip_bfloat16* qlb   = (__hip_bfloat16*)(ws + 96 * MB);
    __hip_bfloat16* khb   = (__hip_bfloat16*)(ws + 100 * MB);
    __hip_bfloat16* klb   = (__hip_bfloat16*)(ws + 104 * MB);
    __hip_bfloat16* vhb   = (__hip_bfloat16*)(ws + 108 * MB);
    __hip_bfloat16* vlb   = (__hip_bfloat16*)(ws + 112 * MB);
    // Phase B overlay: hn@0(8) hn_bf@8(4) w1T@12(32) w3T@44(32) w2T@76(32) gact@108(16) ints@124
    float*          hn    = (float*)(ws + 0 * MB);
    __hip_bfloat16* hn_bf = (__hip_bfloat16*)(ws + 8 * MB);
    __hip_bfloat16* w1T   = (__hip_bfloat16*)(ws + 12 * MB);
    __hip_bfloat16* w3T   = (__hip_bfloat16*)(ws + 44 * MB);
    __hip_bfloat16* w2T   = (__hip_bfloat16*)(ws + 76 * MB);
    __hip_bfloat16* gact  = (__hip_bfloat16*)(ws + 108 * MB);
    int* ibase    = (int*)(ws + 124 * MB);
    int* cnt      = ibase;
    int* fill     = ibase + 8;
    int* off      = ibase + 16;
    int* topEk    = ibase + 32;                       // 4096
    int* tok_list = ibase + 32 + NASSIGN;             // 4096
    float* topW   = (float*)(ibase + 32 + 2 * NASSIGN);
    float* wA     = (float*)(ibase + 32 + 3 * NASSIGN);

    // ---- attention half ----
    dim3 tg(HS / 32, HS / 32);
    transpose_split<<<tg, 256, 0, stream>>>(wq, WqT_h, WqT_l, HS, HS, 0);
    transpose_split<<<tg, 256, 0, stream>>>(wk, WqT_h, WqT_l, HS, HS, 1024);
    transpose_split<<<tg, 256, 0, stream>>>(wv, WqT_h, WqT_l, HS, HS, 2048);
    transpose_split<<<tg, 256, 0, stream>>>(wo, woT_h, woT_l, HS, HS, 0);
    rmsnorm_split<<<NTOK, 256, 0, stream>>>(x, anw, xn_h, xn_l);

    gemm_bf16x3<<<dim3(QKVW / 128, NTOK / 128), 256, 0, stream>>>(
        xn_h, xn_l, WqT_h, WqT_l, nullptr, qkv, NTOK, QKVW, HS);
    rope_convert<<<NTOK, 256, 0, stream>>>(qkv, fc, qhb, qlb, khb, klb, vhb, vlb);

    attn_partial<<<dim3(4, 16, 32), 256, 0, stream>>>(qhb, qlb, khb, klb, vhb, vlb, po, pm, plb);
    attn_merge<<<dim3(16, 16, 2), 256, 0, stream>>>(po, pm, plb, ctx_h, ctx_l);

    gemm_bf16x3<<<dim3(HS / 128, NTOK / 128), 256, 0, stream>>>(
        ctx_h, ctx_l, woT_h, woT_l, x, out, NTOK, HS, HS);   // out = h = x + ctx@wo

    // ---- MoE half (routed top-2, bf16 MFMA experts) ----
    rmsnorm_dual<<<NTOK, 256, 0, stream>>>(out, fnw, hn, hn_bf);
    transpose_bf16<<<dim3(IS / 32, HS / 32, NEXP), 256, 0, stream>>>(w1, w1T, HS, IS);
    transpose_bf16<<<dim3(IS / 32, HS / 32, NEXP), 256, 0, stream>>>(w3, w3T, HS, IS);
    transpose_bf16<<<dim3(HS / 32, IS / 32, NEXP), 256, 0, stream>>>(w2, w2T, IS, HS);

    hipMemsetAsync(cnt, 0, 16 * sizeof(int), stream);   // cnt + fill
    router_kernel<<<NTOK, 64, 0, stream>>>(hn, rw, cnt, topEk, topW);
    offsets_kernel<<<1, 64, 0, stream>>>(cnt, off);
    scatter_kernel<<<NASSIGN / 256, 256, 0, stream>>>(topEk, fill, off, topW, tok_list, wA);

    dim3 gup(IS / 128, NASSIGN / 128, NEXP);
    moe_up_mfma<<<gup, 256, 0, stream>>>(hn_bf, w1T, w3T, gact, cnt, off, tok_list);
    dim3 gdn(HS / 128, NASSIGN / 128, NEXP);
    moe_down_mfma<<<gdn, 256, 0, stream>>>(gact, w2T, out, cnt, off, tok_list, wA);
}

// Round 6
// 685.426 us; speedup vs baseline: 6.7141x; 1.0687x over previous
//
#include <hip/hip_runtime.h>
#include <hip/hip_bf16.h>
#include <math.h>

#define HS 1024      // hidden size
#define IS 2048      // intermediate size
#define NHEAD 16
#define HDIM 64
#define NEXP 8
#define BATCH 2
#define SEQ 1024
#define NTOK (BATCH*SEQ)     // 2048 tokens
#define NASSIGN (NTOK*2)     // 4096 (token, expert) assignments
#define QKVW 3072            // fused qkv row width
#define PAD 72               // LDS row stride for attn (bf16 elems)
#define MAXBLK 40            // max 128-row blocks over all experts (32 + 8 padding)

typedef short bf16x8 __attribute__((ext_vector_type(8)));
typedef float f32x4  __attribute__((ext_vector_type(4)));

// async global->LDS, 16B per lane; lds base must be wave-uniform (dest = base + lane*16)
__device__ __forceinline__ void ldsdma16(void* lds, const void* gp) {
    __builtin_amdgcn_global_load_lds(
        (const __attribute__((address_space(1))) void*)gp,
        (__attribute__((address_space(3))) void*)lds, 16, 0, 0);
}

// ---------------------------------------------------------------- rmsnorm -> split bf16 (hi+lo)
__global__ void rmsnorm_split(const float* __restrict__ x, const float* __restrict__ w,
                              __hip_bfloat16* __restrict__ oh, __hip_bfloat16* __restrict__ ol) {
    int t = blockIdx.x;
    int tid = threadIdx.x;
    const float* row = x + (size_t)t * HS;
    float ss = 0.f;
    for (int i = tid; i < HS; i += 256) { float v = row[i]; ss += v * v; }
    for (int off = 32; off > 0; off >>= 1) ss += __shfl_down(ss, off);
    __shared__ float red[4];
    if ((tid & 63) == 0) red[tid >> 6] = ss;
    __syncthreads();
    float tot = red[0] + red[1] + red[2] + red[3];
    float rr = rsqrtf(tot / (float)HS + 1e-6f);
    for (int i = tid; i < HS; i += 256) {
        float v = w[i] * row[i] * rr;
        __hip_bfloat16 hi = __float2bfloat16(v);
        oh[(size_t)t * HS + i] = hi;
        ol[(size_t)t * HS + i] = __float2bfloat16(v - __bfloat162float(hi));
    }
}

// ---------------------------------------------------------------- rmsnorm dual (fp32 + bf16)
__global__ void rmsnorm_dual(const float* __restrict__ x, const float* __restrict__ w,
                             float* __restrict__ outf, __hip_bfloat16* __restrict__ outb) {
    int t = blockIdx.x;
    int tid = threadIdx.x;
    const float* row = x + (size_t)t * HS;
    float ss = 0.f;
    for (int i = tid; i < HS; i += 256) { float v = row[i]; ss += v * v; }
    for (int off = 32; off > 0; off >>= 1) ss += __shfl_down(ss, off);
    __shared__ float red[4];
    if ((tid & 63) == 0) red[tid >> 6] = ss;
    __syncthreads();
    float tot = red[0] + red[1] + red[2] + red[3];
    float rr = rsqrtf(tot / (float)HS + 1e-6f);
    for (int i = tid; i < HS; i += 256) {
        float v = w[i] * row[i] * rr;
        outf[(size_t)t * HS + i] = v;
        outb[(size_t)t * HS + i] = __float2bfloat16(v);
    }
}

// ---------------------------------------------------------------- transpose fp32 [R][C] -> split bf16 [C][R]
__global__ void transpose_split(const float* __restrict__ src,
                                __hip_bfloat16* __restrict__ dh, __hip_bfloat16* __restrict__ dl,
                                int R, int C, int rowOff) {
    __shared__ float tile[32][33];
    int c0 = blockIdx.x * 32, r0 = blockIdx.y * 32;
    int tx = threadIdx.x & 31, ty = threadIdx.x >> 5;  // 0..7
    #pragma unroll
    for (int i = 0; i < 4; i++) {
        int r = ty + i * 8;
        tile[r][tx] = src[(size_t)(r0 + r) * C + c0 + tx];
    }
    __syncthreads();
    #pragma unroll
    for (int i = 0; i < 4; i++) {
        int c = ty + i * 8;
        float v = tile[tx][c];
        __hip_bfloat16 hi = __float2bfloat16(v);
        size_t o = (size_t)(rowOff + c0 + c) * R + r0 + tx;
        dh[o] = hi;
        dl[o] = __float2bfloat16(v - __bfloat162float(hi));
    }
}

// ---------------------------------------------------------------- transpose fp32 [R][C] -> bf16 [C][R], per expert z
__global__ void transpose_bf16(const float* __restrict__ in, __hip_bfloat16* __restrict__ outp,
                               int R, int C) {
    __shared__ float tile[32][33];
    int e = blockIdx.z;
    const float* src = in + (size_t)e * R * C;
    __hip_bfloat16* dst = outp + (size_t)e * R * C;
    int c0 = blockIdx.x * 32, r0 = blockIdx.y * 32;
    int tx = threadIdx.x & 31, ty = threadIdx.x >> 5;
    #pragma unroll
    for (int i = 0; i < 4; i++) {
        int r = ty + i * 8;
        tile[r][tx] = src[(size_t)(r0 + r) * C + c0 + tx];
    }
    __syncthreads();
    #pragma unroll
    for (int i = 0; i < 4; i++) {
        int c = ty + i * 8;
        dst[(size_t)(c0 + c) * R + r0 + tx] = __float2bfloat16(tile[tx][c]);
    }
}

// ---------------------------------------------------------------- split-bf16 GEMM (fp32-grade), global_load_lds staging
// C[M][N] = (Ah+Al)[M][K] @ (Bh+Bl)[N][K]^T (+resid), via Ah@Bh + Ah@Bl + Al@Bh
__global__ __launch_bounds__(256) void gemm_bf16x3(const __hip_bfloat16* __restrict__ Ah,
                                                   const __hip_bfloat16* __restrict__ Al,
                                                   const __hip_bfloat16* __restrict__ Bh,
                                                   const __hip_bfloat16* __restrict__ Bl,
                                                   const float* __restrict__ resid,
                                                   float* __restrict__ C,
                                                   int M, int N, int K) {
    __shared__ __align__(16) short Ahs[128][32];
    __shared__ __align__(16) short Als[128][32];
    __shared__ __align__(16) short Bhs[128][32];
    __shared__ __align__(16) short Bls[128][32];
    int bm = blockIdx.y * 128, bn = blockIdx.x * 128;
    int t = threadIdx.x;
    int wave = t >> 6, lane = t & 63;
    int wm = (wave & 1) * 64, wn = (wave >> 1) * 64;
    int fr = lane & 15, quad = lane >> 4;
    // staging: wave covers rows [wave*32, wave*32+32) per buffer, 2 dma per buffer
    int r0 = wave * 32;
    int srow = lane >> 2;                          // 0..15 within 16-row chunk
    int schunk = (lane & 3) ^ ((lane >> 3) & 3);   // xor-swizzled 16B chunk
    const __hip_bfloat16* pAh0 = Ah + (size_t)(bm + r0 + srow) * K + schunk * 8;
    const __hip_bfloat16* pAh1 = pAh0 + (size_t)16 * K;
    const __hip_bfloat16* pAl0 = Al + (size_t)(bm + r0 + srow) * K + schunk * 8;
    const __hip_bfloat16* pAl1 = pAl0 + (size_t)16 * K;
    const __hip_bfloat16* pBh0 = Bh + (size_t)(bn + r0 + srow) * K + schunk * 8;
    const __hip_bfloat16* pBh1 = pBh0 + (size_t)16 * K;
    const __hip_bfloat16* pBl0 = Bl + (size_t)(bn + r0 + srow) * K + schunk * 8;
    const __hip_bfloat16* pBl1 = pBl0 + (size_t)16 * K;
    int ca = (quad ^ ((fr >> 1) & 3)) * 8;         // swizzled frag col (shorts)

    f32x4 acc[4][4] = {};
    for (int k0 = 0; k0 < K; k0 += 32) {
        ldsdma16(&Ahs[r0][0],      pAh0 + k0);
        ldsdma16(&Ahs[r0 + 16][0], pAh1 + k0);
        ldsdma16(&Als[r0][0],      pAl0 + k0);
        ldsdma16(&Als[r0 + 16][0], pAl1 + k0);
        ldsdma16(&Bhs[r0][0],      pBh0 + k0);
        ldsdma16(&Bhs[r0 + 16][0], pBh1 + k0);
        ldsdma16(&Bls[r0][0],      pBl0 + k0);
        ldsdma16(&Bls[r0 + 16][0], pBl1 + k0);
        __syncthreads();
        bf16x8 ah[4], bh[4], x[4];
        #pragma unroll
        for (int i = 0; i < 4; i++) {
            ah[i] = *(const bf16x8*)&Ahs[wm + i * 16 + fr][ca];
            bh[i] = *(const bf16x8*)&Bhs[wn + i * 16 + fr][ca];
        }
        #pragma unroll
        for (int mi = 0; mi < 4; mi++)
            #pragma unroll
            for (int ni = 0; ni < 4; ni++)
                acc[mi][ni] = __builtin_amdgcn_mfma_f32_16x16x32_bf16(ah[mi], bh[ni], acc[mi][ni], 0, 0, 0);
        #pragma unroll
        for (int i = 0; i < 4; i++) x[i] = *(const bf16x8*)&Bls[wn + i * 16 + fr][ca];
        #pragma unroll
        for (int mi = 0; mi < 4; mi++)
            #pragma unroll
            for (int ni = 0; ni < 4; ni++)
                acc[mi][ni] = __builtin_amdgcn_mfma_f32_16x16x32_bf16(ah[mi], x[ni], acc[mi][ni], 0, 0, 0);
        #pragma unroll
        for (int i = 0; i < 4; i++) x[i] = *(const bf16x8*)&Als[wm + i * 16 + fr][ca];
        #pragma unroll
        for (int mi = 0; mi < 4; mi++)
            #pragma unroll
            for (int ni = 0; ni < 4; ni++)
                acc[mi][ni] = __builtin_amdgcn_mfma_f32_16x16x32_bf16(x[mi], bh[ni], acc[mi][ni], 0, 0, 0);
        __syncthreads();
    }
    int rq = quad * 4;
    #pragma unroll
    for (int mi = 0; mi < 4; mi++) {
        #pragma unroll
        for (int r = 0; r < 4; r++) {
            size_t rowo = (size_t)(bm + wm + mi * 16 + rq + r) * N + bn + wn;
            #pragma unroll
            for (int ni = 0; ni < 4; ni++) {
                float v = acc[mi][ni][r];
                size_t o = rowo + ni * 16 + fr;
                if (resid) v += resid[o];
                C[o] = v;
            }
        }
    }
}

// ---------------------------------------------------------------- RoPE + convert qkv fp32 -> split bf16 q,k,v
__global__ void rope_convert(const float* __restrict__ qkv, const float* __restrict__ fc,
                             __hip_bfloat16* __restrict__ qh, __hip_bfloat16* __restrict__ ql,
                             __hip_bfloat16* __restrict__ kh, __hip_bfloat16* __restrict__ kl,
                             __hip_bfloat16* __restrict__ vh, __hip_bfloat16* __restrict__ vl) {
    int t = blockIdx.x;
    int s = t & (SEQ - 1);
    const float* row = qkv + (size_t)t * QKVW;
    size_t ob = (size_t)t * HS;
    for (int p = threadIdx.x; p < 512; p += 256) {
        int hh = p >> 5, j = p & 31;
        int col = hh * 64 + 2 * j;
        float cr = fc[s * HDIM + 2 * j];
        float ci = fc[s * HDIM + 2 * j + 1];
        float a = row[col], b = row[col + 1];
        float r0 = a * cr - b * ci, r1 = a * ci + b * cr;
        __hip_bfloat16 h0 = __float2bfloat16(r0), h1 = __float2bfloat16(r1);
        qh[ob + col] = h0;     ql[ob + col]     = __float2bfloat16(r0 - __bfloat162float(h0));
        qh[ob + col + 1] = h1; ql[ob + col + 1] = __float2bfloat16(r1 - __bfloat162float(h1));
        a = row[1024 + col]; b = row[1024 + col + 1];
        r0 = a * cr - b * ci; r1 = a * ci + b * cr;
        h0 = __float2bfloat16(r0); h1 = __float2bfloat16(r1);
        kh[ob + col] = h0;     kl[ob + col]     = __float2bfloat16(r0 - __bfloat162float(h0));
        kh[ob + col + 1] = h1; kl[ob + col + 1] = __float2bfloat16(r1 - __bfloat162float(h1));
        r0 = row[2048 + col]; r1 = row[2048 + col + 1];
        h0 = __float2bfloat16(r0); h1 = __float2bfloat16(r1);
        vh[ob + col] = h0;     vl[ob + col]     = __float2bfloat16(r0 - __bfloat162float(h0));
        vh[ob + col + 1] = h1; vl[ob + col + 1] = __float2bfloat16(r1 - __bfloat162float(h1));
    }
}

// ---------------------------------------------------------------- split-K flash attention, MFMA split-bf16
__global__ __launch_bounds__(256) void attn_partial(
        const __hip_bfloat16* __restrict__ qh, const __hip_bfloat16* __restrict__ ql,
        const __hip_bfloat16* __restrict__ kh, const __hip_bfloat16* __restrict__ kl,
        const __hip_bfloat16* __restrict__ vh, const __hip_bfloat16* __restrict__ vl,
        float* __restrict__ po, float* __restrict__ pm_g, float* __restrict__ pl_g) {
    int c = blockIdx.x, qt = blockIdx.y;
    int nc = (qt + 4) >> 2;
    if (c >= nc) return;
    int bh = blockIdx.z;
    int b = bh >> 4, h = bh & 15;
    int t0 = c * 4, t1 = min(t0 + 4, qt + 1);
    int tid = threadIdx.x;
    int wave = tid >> 6, lane = tid & 63;
    int fr = lane & 15, quad = lane >> 4;
    int w16 = wave * 16;
    __shared__ __align__(16) short Qh[64][PAD], Ql[64][PAD];
    __shared__ __align__(16) short KPh[64][PAD], KPl[64][PAD];
    __shared__ __align__(16) short Vhs[64][PAD], Vls[64][PAD];
    size_t hoff = (size_t)h * HDIM;
    int sr = tid >> 2, sg = tid & 3;
    {
        const __hip_bfloat16* qp  = qh + (size_t)(b * SEQ + qt * 64 + sr) * HS + hoff;
        const __hip_bfloat16* qp2 = ql + (size_t)(b * SEQ + qt * 64 + sr) * HS + hoff;
        *(uint4*)&Qh[sr][sg * 8]       = *(const uint4*)(qp + sg * 8);
        *(uint4*)&Qh[sr][(sg + 4) * 8] = *(const uint4*)(qp + (sg + 4) * 8);
        *(uint4*)&Ql[sr][sg * 8]       = *(const uint4*)(qp2 + sg * 8);
        *(uint4*)&Ql[sr][(sg + 4) * 8] = *(const uint4*)(qp2 + (sg + 4) * 8);
    }
    f32x4 o[4] = {};
    float mrow[4], lrow[4];
    #pragma unroll
    for (int i = 0; i < 4; i++) { mrow[i] = -1e30f; lrow[i] = 0.f; }
    int key0 = (tid & 31) * 2, ds = tid >> 5;
    __syncthreads();

    for (int kt = t0; kt < t1; kt++) {
        int kbase = kt * 64;
        {
            const __hip_bfloat16* kp  = kh + (size_t)(b * SEQ + kbase + sr) * HS + hoff;
            const __hip_bfloat16* kp2 = kl + (size_t)(b * SEQ + kbase + sr) * HS + hoff;
            *(uint4*)&KPh[sr][sg * 8]       = *(const uint4*)(kp + sg * 8);
            *(uint4*)&KPh[sr][(sg + 4) * 8] = *(const uint4*)(kp + (sg + 4) * 8);
            *(uint4*)&KPl[sr][sg * 8]       = *(const uint4*)(kp2 + sg * 8);
            *(uint4*)&KPl[sr][(sg + 4) * 8] = *(const uint4*)(kp2 + (sg + 4) * 8);
        }
        {
            const __hip_bfloat16* v0 = vh + (size_t)(b * SEQ + kbase + key0) * HS + hoff + ds * 8;
            uint4 A = *(const uint4*)v0;
            uint4 Bv = *(const uint4*)(v0 + HS);
            const unsigned short* ap = (const unsigned short*)&A;
            const unsigned short* bp = (const unsigned short*)&Bv;
            #pragma unroll
            for (int j = 0; j < 8; j++)
                *(unsigned*)&Vhs[ds * 8 + j][key0] = (unsigned)ap[j] | ((unsigned)bp[j] << 16);
            const __hip_bfloat16* v2 = vl + (size_t)(b * SEQ + kbase + key0) * HS + hoff + ds * 8;
            uint4 A2 = *(const uint4*)v2;
            uint4 B2 = *(const uint4*)(v2 + HS);
            const unsigned short* ap2 = (const unsigned short*)&A2;
            const unsigned short* bp2 = (const unsigned short*)&B2;
            #pragma unroll
            for (int j = 0; j < 8; j++)
                *(unsigned*)&Vls[ds * 8 + j][key0] = (unsigned)ap2[j] | ((unsigned)bp2[j] << 16);
        }
        __syncthreads();

        f32x4 s[4] = {};
        #pragma unroll
        for (int ks = 0; ks < 2; ks++) {
            bf16x8 a_h = *(const bf16x8*)&Qh[w16 + fr][quad * 8 + ks * 32];
            bf16x8 a_l = *(const bf16x8*)&Ql[w16 + fr][quad * 8 + ks * 32];
            #pragma unroll
            for (int ni = 0; ni < 4; ni++) {
                bf16x8 b_h = *(const bf16x8*)&KPh[ni * 16 + fr][quad * 8 + ks * 32];
                bf16x8 b_l = *(const bf16x8*)&KPl[ni * 16 + fr][quad * 8 + ks * 32];
                s[ni] = __builtin_amdgcn_mfma_f32_16x16x32_bf16(a_h, b_h, s[ni], 0, 0, 0);
                s[ni] = __builtin_amdgcn_mfma_f32_16x16x32_bf16(a_h, b_l, s[ni], 0, 0, 0);
                s[ni] = __builtin_amdgcn_mfma_f32_16x16x32_bf16(a_l, b_h, s[ni], 0, 0, 0);
            }
        }
        int qg = qt * 64 + w16 + quad * 4;
        #pragma unroll
        for (int ni = 0; ni < 4; ni++) {
            int kg = kbase + ni * 16 + fr;
            #pragma unroll
            for (int r = 0; r < 4; r++)
                s[ni][r] = (kg > qg + r) ? -1e9f : s[ni][r] * 0.125f;
        }
        #pragma unroll
        for (int r = 0; r < 4; r++) {
            float mx = fmaxf(fmaxf(s[0][r], s[1][r]), fmaxf(s[2][r], s[3][r]));
            #pragma unroll
            for (int wd = 1; wd < 16; wd <<= 1) mx = fmaxf(mx, __shfl_xor(mx, wd));
            float nm = fmaxf(mrow[r], mx);
            float alpha = __expf(mrow[r] - nm);
            float rs = 0.f;
            #pragma unroll
            for (int ni = 0; ni < 4; ni++) { float e = __expf(s[ni][r] - nm); s[ni][r] = e; rs += e; }
            #pragma unroll
            for (int wd = 1; wd < 16; wd <<= 1) rs += __shfl_xor(rs, wd);
            lrow[r] = lrow[r] * alpha + rs;
            mrow[r] = nm;
            o[0][r] *= alpha; o[1][r] *= alpha; o[2][r] *= alpha; o[3][r] *= alpha;
        }
        __syncthreads();
        #pragma unroll
        for (int ni = 0; ni < 4; ni++)
            #pragma unroll
            for (int r = 0; r < 4; r++) {
                float pv = s[ni][r];
                __hip_bfloat16 hi = __float2bfloat16(pv);
                __hip_bfloat16 lo = __float2bfloat16(pv - __bfloat162float(hi));
                KPh[w16 + quad * 4 + r][ni * 16 + fr] = *(short*)&hi;
                KPl[w16 + quad * 4 + r][ni * 16 + fr] = *(short*)&lo;
            }
        #pragma unroll
        for (int ks = 0; ks < 2; ks++) {
            bf16x8 p_h = *(const bf16x8*)&KPh[w16 + fr][quad * 8 + ks * 32];
            bf16x8 p_l = *(const bf16x8*)&KPl[w16 + fr][quad * 8 + ks * 32];
            #pragma unroll
            for (int ni = 0; ni < 4; ni++) {
                bf16x8 v_h = *(const bf16x8*)&Vhs[ni * 16 + fr][quad * 8 + ks * 32];
                bf16x8 v_l = *(const bf16x8*)&Vls[ni * 16 + fr][quad * 8 + ks * 32];
                o[ni] = __builtin_amdgcn_mfma_f32_16x16x32_bf16(p_h, v_h, o[ni], 0, 0, 0);
                o[ni] = __builtin_amdgcn_mfma_f32_16x16x32_bf16(p_h, v_l, o[ni], 0, 0, 0);
                o[ni] = __builtin_amdgcn_mfma_f32_16x16x32_bf16(p_l, v_h, o[ni], 0, 0, 0);
            }
        }
        __syncthreads();
    }
    int pidx = (bh * 16 + qt) * 4 + c;
    float* pob = po + (size_t)pidx * 4096;
    #pragma unroll
    for (int ni = 0; ni < 4; ni++)
        #pragma unroll
        for (int r = 0; r < 4; r++)
            pob[(w16 + quad * 4 + r) * 64 + ni * 16 + fr] = o[ni][r];
    if (fr == 0) {
        #pragma unroll
        for (int r = 0; r < 4; r++) {
            pm_g[pidx * 64 + w16 + quad * 4 + r] = mrow[r];
            pl_g[pidx * 64 + w16 + quad * 4 + r] = lrow[r];
        }
    }
}

// ---------------------------------------------------------------- merge partials -> ctx as split bf16
__global__ void attn_merge(const float* __restrict__ po, const float* __restrict__ pm,
                           const float* __restrict__ pl,
                           __hip_bfloat16* __restrict__ ch, __hip_bfloat16* __restrict__ cl) {
    int qt = blockIdx.x, h = blockIdx.y, b = blockIdx.z;
    int bh = b * 16 + h;
    int nc = (qt + 4) >> 2;
    int base = (bh * 16 + qt) * 4;
    int tid = threadIdx.x;
    int r  = tid >> 2;
    int d0 = (tid & 3) * 16;
    float mstar = -1e30f;
    for (int c = 0; c < nc; c++) mstar = fmaxf(mstar, pm[(base + c) * 64 + r]);
    float a[4];
    float lsum = 0.f;
    for (int c = 0; c < nc; c++) {
        a[c] = __expf(pm[(base + c) * 64 + r] - mstar);
        lsum += a[c] * pl[(base + c) * 64 + r];
    }
    float inv = 1.f / lsum;
    size_t crow = (size_t)(b * SEQ + qt * 64 + r) * HS + h * HDIM;
    for (int dd = 0; dd < 16; dd += 4) {
        float4 acc = make_float4(0.f, 0.f, 0.f, 0.f);
        for (int c = 0; c < nc; c++) {
            float4 v = *(const float4*)(po + (size_t)(base + c) * 4096 + r * 64 + d0 + dd);
            acc.x += a[c] * v.x; acc.y += a[c] * v.y;
            acc.z += a[c] * v.z; acc.w += a[c] * v.w;
        }
        float vs[4] = {acc.x * inv, acc.y * inv, acc.z * inv, acc.w * inv};
        #pragma unroll
        for (int j = 0; j < 4; j++) {
            __hip_bfloat16 hi = __float2bfloat16(vs[j]);
            ch[crow + d0 + dd + j] = hi;
            cl[crow + d0 + dd + j] = __float2bfloat16(vs[j] - __bfloat162float(hi));
        }
    }
}

// ---------------------------------------------------------------- router (per-token top2)
__global__ void router_kernel(const float* __restrict__ hn, const float* __restrict__ rw,
                              int* __restrict__ cnt, int* __restrict__ topEk,
                              float* __restrict__ topW) {
    int t = blockIdx.x;
    int lane = threadIdx.x;
    float acc[NEXP];
    #pragma unroll
    for (int e = 0; e < NEXP; e++) acc[e] = 0.f;
    const float* row = hn + (size_t)t * HS;
    for (int kk = lane; kk < HS; kk += 64) {
        float xv = row[kk];
        const float* r = rw + (size_t)kk * NEXP;
        #pragma unroll
        for (int e = 0; e < NEXP; e++) acc[e] += xv * r[e];
    }
    #pragma unroll
    for (int e = 0; e < NEXP; e++)
        for (int off = 32; off > 0; off >>= 1) acc[e] += __shfl_down(acc[e], off);
    if (lane == 0) {
        float mx = acc[0];
        #pragma unroll
        for (int e = 1; e < NEXP; e++) mx = fmaxf(mx, acc[e]);
        float p[NEXP]; float s = 0.f;
        #pragma unroll
        for (int e = 0; e < NEXP; e++) { p[e] = __expf(acc[e] - mx); s += p[e]; }
        int i0 = 0;
        #pragma unroll
        for (int e = 1; e < NEXP; e++) if (p[e] > p[i0]) i0 = e;
        int i1 = (i0 == 0) ? 1 : 0;
        #pragma unroll
        for (int e = 0; e < NEXP; e++) if (e != i0 && p[e] > p[i1]) i1 = e;
        float v0 = p[i0], v1 = p[i1], sn = v0 + v1;
        topEk[2 * t]     = i0; topW[2 * t]     = v0 / sn;
        topEk[2 * t + 1] = i1; topW[2 * t + 1] = v1 / sn;
        atomicAdd(&cnt[i0], 1);
        atomicAdd(&cnt[i1], 1);
    }
}

// ---------------------------------------------------------------- offsets + block table
__global__ void offsets_kernel(const int* __restrict__ cnt, int* __restrict__ off,
                               int* __restrict__ blk_e, int* __restrict__ blk_r) {
    if (threadIdx.x == 0) {
        int o = 0, n = 0;
        for (int e = 0; e < NEXP; e++) {
            off[e] = o;
            for (int bm = 0; bm < cnt[e]; bm += 128) { blk_e[n] = e; blk_r[n] = bm; n++; }
            o += cnt[e];
        }
        for (; n < MAXBLK; n++) { blk_e[n] = -1; blk_r[n] = 0; }
    }
}

__global__ void scatter_kernel(const int* __restrict__ topEk, int* __restrict__ fill,
                               const int* __restrict__ off, const float* __restrict__ topW,
                               int* __restrict__ tok_list, float* __restrict__ wA) {
    int idx = blockIdx.x * 256 + threadIdx.x;
    int e = topEk[idx];
    int slot = atomicAdd(&fill[e], 1);
    int gidx = off[e] + slot;
    tok_list[gidx] = idx >> 1;
    wA[gidx] = topW[idx];
}

// ---------------------------------------------------------------- MoE up-proj, bf16 MFMA + global_load_lds
__global__ __launch_bounds__(256) void moe_up_mfma(const __hip_bfloat16* __restrict__ Abf,
                                                   const __hip_bfloat16* __restrict__ B1T,
                                                   const __hip_bfloat16* __restrict__ B3T,
                                                   __hip_bfloat16* __restrict__ g,
                                                   const int* __restrict__ cnt,
                                                   const int* __restrict__ off,
                                                   const int* __restrict__ tok_list,
                                                   const int* __restrict__ blk_e,
                                                   const int* __restrict__ blk_r) {
    int e = blk_e[blockIdx.y];
    if (e < 0) return;
    int bm = blk_r[blockIdx.y];
    int ce = cnt[e], oe = off[e];
    int bn = blockIdx.x * 128;
    const __hip_bfloat16* b1 = B1T + (size_t)e * IS * HS;   // [IS][HS]
    const __hip_bfloat16* b3 = B3T + (size_t)e * IS * HS;

    __shared__ __align__(16) short As[128][32];
    __shared__ __align__(16) short B1s[128][32];
    __shared__ __align__(16) short B3s[128][32];

    int t = threadIdx.x;
    int wave = t >> 6, lane = t & 63;
    int wm = (wave & 1) * 64, wn = (wave >> 1) * 64;
    int fr = lane & 15, quad = lane >> 4;
    int r0 = wave * 32;
    int srow = lane >> 2;
    int schunk = (lane & 3) ^ ((lane >> 3) & 3);
    int tokA0 = tok_list[oe + min(bm + r0 + srow, ce - 1)];
    int tokA1 = tok_list[oe + min(bm + r0 + 16 + srow, ce - 1)];
    const __hip_bfloat16* pA0 = Abf + (size_t)tokA0 * HS + schunk * 8;
    const __hip_bfloat16* pA1 = Abf + (size_t)tokA1 * HS + schunk * 8;
    const __hip_bfloat16* pB1a = b1 + (size_t)(bn + r0 + srow) * HS + schunk * 8;
    const __hip_bfloat16* pB1b = pB1a + (size_t)16 * HS;
    const __hip_bfloat16* pB3a = b3 + (size_t)(bn + r0 + srow) * HS + schunk * 8;
    const __hip_bfloat16* pB3b = pB3a + (size_t)16 * HS;
    int ca = (quad ^ ((fr >> 1) & 3)) * 8;

    f32x4 acc1[4][4] = {};
    f32x4 acc3[4][4] = {};

    for (int k0 = 0; k0 < HS; k0 += 32) {
        ldsdma16(&As[r0][0],       pA0 + k0);
        ldsdma16(&As[r0 + 16][0],  pA1 + k0);
        ldsdma16(&B1s[r0][0],      pB1a + k0);
        ldsdma16(&B1s[r0 + 16][0], pB1b + k0);
        ldsdma16(&B3s[r0][0],      pB3a + k0);
        ldsdma16(&B3s[r0 + 16][0], pB3b + k0);
        __syncthreads();
        bf16x8 a[4], f1[4], f3[4];
        #pragma unroll
        for (int i = 0; i < 4; i++) {
            a[i]  = *(const bf16x8*)&As[wm + i * 16 + fr][ca];
            f1[i] = *(const bf16x8*)&B1s[wn + i * 16 + fr][ca];
            f3[i] = *(const bf16x8*)&B3s[wn + i * 16 + fr][ca];
        }
        #pragma unroll
        for (int mi = 0; mi < 4; mi++)
            #pragma unroll
            for (int ni = 0; ni < 4; ni++) {
                acc1[mi][ni] = __builtin_amdgcn_mfma_f32_16x16x32_bf16(a[mi], f1[ni], acc1[mi][ni], 0, 0, 0);
                acc3[mi][ni] = __builtin_amdgcn_mfma_f32_16x16x32_bf16(a[mi], f3[ni], acc3[mi][ni], 0, 0, 0);
            }
        __syncthreads();
    }
    int rq = quad * 4;
    #pragma unroll
    for (int mi = 0; mi < 4; mi++) {
        #pragma unroll
        for (int r = 0; r < 4; r++) {
            int slot = bm + wm + mi * 16 + rq + r;
            if (slot < ce) {
                size_t rowo = (size_t)(oe + slot) * IS + bn + wn;
                #pragma unroll
                for (int ni = 0; ni < 4; ni++) {
                    float x1 = acc1[mi][ni][r];
                    float x3 = acc3[mi][ni][r];
                    float sv = (x1 / (1.f + __expf(-x1))) * x3;
                    g[rowo + ni * 16 + fr] = __float2bfloat16(sv);
                }
            }
        }
    }
}

// ---------------------------------------------------------------- MoE down-proj, bf16 MFMA + global_load_lds
__global__ __launch_bounds__(256) void moe_down_mfma(const __hip_bfloat16* __restrict__ g,
                                                     const __hip_bfloat16* __restrict__ B2T,
                                                     float* __restrict__ out,
                                                     const int* __restrict__ cnt,
                                                     const int* __restrict__ off,
                                                     const int* __restrict__ tok_list,
                                                     const float* __restrict__ wA,
                                                     const int* __restrict__ blk_e,
                                                     const int* __restrict__ blk_r) {
    int e = blk_e[blockIdx.y];
    if (e < 0) return;
    int bm = blk_r[blockIdx.y];
    int ce = cnt[e], oe = off[e];
    int bn = blockIdx.x * 128;
    const __hip_bfloat16* b2 = B2T + (size_t)e * HS * IS;   // [HS][IS]

    __shared__ __align__(16) short As[128][32];
    __shared__ __align__(16) short Bs[128][32];

    int t = threadIdx.x;
    int wave = t >> 6, lane = t & 63;
    int wm = (wave & 1) * 64, wn = (wave >> 1) * 64;
    int fr = lane & 15, quad = lane >> 4;
    int r0 = wave * 32;
    int srow = lane >> 2;
    int schunk = (lane & 3) ^ ((lane >> 3) & 3);
    int ga0 = oe + min(bm + r0 + srow, ce - 1);
    int ga1 = oe + min(bm + r0 + 16 + srow, ce - 1);
    const __hip_bfloat16* pA0 = g + (size_t)ga0 * IS + schunk * 8;
    const __hip_bfloat16* pA1 = g + (size_t)ga1 * IS + schunk * 8;
    const __hip_bfloat16* pBa = b2 + (size_t)(bn + r0 + srow) * IS + schunk * 8;
    const __hip_bfloat16* pBb = pBa + (size_t)16 * IS;
    int ca = (quad ^ ((fr >> 1) & 3)) * 8;

    f32x4 acc[4][4] = {};

    for (int k0 = 0; k0 < IS; k0 += 32) {
        ldsdma16(&As[r0][0],      pA0 + k0);
        ldsdma16(&As[r0 + 16][0], pA1 + k0);
        ldsdma16(&Bs[r0][0],      pBa + k0);
        ldsdma16(&Bs[r0 + 16][0], pBb + k0);
        __syncthreads();
        bf16x8 a[4], f[4];
        #pragma unroll
        for (int i = 0; i < 4; i++) {
            a[i] = *(const bf16x8*)&As[wm + i * 16 + fr][ca];
            f[i] = *(const bf16x8*)&Bs[wn + i * 16 + fr][ca];
        }
        #pragma unroll
        for (int mi = 0; mi < 4; mi++)
            #pragma unroll
            for (int ni = 0; ni < 4; ni++)
                acc[mi][ni] = __builtin_amdgcn_mfma_f32_16x16x32_bf16(a[mi], f[ni], acc[mi][ni], 0, 0, 0);
        __syncthreads();
    }
    int rq = quad * 4;
    #pragma unroll
    for (int mi = 0; mi < 4; mi++) {
        #pragma unroll
        for (int r = 0; r < 4; r++) {
            int slot = bm + wm + mi * 16 + rq + r;
            if (slot < ce) {
                int gidx = oe + slot;
                int tok = tok_list[gidx];
                float wgt = wA[gidx];
                size_t rowo = (size_t)tok * HS + bn + wn;
                #pragma unroll
                for (int ni = 0; ni < 4; ni++)
                    atomicAdd(out + rowo + ni * 16 + fr, wgt * acc[mi][ni][r]);
            }
        }
    }
}

// ---------------------------------------------------------------- launch
extern "C" void kernel_launch(void* const* d_in, const int* in_sizes, int n_in,
                              void* d_out, int out_size, void* d_ws, size_t ws_size,
                              hipStream_t stream) {
    const float* x   = (const float*)d_in[0];
    const float* anw = (const float*)d_in[1];
    const float* fnw = (const float*)d_in[2];
    const float* wq  = (const float*)d_in[3];
    const float* wk  = (const float*)d_in[4];
    const float* wv  = (const float*)d_in[5];
    const float* wo  = (const float*)d_in[6];
    const float* rw  = (const float*)d_in[7];
    const float* w1  = (const float*)d_in[8];
    const float* w3  = (const float*)d_in[9];
    const float* w2  = (const float*)d_in[10];
    const float* fc  = (const float*)d_in[11];
    float* out = (float*)d_out;

    char* ws = (char*)d_ws;
    const size_t MB = 1024 * 1024;
    __hip_bfloat16* xn_h  = (__hip_bfloat16*)(ws + 0 * MB);
    __hip_bfloat16* xn_l  = (__hip_bfloat16*)(ws + 4 * MB);
    float*          qkv   = (float*)(ws + 8 * MB);
    __hip_bfloat16* WqT_h = (__hip_bfloat16*)(ws + 32 * MB);
    __hip_bfloat16* WqT_l = (__hip_bfloat16*)(ws + 38 * MB);
    __hip_bfloat16* woT_h = (__hip_bfloat16*)(ws + 44 * MB);
    __hip_bfloat16* woT_l = (__hip_bfloat16*)(ws + 46 * MB);
    float*          po    = (float*)(ws + 48 * MB);
    float*          pm    = (float*)(ws + 82 * MB);
    float*          plb   = (float*)(ws + 83 * MB);
    __hip_bfloat16* ctx_h = (__hip_bfloat16*)(ws + 84 * MB);
    __hip_bfloat16* ctx_l = (__hip_bfloat16*)(ws + 88 * MB);
    __hip_bfloat16* qhb   = (__hip_bfloat16*)(ws + 92 * MB);
    __hip_bfloat16* qlb   = (__hip_bfloat16*)(ws + 96 * MB);
    __hip_bfloat16* khb   = (__hip_bfloat16*)(ws + 100 * MB);
    __hip_bfloat16* klb   = (__hip_bfloat16*)(ws + 104 * MB);
    __hip_bfloat16* vhb   = (__hip_bfloat16*)(ws + 108 * MB);
    __hip_bfloat16* vlb   = (__hip_bfloat16*)(ws + 112 * MB);
    float*          hn    = (float*)(ws + 0 * MB);
    __hip_bfloat16* hn_bf = (__hip_bfloat16*)(ws + 8 * MB);
    __hip_bfloat16* w1T   = (__hip_bfloat16*)(ws + 12 * MB);
    __hip_bfloat16* w3T   = (__hip_bfloat16*)(ws + 44 * MB);
    __hip_bfloat16* w2T   = (__hip_bfloat16*)(ws + 76 * MB);
    __hip_bfloat16* gact  = (__hip_bfloat16*)(ws + 108 * MB);
    int* ibase    = (int*)(ws + 124 * MB);
    int* cnt      = ibase;                 // 8
    int* fill     = ibase + 8;             // 8
    int* off      = ibase + 16;            // 8
    int* blk_e    = ibase + 24;            // 40
    int* blk_r    = ibase + 64;            // 40
    int* topEk    = ibase + 128;           // 4096
    int* tok_list = ibase + 128 + NASSIGN; // 4096
    float* topW   = (float*)(ibase + 128 + 2 * NASSIGN);
    float* wA     = (float*)(ibase + 128 + 3 * NASSIGN);

    // ---- attention half ----
    dim3 tg(HS / 32, HS / 32);
    transpose_split<<<tg, 256, 0, stream>>>(wq, WqT_h, WqT_l, HS, HS, 0);
    transpose_split<<<tg, 256, 0, stream>>>(wk, WqT_h, WqT_l, HS, HS, 1024);
    transpose_split<<<tg, 256, 0, stream>>>(wv, WqT_h, WqT_l, HS, HS, 2048);
    transpose_split<<<tg, 256, 0, stream>>>(wo, woT_h, woT_l, HS, HS, 0);
    rmsnorm_split<<<NTOK, 256, 0, stream>>>(x, anw, xn_h, xn_l);

    gemm_bf16x3<<<dim3(QKVW / 128, NTOK / 128), 256, 0, stream>>>(
        xn_h, xn_l, WqT_h, WqT_l, nullptr, qkv, NTOK, QKVW, HS);
    rope_convert<<<NTOK, 256, 0, stream>>>(qkv, fc, qhb, qlb, khb, klb, vhb, vlb);

    attn_partial<<<dim3(4, 16, 32), 256, 0, stream>>>(qhb, qlb, khb, klb, vhb, vlb, po, pm, plb);
    attn_merge<<<dim3(16, 16, 2), 256, 0, stream>>>(po, pm, plb, ctx_h, ctx_l);

    gemm_bf16x3<<<dim3(HS / 128, NTOK / 128), 256, 0, stream>>>(
        ctx_h, ctx_l, woT_h, woT_l, x, out, NTOK, HS, HS);   // out = h = x + ctx@wo

    // ---- MoE half (routed top-2, bf16 MFMA experts) ----
    rmsnorm_dual<<<NTOK, 256, 0, stream>>>(out, fnw, hn, hn_bf);
    transpose_bf16<<<dim3(IS / 32, HS / 32, NEXP), 256, 0, stream>>>(w1, w1T, HS, IS);
    transpose_bf16<<<dim3(IS / 32, HS / 32, NEXP), 256, 0, stream>>>(w3, w3T, HS, IS);
    transpose_bf16<<<dim3(HS / 32, IS / 32, NEXP), 256, 0, stream>>>(w2, w2T, IS, HS);

    hipMemsetAsync(cnt, 0, 16 * sizeof(int), stream);   // cnt + fill
    router_kernel<<<NTOK, 64, 0, stream>>>(hn, rw, cnt, topEk, topW);
    offsets_kernel<<<1, 64, 0, stream>>>(cnt, off, blk_e, blk_r);
    scatter_kernel<<<NASSIGN / 256, 256, 0, stream>>>(topEk, fill, off, topW, tok_list, wA);

    moe_up_mfma<<<dim3(IS / 128, MAXBLK), 256, 0, stream>>>(
        hn_bf, w1T, w3T, gact, cnt, off, tok_list, blk_e, blk_r);
    moe_down_mfma<<<dim3(HS / 128, MAXBLK), 256, 0, stream>>>(
        gact, w2T, out, cnt, off, tok_list, wA, blk_e, blk_r);
}

// Round 7
// 671.416 us; speedup vs baseline: 6.8542x; 1.0209x over previous
//
#include <hip/hip_runtime.h>
#include <hip/hip_bf16.h>
#include <math.h>

#define HS 1024      // hidden size
#define IS 2048      // intermediate size
#define NHEAD 16
#define HDIM 64
#define NEXP 8
#define BATCH 2
#define SEQ 1024
#define NTOK (BATCH*SEQ)     // 2048 tokens
#define NASSIGN (NTOK*2)     // 4096 (token, expert) assignments
#define QKVW 3072            // fused qkv row width
#define PAD 72               // LDS row stride for attn (bf16 elems)
#define MAXBLK 40            // max 128-row blocks over all experts

typedef short bf16x8 __attribute__((ext_vector_type(8)));
typedef float f32x4  __attribute__((ext_vector_type(4)));

// async global->LDS, 16B per lane; lds dest = base + lane*16 (wave-uniform base)
__device__ __forceinline__ void ldsdma16(void* lds, const void* gp) {
    __builtin_amdgcn_global_load_lds(
        (const __attribute__((address_space(1))) void*)gp,
        (__attribute__((address_space(3))) void*)lds, 16, 0, 0);
}

// ---------------------------------------------------------------- rmsnorm -> split bf16 (hi+lo)
__global__ void rmsnorm_split(const float* __restrict__ x, const float* __restrict__ w,
                              __hip_bfloat16* __restrict__ oh, __hip_bfloat16* __restrict__ ol) {
    int t = blockIdx.x;
    int tid = threadIdx.x;
    const float* row = x + (size_t)t * HS;
    float ss = 0.f;
    for (int i = tid; i < HS; i += 256) { float v = row[i]; ss += v * v; }
    for (int off = 32; off > 0; off >>= 1) ss += __shfl_down(ss, off);
    __shared__ float red[4];
    if ((tid & 63) == 0) red[tid >> 6] = ss;
    __syncthreads();
    float tot = red[0] + red[1] + red[2] + red[3];
    float rr = rsqrtf(tot / (float)HS + 1e-6f);
    for (int i = tid; i < HS; i += 256) {
        float v = w[i] * row[i] * rr;
        __hip_bfloat16 hi = __float2bfloat16(v);
        oh[(size_t)t * HS + i] = hi;
        ol[(size_t)t * HS + i] = __float2bfloat16(v - __bfloat162float(hi));
    }
}

// ---------------------------------------------------------------- rmsnorm dual (fp32 + bf16)
__global__ void rmsnorm_dual(const float* __restrict__ x, const float* __restrict__ w,
                             float* __restrict__ outf, __hip_bfloat16* __restrict__ outb) {
    int t = blockIdx.x;
    int tid = threadIdx.x;
    const float* row = x + (size_t)t * HS;
    float ss = 0.f;
    for (int i = tid; i < HS; i += 256) { float v = row[i]; ss += v * v; }
    for (int off = 32; off > 0; off >>= 1) ss += __shfl_down(ss, off);
    __shared__ float red[4];
    if ((tid & 63) == 0) red[tid >> 6] = ss;
    __syncthreads();
    float tot = red[0] + red[1] + red[2] + red[3];
    float rr = rsqrtf(tot / (float)HS + 1e-6f);
    for (int i = tid; i < HS; i += 256) {
        float v = w[i] * row[i] * rr;
        outf[(size_t)t * HS + i] = v;
        outb[(size_t)t * HS + i] = __float2bfloat16(v);
    }
}

// ---------------------------------------------------------------- transpose fp32 [R][C] -> split bf16 [C][R]
__global__ void transpose_split(const float* __restrict__ src,
                                __hip_bfloat16* __restrict__ dh, __hip_bfloat16* __restrict__ dl,
                                int R, int C, int rowOff) {
    __shared__ float tile[32][33];
    int c0 = blockIdx.x * 32, r0 = blockIdx.y * 32;
    int tx = threadIdx.x & 31, ty = threadIdx.x >> 5;  // 0..7
    #pragma unroll
    for (int i = 0; i < 4; i++) {
        int r = ty + i * 8;
        tile[r][tx] = src[(size_t)(r0 + r) * C + c0 + tx];
    }
    __syncthreads();
    #pragma unroll
    for (int i = 0; i < 4; i++) {
        int c = ty + i * 8;
        float v = tile[tx][c];
        __hip_bfloat16 hi = __float2bfloat16(v);
        size_t o = (size_t)(rowOff + c0 + c) * R + r0 + tx;
        dh[o] = hi;
        dl[o] = __float2bfloat16(v - __bfloat162float(hi));
    }
}

// ---------------------------------------------------------------- transpose fp32 [R][C] -> bf16 [C][R], per expert z
__global__ void transpose_bf16(const float* __restrict__ in, __hip_bfloat16* __restrict__ outp,
                               int R, int C) {
    __shared__ float tile[32][33];
    int e = blockIdx.z;
    const float* src = in + (size_t)e * R * C;
    __hip_bfloat16* dst = outp + (size_t)e * R * C;
    int c0 = blockIdx.x * 32, r0 = blockIdx.y * 32;
    int tx = threadIdx.x & 31, ty = threadIdx.x >> 5;
    #pragma unroll
    for (int i = 0; i < 4; i++) {
        int r = ty + i * 8;
        tile[r][tx] = src[(size_t)(r0 + r) * C + c0 + tx];
    }
    __syncthreads();
    #pragma unroll
    for (int i = 0; i < 4; i++) {
        int c = ty + i * 8;
        dst[(size_t)(c0 + c) * R + r0 + tx] = __float2bfloat16(tile[tx][c]);
    }
}

// ---------------------------------------------------------------- split-bf16 GEMM, double-buffered DMA pipeline
// C[M][N] = (Ah+Al)[M][K] @ (Bh+Bl)[N][K]^T (+resid), via Ah@Bh + Ah@Bl + Al@Bh
__global__ __launch_bounds__(256) void gemm_bf16x3(const __hip_bfloat16* __restrict__ Ah,
                                                   const __hip_bfloat16* __restrict__ Al,
                                                   const __hip_bfloat16* __restrict__ Bh,
                                                   const __hip_bfloat16* __restrict__ Bl,
                                                   const float* __restrict__ resid,
                                                   float* __restrict__ C,
                                                   int M, int N, int K) {
    __shared__ __align__(16) short Ahs[2][128][32];   // 16 KB
    __shared__ __align__(16) short Als[2][128][32];
    __shared__ __align__(16) short Bhs[2][128][32];
    __shared__ __align__(16) short Bls[2][128][32];   // total 64 KB
    int bm = blockIdx.y * 128, bn = blockIdx.x * 128;
    int t = threadIdx.x;
    int wave = t >> 6, lane = t & 63;
    int wm = (wave & 1) * 64, wn = (wave >> 1) * 64;
    int fr = lane & 15, quad = lane >> 4;
    int r0 = wave * 32;
    int srow = lane >> 2;
    int schunk = (lane & 3) ^ ((lane >> 3) & 3);   // xor-swizzled 16B chunk
    const __hip_bfloat16* pAh0 = Ah + (size_t)(bm + r0 + srow) * K + schunk * 8;
    const __hip_bfloat16* pAh1 = pAh0 + (size_t)16 * K;
    const __hip_bfloat16* pAl0 = Al + (size_t)(bm + r0 + srow) * K + schunk * 8;
    const __hip_bfloat16* pAl1 = pAl0 + (size_t)16 * K;
    const __hip_bfloat16* pBh0 = Bh + (size_t)(bn + r0 + srow) * K + schunk * 8;
    const __hip_bfloat16* pBh1 = pBh0 + (size_t)16 * K;
    const __hip_bfloat16* pBl0 = Bl + (size_t)(bn + r0 + srow) * K + schunk * 8;
    const __hip_bfloat16* pBl1 = pBl0 + (size_t)16 * K;
    int ca = (quad ^ ((fr >> 1) & 3)) * 8;         // swizzled frag col (shorts)

    // prologue: stage 0
    ldsdma16(&Ahs[0][r0][0],      pAh0);
    ldsdma16(&Ahs[0][r0 + 16][0], pAh1);
    ldsdma16(&Als[0][r0][0],      pAl0);
    ldsdma16(&Als[0][r0 + 16][0], pAl1);
    ldsdma16(&Bhs[0][r0][0],      pBh0);
    ldsdma16(&Bhs[0][r0 + 16][0], pBh1);
    ldsdma16(&Bls[0][r0][0],      pBl0);
    ldsdma16(&Bls[0][r0 + 16][0], pBl1);

    f32x4 acc[4][4] = {};
    int NIT = K >> 5;
    for (int it = 0; it < NIT; it++) {
        int cur = it & 1;
        __syncthreads();   // DMA(it) complete; prev compute done
        if (it + 1 < NIT) {
            int k1 = (it + 1) << 5;
            int nxt = cur ^ 1;
            ldsdma16(&Ahs[nxt][r0][0],      pAh0 + k1);
            ldsdma16(&Ahs[nxt][r0 + 16][0], pAh1 + k1);
            ldsdma16(&Als[nxt][r0][0],      pAl0 + k1);
            ldsdma16(&Als[nxt][r0 + 16][0], pAl1 + k1);
            ldsdma16(&Bhs[nxt][r0][0],      pBh0 + k1);
            ldsdma16(&Bhs[nxt][r0 + 16][0], pBh1 + k1);
            ldsdma16(&Bls[nxt][r0][0],      pBl0 + k1);
            ldsdma16(&Bls[nxt][r0 + 16][0], pBl1 + k1);
        }
        bf16x8 ah[4], bh[4], x[4];
        #pragma unroll
        for (int i = 0; i < 4; i++) {
            ah[i] = *(const bf16x8*)&Ahs[cur][wm + i * 16 + fr][ca];
            bh[i] = *(const bf16x8*)&Bhs[cur][wn + i * 16 + fr][ca];
        }
        #pragma unroll
        for (int mi = 0; mi < 4; mi++)
            #pragma unroll
            for (int ni = 0; ni < 4; ni++)
                acc[mi][ni] = __builtin_amdgcn_mfma_f32_16x16x32_bf16(ah[mi], bh[ni], acc[mi][ni], 0, 0, 0);
        #pragma unroll
        for (int i = 0; i < 4; i++) x[i] = *(const bf16x8*)&Bls[cur][wn + i * 16 + fr][ca];
        #pragma unroll
        for (int mi = 0; mi < 4; mi++)
            #pragma unroll
            for (int ni = 0; ni < 4; ni++)
                acc[mi][ni] = __builtin_amdgcn_mfma_f32_16x16x32_bf16(ah[mi], x[ni], acc[mi][ni], 0, 0, 0);
        #pragma unroll
        for (int i = 0; i < 4; i++) x[i] = *(const bf16x8*)&Als[cur][wm + i * 16 + fr][ca];
        #pragma unroll
        for (int mi = 0; mi < 4; mi++)
            #pragma unroll
            for (int ni = 0; ni < 4; ni++)
                acc[mi][ni] = __builtin_amdgcn_mfma_f32_16x16x32_bf16(x[mi], bh[ni], acc[mi][ni], 0, 0, 0);
    }
    int rq = quad * 4;
    #pragma unroll
    for (int mi = 0; mi < 4; mi++) {
        #pragma unroll
        for (int r = 0; r < 4; r++) {
            size_t rowo = (size_t)(bm + wm + mi * 16 + rq + r) * N + bn + wn;
            #pragma unroll
            for (int ni = 0; ni < 4; ni++) {
                float v = acc[mi][ni][r];
                size_t o = rowo + ni * 16 + fr;
                if (resid) v += resid[o];
                C[o] = v;
            }
        }
    }
}

// ---------------------------------------------------------------- RoPE + convert qkv fp32 -> split bf16 q,k,v
__global__ void rope_convert(const float* __restrict__ qkv, const float* __restrict__ fc,
                             __hip_bfloat16* __restrict__ qh, __hip_bfloat16* __restrict__ ql,
                             __hip_bfloat16* __restrict__ kh, __hip_bfloat16* __restrict__ kl,
                             __hip_bfloat16* __restrict__ vh, __hip_bfloat16* __restrict__ vl) {
    int t = blockIdx.x;
    int s = t & (SEQ - 1);
    const float* row = qkv + (size_t)t * QKVW;
    size_t ob = (size_t)t * HS;
    for (int p = threadIdx.x; p < 512; p += 256) {
        int hh = p >> 5, j = p & 31;
        int col = hh * 64 + 2 * j;
        float cr = fc[s * HDIM + 2 * j];
        float ci = fc[s * HDIM + 2 * j + 1];
        float a = row[col], b = row[col + 1];
        float r0 = a * cr - b * ci, r1 = a * ci + b * cr;
        __hip_bfloat16 h0 = __float2bfloat16(r0), h1 = __float2bfloat16(r1);
        qh[ob + col] = h0;     ql[ob + col]     = __float2bfloat16(r0 - __bfloat162float(h0));
        qh[ob + col + 1] = h1; ql[ob + col + 1] = __float2bfloat16(r1 - __bfloat162float(h1));
        a = row[1024 + col]; b = row[1024 + col + 1];
        r0 = a * cr - b * ci; r1 = a * ci + b * cr;
        h0 = __float2bfloat16(r0); h1 = __float2bfloat16(r1);
        kh[ob + col] = h0;     kl[ob + col]     = __float2bfloat16(r0 - __bfloat162float(h0));
        kh[ob + col + 1] = h1; kl[ob + col + 1] = __float2bfloat16(r1 - __bfloat162float(h1));
        r0 = row[2048 + col]; r1 = row[2048 + col + 1];
        h0 = __float2bfloat16(r0); h1 = __float2bfloat16(r1);
        vh[ob + col] = h0;     vl[ob + col]     = __float2bfloat16(r0 - __bfloat162float(h0));
        vh[ob + col + 1] = h1; vl[ob + col + 1] = __float2bfloat16(r1 - __bfloat162float(h1));
    }
}

// ---------------------------------------------------------------- split-K flash attention, MFMA split-bf16
__global__ __launch_bounds__(256) void attn_partial(
        const __hip_bfloat16* __restrict__ qh, const __hip_bfloat16* __restrict__ ql,
        const __hip_bfloat16* __restrict__ kh, const __hip_bfloat16* __restrict__ kl,
        const __hip_bfloat16* __restrict__ vh, const __hip_bfloat16* __restrict__ vl,
        float* __restrict__ po, float* __restrict__ pm_g, float* __restrict__ pl_g) {
    int c = blockIdx.x, qt = blockIdx.y;
    int nc = (qt + 4) >> 2;
    if (c >= nc) return;
    int bh = blockIdx.z;
    int b = bh >> 4, h = bh & 15;
    int t0 = c * 4, t1 = min(t0 + 4, qt + 1);
    int tid = threadIdx.x;
    int wave = tid >> 6, lane = tid & 63;
    int fr = lane & 15, quad = lane >> 4;
    int w16 = wave * 16;
    __shared__ __align__(16) short Qh[64][PAD], Ql[64][PAD];
    __shared__ __align__(16) short KPh[64][PAD], KPl[64][PAD];
    __shared__ __align__(16) short Vhs[64][PAD], Vls[64][PAD];
    size_t hoff = (size_t)h * HDIM;
    int sr = tid >> 2, sg = tid & 3;
    {
        const __hip_bfloat16* qp  = qh + (size_t)(b * SEQ + qt * 64 + sr) * HS + hoff;
        const __hip_bfloat16* qp2 = ql + (size_t)(b * SEQ + qt * 64 + sr) * HS + hoff;
        *(uint4*)&Qh[sr][sg * 8]       = *(const uint4*)(qp + sg * 8);
        *(uint4*)&Qh[sr][(sg + 4) * 8] = *(const uint4*)(qp + (sg + 4) * 8);
        *(uint4*)&Ql[sr][sg * 8]       = *(const uint4*)(qp2 + sg * 8);
        *(uint4*)&Ql[sr][(sg + 4) * 8] = *(const uint4*)(qp2 + (sg + 4) * 8);
    }
    f32x4 o[4] = {};
    float mrow[4], lrow[4];
    #pragma unroll
    for (int i = 0; i < 4; i++) { mrow[i] = -1e30f; lrow[i] = 0.f; }
    int key0 = (tid & 31) * 2, ds = tid >> 5;
    __syncthreads();

    for (int kt = t0; kt < t1; kt++) {
        int kbase = kt * 64;
        {
            const __hip_bfloat16* kp  = kh + (size_t)(b * SEQ + kbase + sr) * HS + hoff;
            const __hip_bfloat16* kp2 = kl + (size_t)(b * SEQ + kbase + sr) * HS + hoff;
            *(uint4*)&KPh[sr][sg * 8]       = *(const uint4*)(kp + sg * 8);
            *(uint4*)&KPh[sr][(sg + 4) * 8] = *(const uint4*)(kp + (sg + 4) * 8);
            *(uint4*)&KPl[sr][sg * 8]       = *(const uint4*)(kp2 + sg * 8);
            *(uint4*)&KPl[sr][(sg + 4) * 8] = *(const uint4*)(kp2 + (sg + 4) * 8);
        }
        {
            const __hip_bfloat16* v0 = vh + (size_t)(b * SEQ + kbase + key0) * HS + hoff + ds * 8;
            uint4 A = *(const uint4*)v0;
            uint4 Bv = *(const uint4*)(v0 + HS);
            const unsigned short* ap = (const unsigned short*)&A;
            const unsigned short* bp = (const unsigned short*)&Bv;
            #pragma unroll
            for (int j = 0; j < 8; j++)
                *(unsigned*)&Vhs[ds * 8 + j][key0] = (unsigned)ap[j] | ((unsigned)bp[j] << 16);
            const __hip_bfloat16* v2 = vl + (size_t)(b * SEQ + kbase + key0) * HS + hoff + ds * 8;
            uint4 A2 = *(const uint4*)v2;
            uint4 B2 = *(const uint4*)(v2 + HS);
            const unsigned short* ap2 = (const unsigned short*)&A2;
            const unsigned short* bp2 = (const unsigned short*)&B2;
            #pragma unroll
            for (int j = 0; j < 8; j++)
                *(unsigned*)&Vls[ds * 8 + j][key0] = (unsigned)ap2[j] | ((unsigned)bp2[j] << 16);
        }
        __syncthreads();

        f32x4 s[4] = {};
        #pragma unroll
        for (int ks = 0; ks < 2; ks++) {
            bf16x8 a_h = *(const bf16x8*)&Qh[w16 + fr][quad * 8 + ks * 32];
            bf16x8 a_l = *(const bf16x8*)&Ql[w16 + fr][quad * 8 + ks * 32];
            #pragma unroll
            for (int ni = 0; ni < 4; ni++) {
                bf16x8 b_h = *(const bf16x8*)&KPh[ni * 16 + fr][quad * 8 + ks * 32];
                bf16x8 b_l = *(const bf16x8*)&KPl[ni * 16 + fr][quad * 8 + ks * 32];
                s[ni] = __builtin_amdgcn_mfma_f32_16x16x32_bf16(a_h, b_h, s[ni], 0, 0, 0);
                s[ni] = __builtin_amdgcn_mfma_f32_16x16x32_bf16(a_h, b_l, s[ni], 0, 0, 0);
                s[ni] = __builtin_amdgcn_mfma_f32_16x16x32_bf16(a_l, b_h, s[ni], 0, 0, 0);
            }
        }
        int qg = qt * 64 + w16 + quad * 4;
        #pragma unroll
        for (int ni = 0; ni < 4; ni++) {
            int kg = kbase + ni * 16 + fr;
            #pragma unroll
            for (int r = 0; r < 4; r++)
                s[ni][r] = (kg > qg + r) ? -1e9f : s[ni][r] * 0.125f;
        }
        #pragma unroll
        for (int r = 0; r < 4; r++) {
            float mx = fmaxf(fmaxf(s[0][r], s[1][r]), fmaxf(s[2][r], s[3][r]));
            #pragma unroll
            for (int wd = 1; wd < 16; wd <<= 1) mx = fmaxf(mx, __shfl_xor(mx, wd));
            float nm = fmaxf(mrow[r], mx);
            float alpha = __expf(mrow[r] - nm);
            float rs = 0.f;
            #pragma unroll
            for (int ni = 0; ni < 4; ni++) { float e = __expf(s[ni][r] - nm); s[ni][r] = e; rs += e; }
            #pragma unroll
            for (int wd = 1; wd < 16; wd <<= 1) rs += __shfl_xor(rs, wd);
            lrow[r] = lrow[r] * alpha + rs;
            mrow[r] = nm;
            o[0][r] *= alpha; o[1][r] *= alpha; o[2][r] *= alpha; o[3][r] *= alpha;
        }
        __syncthreads();
        #pragma unroll
        for (int ni = 0; ni < 4; ni++)
            #pragma unroll
            for (int r = 0; r < 4; r++) {
                float pv = s[ni][r];
                __hip_bfloat16 hi = __float2bfloat16(pv);
                __hip_bfloat16 lo = __float2bfloat16(pv - __bfloat162float(hi));
                KPh[w16 + quad * 4 + r][ni * 16 + fr] = *(short*)&hi;
                KPl[w16 + quad * 4 + r][ni * 16 + fr] = *(short*)&lo;
            }
        #pragma unroll
        for (int ks = 0; ks < 2; ks++) {
            bf16x8 p_h = *(const bf16x8*)&KPh[w16 + fr][quad * 8 + ks * 32];
            bf16x8 p_l = *(const bf16x8*)&KPl[w16 + fr][quad * 8 + ks * 32];
            #pragma unroll
            for (int ni = 0; ni < 4; ni++) {
                bf16x8 v_h = *(const bf16x8*)&Vhs[ni * 16 + fr][quad * 8 + ks * 32];
                bf16x8 v_l = *(const bf16x8*)&Vls[ni * 16 + fr][quad * 8 + ks * 32];
                o[ni] = __builtin_amdgcn_mfma_f32_16x16x32_bf16(p_h, v_h, o[ni], 0, 0, 0);
                o[ni] = __builtin_amdgcn_mfma_f32_16x16x32_bf16(p_h, v_l, o[ni], 0, 0, 0);
                o[ni] = __builtin_amdgcn_mfma_f32_16x16x32_bf16(p_l, v_h, o[ni], 0, 0, 0);
            }
        }
        __syncthreads();
    }
    int pidx = (bh * 16 + qt) * 4 + c;
    float* pob = po + (size_t)pidx * 4096;
    #pragma unroll
    for (int ni = 0; ni < 4; ni++)
        #pragma unroll
        for (int r = 0; r < 4; r++)
            pob[(w16 + quad * 4 + r) * 64 + ni * 16 + fr] = o[ni][r];
    if (fr == 0) {
        #pragma unroll
        for (int r = 0; r < 4; r++) {
            pm_g[pidx * 64 + w16 + quad * 4 + r] = mrow[r];
            pl_g[pidx * 64 + w16 + quad * 4 + r] = lrow[r];
        }
    }
}

// ---------------------------------------------------------------- merge partials -> ctx as split bf16
__global__ void attn_merge(const float* __restrict__ po, const float* __restrict__ pm,
                           const float* __restrict__ pl,
                           __hip_bfloat16* __restrict__ ch, __hip_bfloat16* __restrict__ cl) {
    int qt = blockIdx.x, h = blockIdx.y, b = blockIdx.z;
    int bh = b * 16 + h;
    int nc = (qt + 4) >> 2;
    int base = (bh * 16 + qt) * 4;
    int tid = threadIdx.x;
    int r  = tid >> 2;
    int d0 = (tid & 3) * 16;
    float mstar = -1e30f;
    for (int c = 0; c < nc; c++) mstar = fmaxf(mstar, pm[(base + c) * 64 + r]);
    float a[4];
    float lsum = 0.f;
    for (int c = 0; c < nc; c++) {
        a[c] = __expf(pm[(base + c) * 64 + r] - mstar);
        lsum += a[c] * pl[(base + c) * 64 + r];
    }
    float inv = 1.f / lsum;
    size_t crow = (size_t)(b * SEQ + qt * 64 + r) * HS + h * HDIM;
    for (int dd = 0; dd < 16; dd += 4) {
        float4 acc = make_float4(0.f, 0.f, 0.f, 0.f);
        for (int c = 0; c < nc; c++) {
            float4 v = *(const float4*)(po + (size_t)(base + c) * 4096 + r * 64 + d0 + dd);
            acc.x += a[c] * v.x; acc.y += a[c] * v.y;
            acc.z += a[c] * v.z; acc.w += a[c] * v.w;
        }
        float vs[4] = {acc.x * inv, acc.y * inv, acc.z * inv, acc.w * inv};
        #pragma unroll
        for (int j = 0; j < 4; j++) {
            __hip_bfloat16 hi = __float2bfloat16(vs[j]);
            ch[crow + d0 + dd + j] = hi;
            cl[crow + d0 + dd + j] = __float2bfloat16(vs[j] - __bfloat162float(hi));
        }
    }
}

// ---------------------------------------------------------------- router (per-token top2)
__global__ void router_kernel(const float* __restrict__ hn, const float* __restrict__ rw,
                              int* __restrict__ cnt, int* __restrict__ topEk,
                              float* __restrict__ topW) {
    int t = blockIdx.x;
    int lane = threadIdx.x;
    float acc[NEXP];
    #pragma unroll
    for (int e = 0; e < NEXP; e++) acc[e] = 0.f;
    const float* row = hn + (size_t)t * HS;
    for (int kk = lane; kk < HS; kk += 64) {
        float xv = row[kk];
        const float* r = rw + (size_t)kk * NEXP;
        #pragma unroll
        for (int e = 0; e < NEXP; e++) acc[e] += xv * r[e];
    }
    #pragma unroll
    for (int e = 0; e < NEXP; e++)
        for (int off = 32; off > 0; off >>= 1) acc[e] += __shfl_down(acc[e], off);
    if (lane == 0) {
        float mx = acc[0];
        #pragma unroll
        for (int e = 1; e < NEXP; e++) mx = fmaxf(mx, acc[e]);
        float p[NEXP]; float s = 0.f;
        #pragma unroll
        for (int e = 0; e < NEXP; e++) { p[e] = __expf(acc[e] - mx); s += p[e]; }
        int i0 = 0;
        #pragma unroll
        for (int e = 1; e < NEXP; e++) if (p[e] > p[i0]) i0 = e;
        int i1 = (i0 == 0) ? 1 : 0;
        #pragma unroll
        for (int e = 0; e < NEXP; e++) if (e != i0 && p[e] > p[i1]) i1 = e;
        float v0 = p[i0], v1 = p[i1], sn = v0 + v1;
        topEk[2 * t]     = i0; topW[2 * t]     = v0 / sn;
        topEk[2 * t + 1] = i1; topW[2 * t + 1] = v1 / sn;
        atomicAdd(&cnt[i0], 1);
        atomicAdd(&cnt[i1], 1);
    }
}

// ---------------------------------------------------------------- offsets + block table
__global__ void offsets_kernel(const int* __restrict__ cnt, int* __restrict__ off,
                               int* __restrict__ blk_e, int* __restrict__ blk_r) {
    if (threadIdx.x == 0) {
        int o = 0, n = 0;
        for (int e = 0; e < NEXP; e++) {
            off[e] = o;
            for (int bm = 0; bm < cnt[e]; bm += 128) { blk_e[n] = e; blk_r[n] = bm; n++; }
            o += cnt[e];
        }
        for (; n < MAXBLK; n++) { blk_e[n] = -1; blk_r[n] = 0; }
    }
}

__global__ void scatter_kernel(const int* __restrict__ topEk, int* __restrict__ fill,
                               const int* __restrict__ off, const float* __restrict__ topW,
                               int* __restrict__ tok_list, float* __restrict__ wA) {
    int idx = blockIdx.x * 256 + threadIdx.x;
    int e = topEk[idx];
    int slot = atomicAdd(&fill[e], 1);
    int gidx = off[e] + slot;
    tok_list[gidx] = idx >> 1;
    wA[gidx] = topW[idx];
}

// ---------------------------------------------------------------- MoE up-proj, dbuf DMA pipeline
__global__ __launch_bounds__(256) void moe_up_mfma(const __hip_bfloat16* __restrict__ Abf,
                                                   const __hip_bfloat16* __restrict__ B1T,
                                                   const __hip_bfloat16* __restrict__ B3T,
                                                   __hip_bfloat16* __restrict__ g,
                                                   const int* __restrict__ cnt,
                                                   const int* __restrict__ off,
                                                   const int* __restrict__ tok_list,
                                                   const int* __restrict__ blk_e,
                                                   const int* __restrict__ blk_r) {
    int e = blk_e[blockIdx.y];
    if (e < 0) return;
    int bm = blk_r[blockIdx.y];
    int ce = cnt[e], oe = off[e];
    int bn = blockIdx.x * 128;
    const __hip_bfloat16* b1 = B1T + (size_t)e * IS * HS;   // [IS][HS]
    const __hip_bfloat16* b3 = B3T + (size_t)e * IS * HS;

    __shared__ __align__(16) short As[2][128][32];
    __shared__ __align__(16) short B1s[2][128][32];
    __shared__ __align__(16) short B3s[2][128][32];   // 48 KB

    int t = threadIdx.x;
    int wave = t >> 6, lane = t & 63;
    int wm = (wave & 1) * 64, wn = (wave >> 1) * 64;
    int fr = lane & 15, quad = lane >> 4;
    int r0 = wave * 32;
    int srow = lane >> 2;
    int schunk = (lane & 3) ^ ((lane >> 3) & 3);
    int tokA0 = tok_list[oe + min(bm + r0 + srow, ce - 1)];
    int tokA1 = tok_list[oe + min(bm + r0 + 16 + srow, ce - 1)];
    const __hip_bfloat16* pA0 = Abf + (size_t)tokA0 * HS + schunk * 8;
    const __hip_bfloat16* pA1 = Abf + (size_t)tokA1 * HS + schunk * 8;
    const __hip_bfloat16* pB1a = b1 + (size_t)(bn + r0 + srow) * HS + schunk * 8;
    const __hip_bfloat16* pB1b = pB1a + (size_t)16 * HS;
    const __hip_bfloat16* pB3a = b3 + (size_t)(bn + r0 + srow) * HS + schunk * 8;
    const __hip_bfloat16* pB3b = pB3a + (size_t)16 * HS;
    int ca = (quad ^ ((fr >> 1) & 3)) * 8;

    ldsdma16(&As[0][r0][0],       pA0);
    ldsdma16(&As[0][r0 + 16][0],  pA1);
    ldsdma16(&B1s[0][r0][0],      pB1a);
    ldsdma16(&B1s[0][r0 + 16][0], pB1b);
    ldsdma16(&B3s[0][r0][0],      pB3a);
    ldsdma16(&B3s[0][r0 + 16][0], pB3b);

    f32x4 acc1[4][4] = {};
    f32x4 acc3[4][4] = {};
    const int NIT = HS >> 5;
    for (int it = 0; it < NIT; it++) {
        int cur = it & 1;
        __syncthreads();
        if (it + 1 < NIT) {
            int k1 = (it + 1) << 5;
            int nxt = cur ^ 1;
            ldsdma16(&As[nxt][r0][0],       pA0 + k1);
            ldsdma16(&As[nxt][r0 + 16][0],  pA1 + k1);
            ldsdma16(&B1s[nxt][r0][0],      pB1a + k1);
            ldsdma16(&B1s[nxt][r0 + 16][0], pB1b + k1);
            ldsdma16(&B3s[nxt][r0][0],      pB3a + k1);
            ldsdma16(&B3s[nxt][r0 + 16][0], pB3b + k1);
        }
        bf16x8 a[4], f1[4], f3[4];
        #pragma unroll
        for (int i = 0; i < 4; i++) {
            a[i]  = *(const bf16x8*)&As[cur][wm + i * 16 + fr][ca];
            f1[i] = *(const bf16x8*)&B1s[cur][wn + i * 16 + fr][ca];
            f3[i] = *(const bf16x8*)&B3s[cur][wn + i * 16 + fr][ca];
        }
        #pragma unroll
        for (int mi = 0; mi < 4; mi++)
            #pragma unroll
            for (int ni = 0; ni < 4; ni++) {
                acc1[mi][ni] = __builtin_amdgcn_mfma_f32_16x16x32_bf16(a[mi], f1[ni], acc1[mi][ni], 0, 0, 0);
                acc3[mi][ni] = __builtin_amdgcn_mfma_f32_16x16x32_bf16(a[mi], f3[ni], acc3[mi][ni], 0, 0, 0);
            }
    }
    int rq = quad * 4;
    #pragma unroll
    for (int mi = 0; mi < 4; mi++) {
        #pragma unroll
        for (int r = 0; r < 4; r++) {
            int slot = bm + wm + mi * 16 + rq + r;
            if (slot < ce) {
                size_t rowo = (size_t)(oe + slot) * IS + bn + wn;
                #pragma unroll
                for (int ni = 0; ni < 4; ni++) {
                    float x1 = acc1[mi][ni][r];
                    float x3 = acc3[mi][ni][r];
                    float sv = (x1 / (1.f + __expf(-x1))) * x3;
                    g[rowo + ni * 16 + fr] = __float2bfloat16(sv);
                }
            }
        }
    }
}

// ---------------------------------------------------------------- MoE down-proj, dbuf DMA pipeline
__global__ __launch_bounds__(256) void moe_down_mfma(const __hip_bfloat16* __restrict__ g,
                                                     const __hip_bfloat16* __restrict__ B2T,
                                                     float* __restrict__ out,
                                                     const int* __restrict__ cnt,
                                                     const int* __restrict__ off,
                                                     const int* __restrict__ tok_list,
                                                     const float* __restrict__ wA,
                                                     const int* __restrict__ blk_e,
                                                     const int* __restrict__ blk_r) {
    int e = blk_e[blockIdx.y];
    if (e < 0) return;
    int bm = blk_r[blockIdx.y];
    int ce = cnt[e], oe = off[e];
    int bn = blockIdx.x * 128;
    const __hip_bfloat16* b2 = B2T + (size_t)e * HS * IS;   // [HS][IS]

    __shared__ __align__(16) short As[2][128][32];
    __shared__ __align__(16) short Bs[2][128][32];   // 32 KB

    int t = threadIdx.x;
    int wave = t >> 6, lane = t & 63;
    int wm = (wave & 1) * 64, wn = (wave >> 1) * 64;
    int fr = lane & 15, quad = lane >> 4;
    int r0 = wave * 32;
    int srow = lane >> 2;
    int schunk = (lane & 3) ^ ((lane >> 3) & 3);
    int ga0 = oe + min(bm + r0 + srow, ce - 1);
    int ga1 = oe + min(bm + r0 + 16 + srow, ce - 1);
    const __hip_bfloat16* pA0 = g + (size_t)ga0 * IS + schunk * 8;
    const __hip_bfloat16* pA1 = g + (size_t)ga1 * IS + schunk * 8;
    const __hip_bfloat16* pBa = b2 + (size_t)(bn + r0 + srow) * IS + schunk * 8;
    const __hip_bfloat16* pBb = pBa + (size_t)16 * IS;
    int ca = (quad ^ ((fr >> 1) & 3)) * 8;

    ldsdma16(&As[0][r0][0],      pA0);
    ldsdma16(&As[0][r0 + 16][0], pA1);
    ldsdma16(&Bs[0][r0][0],      pBa);
    ldsdma16(&Bs[0][r0 + 16][0], pBb);

    f32x4 acc[4][4] = {};
    const int NIT = IS >> 5;
    for (int it = 0; it < NIT; it++) {
        int cur = it & 1;
        __syncthreads();
        if (it + 1 < NIT) {
            int k1 = (it + 1) << 5;
            int nxt = cur ^ 1;
            ldsdma16(&As[nxt][r0][0],      pA0 + k1);
            ldsdma16(&As[nxt][r0 + 16][0], pA1 + k1);
            ldsdma16(&Bs[nxt][r0][0],      pBa + k1);
            ldsdma16(&Bs[nxt][r0 + 16][0], pBb + k1);
        }
        bf16x8 a[4], f[4];
        #pragma unroll
        for (int i = 0; i < 4; i++) {
            a[i] = *(const bf16x8*)&As[cur][wm + i * 16 + fr][ca];
            f[i] = *(const bf16x8*)&Bs[cur][wn + i * 16 + fr][ca];
        }
        #pragma unroll
        for (int mi = 0; mi < 4; mi++)
            #pragma unroll
            for (int ni = 0; ni < 4; ni++)
                acc[mi][ni] = __builtin_amdgcn_mfma_f32_16x16x32_bf16(a[mi], f[ni], acc[mi][ni], 0, 0, 0);
    }
    int rq = quad * 4;
    #pragma unroll
    for (int mi = 0; mi < 4; mi++) {
        #pragma unroll
        for (int r = 0; r < 4; r++) {
            int slot = bm + wm + mi * 16 + rq + r;
            if (slot < ce) {
                int gidx = oe + slot;
                int tok = tok_list[gidx];
                float wgt = wA[gidx];
                size_t rowo = (size_t)tok * HS + bn + wn;
                #pragma unroll
                for (int ni = 0; ni < 4; ni++)
                    atomicAdd(out + rowo + ni * 16 + fr, wgt * acc[mi][ni][r]);
            }
        }
    }
}

// ---------------------------------------------------------------- launch
extern "C" void kernel_launch(void* const* d_in, const int* in_sizes, int n_in,
                              void* d_out, int out_size, void* d_ws, size_t ws_size,
                              hipStream_t stream) {
    const float* x   = (const float*)d_in[0];
    const float* anw = (const float*)d_in[1];
    const float* fnw = (const float*)d_in[2];
    const float* wq  = (const float*)d_in[3];
    const float* wk  = (const float*)d_in[4];
    const float* wv  = (const float*)d_in[5];
    const float* wo  = (const float*)d_in[6];
    const float* rw  = (const float*)d_in[7];
    const float* w1  = (const float*)d_in[8];
    const float* w3  = (const float*)d_in[9];
    const float* w2  = (const float*)d_in[10];
    const float* fc  = (const float*)d_in[11];
    float* out = (float*)d_out;

    char* ws = (char*)d_ws;
    const size_t MB = 1024 * 1024;
    __hip_bfloat16* xn_h  = (__hip_bfloat16*)(ws + 0 * MB);
    __hip_bfloat16* xn_l  = (__hip_bfloat16*)(ws + 4 * MB);
    float*          qkv   = (float*)(ws + 8 * MB);
    __hip_bfloat16* WqT_h = (__hip_bfloat16*)(ws + 32 * MB);
    __hip_bfloat16* WqT_l = (__hip_bfloat16*)(ws + 38 * MB);
    __hip_bfloat16* woT_h = (__hip_bfloat16*)(ws + 44 * MB);
    __hip_bfloat16* woT_l = (__hip_bfloat16*)(ws + 46 * MB);
    float*          po    = (float*)(ws + 48 * MB);
    float*          pm    = (float*)(ws + 82 * MB);
    float*          plb   = (float*)(ws + 83 * MB);
    __hip_bfloat16* ctx_h = (__hip_bfloat16*)(ws + 84 * MB);
    __hip_bfloat16* ctx_l = (__hip_bfloat16*)(ws + 88 * MB);
    __hip_bfloat16* qhb   = (__hip_bfloat16*)(ws + 92 * MB);
    __hip_bfloat16* qlb   = (__hip_bfloat16*)(ws + 96 * MB);
    __hip_bfloat16* khb   = (__hip_bfloat16*)(ws + 100 * MB);
    __hip_bfloat16* klb   = (__hip_bfloat16*)(ws + 104 * MB);
    __hip_bfloat16* vhb   = (__hip_bfloat16*)(ws + 108 * MB);
    __hip_bfloat16* vlb   = (__hip_bfloat16*)(ws + 112 * MB);
    float*          hn    = (float*)(ws + 0 * MB);
    __hip_bfloat16* hn_bf = (__hip_bfloat16*)(ws + 8 * MB);
    __hip_bfloat16* w1T   = (__hip_bfloat16*)(ws + 12 * MB);
    __hip_bfloat16* w3T   = (__hip_bfloat16*)(ws + 44 * MB);
    __hip_bfloat16* w2T   = (__hip_bfloat16*)(ws + 76 * MB);
    __hip_bfloat16* gact  = (__hip_bfloat16*)(ws + 108 * MB);
    int* ibase    = (int*)(ws + 124 * MB);
    int* cnt      = ibase;                 // 8
    int* fill     = ibase + 8;             // 8
    int* off      = ibase + 16;            // 8
    int* blk_e    = ibase + 24;            // 40
    int* blk_r    = ibase + 64;            // 40
    int* topEk    = ibase + 128;           // 4096
    int* tok_list = ibase + 128 + NASSIGN; // 4096
    float* topW   = (float*)(ibase + 128 + 2 * NASSIGN);
    float* wA     = (float*)(ibase + 128 + 3 * NASSIGN);

    // ---- attention half ----
    dim3 tg(HS / 32, HS / 32);
    transpose_split<<<tg, 256, 0, stream>>>(wq, WqT_h, WqT_l, HS, HS, 0);
    transpose_split<<<tg, 256, 0, stream>>>(wk, WqT_h, WqT_l, HS, HS, 1024);
    transpose_split<<<tg, 256, 0, stream>>>(wv, WqT_h, WqT_l, HS, HS, 2048);
    transpose_split<<<tg, 256, 0, stream>>>(wo, woT_h, woT_l, HS, HS, 0);
    rmsnorm_split<<<NTOK, 256, 0, stream>>>(x, anw, xn_h, xn_l);

    gemm_bf16x3<<<dim3(QKVW / 128, NTOK / 128), 256, 0, stream>>>(
        xn_h, xn_l, WqT_h, WqT_l, nullptr, qkv, NTOK, QKVW, HS);
    rope_convert<<<NTOK, 256, 0, stream>>>(qkv, fc, qhb, qlb, khb, klb, vhb, vlb);

    attn_partial<<<dim3(4, 16, 32), 256, 0, stream>>>(qhb, qlb, khb, klb, vhb, vlb, po, pm, plb);
    attn_merge<<<dim3(16, 16, 2), 256, 0, stream>>>(po, pm, plb, ctx_h, ctx_l);

    gemm_bf16x3<<<dim3(HS / 128, NTOK / 128), 256, 0, stream>>>(
        ctx_h, ctx_l, woT_h, woT_l, x, out, NTOK, HS, HS);   // out = h = x + ctx@wo

    // ---- MoE half (routed top-2, bf16 MFMA experts) ----
    rmsnorm_dual<<<NTOK, 256, 0, stream>>>(out, fnw, hn, hn_bf);
    transpose_bf16<<<dim3(IS / 32, HS / 32, NEXP), 256, 0, stream>>>(w1, w1T, HS, IS);
    transpose_bf16<<<dim3(IS / 32, HS / 32, NEXP), 256, 0, stream>>>(w3, w3T, HS, IS);
    transpose_bf16<<<dim3(HS / 32, IS / 32, NEXP), 256, 0, stream>>>(w2, w2T, IS, HS);

    hipMemsetAsync(cnt, 0, 16 * sizeof(int), stream);   // cnt + fill
    router_kernel<<<NTOK, 64, 0, stream>>>(hn, rw, cnt, topEk, topW);
    offsets_kernel<<<1, 64, 0, stream>>>(cnt, off, blk_e, blk_r);
    scatter_kernel<<<NASSIGN / 256, 256, 0, stream>>>(topEk, fill, off, topW, tok_list, wA);

    moe_up_mfma<<<dim3(IS / 128, MAXBLK), 256, 0, stream>>>(
        hn_bf, w1T, w3T, gact, cnt, off, tok_list, blk_e, blk_r);
    moe_down_mfma<<<dim3(HS / 128, MAXBLK), 256, 0, stream>>>(
        gact, w2T, out, cnt, off, tok_list, wA, blk_e, blk_r);
}

// Round 8
// 630.624 us; speedup vs baseline: 7.2976x; 1.0647x over previous
//
#include <hip/hip_runtime.h>
#include <hip/hip_bf16.h>
#include <math.h>

#define HS 1024      // hidden size
#define IS 2048      // intermediate size
#define NHEAD 16
#define HDIM 64
#define NEXP 8
#define BATCH 2
#define SEQ 1024
#define NTOK (BATCH*SEQ)     // 2048 tokens
#define NASSIGN (NTOK*2)     // 4096 (token, expert) assignments
#define QKVW 3072            // fused qkv row width
#define PAD 72               // LDS row stride for attn (bf16 elems)
#define MAXBLK 40            // max 128-row blocks over all experts

typedef short bf16x8 __attribute__((ext_vector_type(8)));
typedef float f32x4  __attribute__((ext_vector_type(4)));

// async global->LDS, 16B per lane; lds dest = base + lane*16 (wave-uniform base)
__device__ __forceinline__ void ldsdma16(void* lds, const void* gp) {
    __builtin_amdgcn_global_load_lds(
        (const __attribute__((address_space(1))) void*)gp,
        (__attribute__((address_space(3))) void*)lds, 16, 0, 0);
}

// ---------------------------------------------------------------- rmsnorm -> split bf16 (hi+lo)
__global__ void rmsnorm_split(const float* __restrict__ x, const float* __restrict__ w,
                              __hip_bfloat16* __restrict__ oh, __hip_bfloat16* __restrict__ ol) {
    int t = blockIdx.x;
    int tid = threadIdx.x;
    const float* row = x + (size_t)t * HS;
    float ss = 0.f;
    for (int i = tid; i < HS; i += 256) { float v = row[i]; ss += v * v; }
    for (int off = 32; off > 0; off >>= 1) ss += __shfl_down(ss, off);
    __shared__ float red[4];
    if ((tid & 63) == 0) red[tid >> 6] = ss;
    __syncthreads();
    float tot = red[0] + red[1] + red[2] + red[3];
    float rr = rsqrtf(tot / (float)HS + 1e-6f);
    for (int i = tid; i < HS; i += 256) {
        float v = w[i] * row[i] * rr;
        __hip_bfloat16 hi = __float2bfloat16(v);
        oh[(size_t)t * HS + i] = hi;
        ol[(size_t)t * HS + i] = __float2bfloat16(v - __bfloat162float(hi));
    }
}

// ---------------------------------------------------------------- rmsnorm dual (fp32 + bf16)
__global__ void rmsnorm_dual(const float* __restrict__ x, const float* __restrict__ w,
                             float* __restrict__ outf, __hip_bfloat16* __restrict__ outb) {
    int t = blockIdx.x;
    int tid = threadIdx.x;
    const float* row = x + (size_t)t * HS;
    float ss = 0.f;
    for (int i = tid; i < HS; i += 256) { float v = row[i]; ss += v * v; }
    for (int off = 32; off > 0; off >>= 1) ss += __shfl_down(ss, off);
    __shared__ float red[4];
    if ((tid & 63) == 0) red[tid >> 6] = ss;
    __syncthreads();
    float tot = red[0] + red[1] + red[2] + red[3];
    float rr = rsqrtf(tot / (float)HS + 1e-6f);
    for (int i = tid; i < HS; i += 256) {
        float v = w[i] * row[i] * rr;
        outf[(size_t)t * HS + i] = v;
        outb[(size_t)t * HS + i] = __float2bfloat16(v);
    }
}

// ---------------------------------------------------------------- transpose fp32 [R][C] -> split bf16 [C][R]
__global__ void transpose_split(const float* __restrict__ src,
                                __hip_bfloat16* __restrict__ dh, __hip_bfloat16* __restrict__ dl,
                                int R, int C, int rowOff) {
    __shared__ float tile[32][33];
    int c0 = blockIdx.x * 32, r0 = blockIdx.y * 32;
    int tx = threadIdx.x & 31, ty = threadIdx.x >> 5;  // 0..7
    #pragma unroll
    for (int i = 0; i < 4; i++) {
        int r = ty + i * 8;
        tile[r][tx] = src[(size_t)(r0 + r) * C + c0 + tx];
    }
    __syncthreads();
    #pragma unroll
    for (int i = 0; i < 4; i++) {
        int c = ty + i * 8;
        float v = tile[tx][c];
        __hip_bfloat16 hi = __float2bfloat16(v);
        size_t o = (size_t)(rowOff + c0 + c) * R + r0 + tx;
        dh[o] = hi;
        dl[o] = __float2bfloat16(v - __bfloat162float(hi));
    }
}

// ---------------------------------------------------------------- transpose fp32 [R][C] -> bf16 [C][R], per expert z
__global__ void transpose_bf16(const float* __restrict__ in, __hip_bfloat16* __restrict__ outp,
                               int R, int C) {
    __shared__ float tile[32][33];
    int e = blockIdx.z;
    const float* src = in + (size_t)e * R * C;
    __hip_bfloat16* dst = outp + (size_t)e * R * C;
    int c0 = blockIdx.x * 32, r0 = blockIdx.y * 32;
    int tx = threadIdx.x & 31, ty = threadIdx.x >> 5;
    #pragma unroll
    for (int i = 0; i < 4; i++) {
        int r = ty + i * 8;
        tile[r][tx] = src[(size_t)(r0 + r) * C + c0 + tx];
    }
    __syncthreads();
    #pragma unroll
    for (int i = 0; i < 4; i++) {
        int c = ty + i * 8;
        dst[(size_t)(c0 + c) * R + r0 + tx] = __float2bfloat16(tile[tx][c]);
    }
}

// ---------------------------------------------------------------- split-bf16 GEMM, 128x64 tile, dbuf DMA
// C[M][N] = (Ah+Al)[M][K] @ (Bh+Bl)[N][K]^T (+resid), via Ah@Bh + Ah@Bl + Al@Bh
__global__ __launch_bounds__(256) void gemm_bf16x3(const __hip_bfloat16* __restrict__ Ah,
                                                   const __hip_bfloat16* __restrict__ Al,
                                                   const __hip_bfloat16* __restrict__ Bh,
                                                   const __hip_bfloat16* __restrict__ Bl,
                                                   const float* __restrict__ resid,
                                                   float* __restrict__ C,
                                                   int M, int N, int K) {
    __shared__ __align__(16) short Ahs[2][128][32];   // 16 KB
    __shared__ __align__(16) short Als[2][128][32];   // 16 KB
    __shared__ __align__(16) short Bhs[2][64][32];    // 8 KB
    __shared__ __align__(16) short Bls[2][64][32];    // 8 KB -> 48 KB total
    int bm = blockIdx.y * 128, bn = blockIdx.x * 64;
    int t = threadIdx.x;
    int wave = t >> 6, lane = t & 63;
    int wm = (wave & 1) * 64, wn = (wave >> 1) * 32;
    int fr = lane & 15, quad = lane >> 4;
    int rA = wave * 32;            // A rows staged by this wave
    int rB = wave * 16;            // B rows staged by this wave
    int srow = lane >> 2;
    int schunk = (lane & 3) ^ ((lane >> 3) & 3);   // xor-swizzled 16B chunk
    const __hip_bfloat16* pAh0 = Ah + (size_t)(bm + rA + srow) * K + schunk * 8;
    const __hip_bfloat16* pAh1 = pAh0 + (size_t)16 * K;
    const __hip_bfloat16* pAl0 = Al + (size_t)(bm + rA + srow) * K + schunk * 8;
    const __hip_bfloat16* pAl1 = pAl0 + (size_t)16 * K;
    const __hip_bfloat16* pBh  = Bh + (size_t)(bn + rB + srow) * K + schunk * 8;
    const __hip_bfloat16* pBl  = Bl + (size_t)(bn + rB + srow) * K + schunk * 8;
    int ca = (quad ^ ((fr >> 1) & 3)) * 8;         // swizzled frag col (shorts)

    ldsdma16(&Ahs[0][rA][0],      pAh0);
    ldsdma16(&Ahs[0][rA + 16][0], pAh1);
    ldsdma16(&Als[0][rA][0],      pAl0);
    ldsdma16(&Als[0][rA + 16][0], pAl1);
    ldsdma16(&Bhs[0][rB][0],      pBh);
    ldsdma16(&Bls[0][rB][0],      pBl);

    f32x4 acc[4][2] = {};
    int NIT = K >> 5;
    for (int it = 0; it < NIT; it++) {
        int cur = it & 1;
        __syncthreads();
        if (it + 1 < NIT) {
            int k1 = (it + 1) << 5;
            int nxt = cur ^ 1;
            ldsdma16(&Ahs[nxt][rA][0],      pAh0 + k1);
            ldsdma16(&Ahs[nxt][rA + 16][0], pAh1 + k1);
            ldsdma16(&Als[nxt][rA][0],      pAl0 + k1);
            ldsdma16(&Als[nxt][rA + 16][0], pAl1 + k1);
            ldsdma16(&Bhs[nxt][rB][0],      pBh + k1);
            ldsdma16(&Bls[nxt][rB][0],      pBl + k1);
        }
        bf16x8 ah[4], bh[2], x[4];
        #pragma unroll
        for (int i = 0; i < 4; i++) ah[i] = *(const bf16x8*)&Ahs[cur][wm + i * 16 + fr][ca];
        #pragma unroll
        for (int i = 0; i < 2; i++) bh[i] = *(const bf16x8*)&Bhs[cur][wn + i * 16 + fr][ca];
        #pragma unroll
        for (int mi = 0; mi < 4; mi++)
            #pragma unroll
            for (int ni = 0; ni < 2; ni++)
                acc[mi][ni] = __builtin_amdgcn_mfma_f32_16x16x32_bf16(ah[mi], bh[ni], acc[mi][ni], 0, 0, 0);
        #pragma unroll
        for (int i = 0; i < 2; i++) x[i] = *(const bf16x8*)&Bls[cur][wn + i * 16 + fr][ca];
        #pragma unroll
        for (int mi = 0; mi < 4; mi++)
            #pragma unroll
            for (int ni = 0; ni < 2; ni++)
                acc[mi][ni] = __builtin_amdgcn_mfma_f32_16x16x32_bf16(ah[mi], x[ni], acc[mi][ni], 0, 0, 0);
        #pragma unroll
        for (int i = 0; i < 4; i++) x[i] = *(const bf16x8*)&Als[cur][wm + i * 16 + fr][ca];
        #pragma unroll
        for (int mi = 0; mi < 4; mi++)
            #pragma unroll
            for (int ni = 0; ni < 2; ni++)
                acc[mi][ni] = __builtin_amdgcn_mfma_f32_16x16x32_bf16(x[mi], bh[ni], acc[mi][ni], 0, 0, 0);
    }
    int rq = quad * 4;
    #pragma unroll
    for (int mi = 0; mi < 4; mi++) {
        #pragma unroll
        for (int r = 0; r < 4; r++) {
            size_t rowo = (size_t)(bm + wm + mi * 16 + rq + r) * N + bn + wn;
            #pragma unroll
            for (int ni = 0; ni < 2; ni++) {
                float v = acc[mi][ni][r];
                size_t o = rowo + ni * 16 + fr;
                if (resid) v += resid[o];
                C[o] = v;
            }
        }
    }
}

// ---------------------------------------------------------------- RoPE + convert qkv fp32 -> split bf16 q,k,v
__global__ void rope_convert(const float* __restrict__ qkv, const float* __restrict__ fc,
                             __hip_bfloat16* __restrict__ qh, __hip_bfloat16* __restrict__ ql,
                             __hip_bfloat16* __restrict__ kh, __hip_bfloat16* __restrict__ kl,
                             __hip_bfloat16* __restrict__ vh, __hip_bfloat16* __restrict__ vl) {
    int t = blockIdx.x;
    int s = t & (SEQ - 1);
    const float* row = qkv + (size_t)t * QKVW;
    size_t ob = (size_t)t * HS;
    for (int p = threadIdx.x; p < 512; p += 256) {
        int hh = p >> 5, j = p & 31;
        int col = hh * 64 + 2 * j;
        float cr = fc[s * HDIM + 2 * j];
        float ci = fc[s * HDIM + 2 * j + 1];
        float a = row[col], b = row[col + 1];
        float r0 = a * cr - b * ci, r1 = a * ci + b * cr;
        __hip_bfloat16 h0 = __float2bfloat16(r0), h1 = __float2bfloat16(r1);
        qh[ob + col] = h0;     ql[ob + col]     = __float2bfloat16(r0 - __bfloat162float(h0));
        qh[ob + col + 1] = h1; ql[ob + col + 1] = __float2bfloat16(r1 - __bfloat162float(h1));
        a = row[1024 + col]; b = row[1024 + col + 1];
        r0 = a * cr - b * ci; r1 = a * ci + b * cr;
        h0 = __float2bfloat16(r0); h1 = __float2bfloat16(r1);
        kh[ob + col] = h0;     kl[ob + col]     = __float2bfloat16(r0 - __bfloat162float(h0));
        kh[ob + col + 1] = h1; kl[ob + col + 1] = __float2bfloat16(r1 - __bfloat162float(h1));
        r0 = row[2048 + col]; r1 = row[2048 + col + 1];
        h0 = __float2bfloat16(r0); h1 = __float2bfloat16(r1);
        vh[ob + col] = h0;     vl[ob + col]     = __float2bfloat16(r0 - __bfloat162float(h0));
        vh[ob + col + 1] = h1; vl[ob + col + 1] = __float2bfloat16(r1 - __bfloat162float(h1));
    }
}

// ---------------------------------------------------------------- split-K flash attention, MFMA split-bf16
__global__ __launch_bounds__(256) void attn_partial(
        const __hip_bfloat16* __restrict__ qh, const __hip_bfloat16* __restrict__ ql,
        const __hip_bfloat16* __restrict__ kh, const __hip_bfloat16* __restrict__ kl,
        const __hip_bfloat16* __restrict__ vh, const __hip_bfloat16* __restrict__ vl,
        float* __restrict__ po, float* __restrict__ pm_g, float* __restrict__ pl_g) {
    int c = blockIdx.x, qt = blockIdx.y;
    int nc = (qt + 4) >> 2;
    if (c >= nc) return;
    int bh = blockIdx.z;
    int b = bh >> 4, h = bh & 15;
    int t0 = c * 4, t1 = min(t0 + 4, qt + 1);
    int tid = threadIdx.x;
    int wave = tid >> 6, lane = tid & 63;
    int fr = lane & 15, quad = lane >> 4;
    int w16 = wave * 16;
    __shared__ __align__(16) short Qh[64][PAD], Ql[64][PAD];
    __shared__ __align__(16) short KPh[64][PAD], KPl[64][PAD];
    __shared__ __align__(16) short Vhs[64][PAD], Vls[64][PAD];
    size_t hoff = (size_t)h * HDIM;
    int sr = tid >> 2, sg = tid & 3;
    {
        const __hip_bfloat16* qp  = qh + (size_t)(b * SEQ + qt * 64 + sr) * HS + hoff;
        const __hip_bfloat16* qp2 = ql + (size_t)(b * SEQ + qt * 64 + sr) * HS + hoff;
        *(uint4*)&Qh[sr][sg * 8]       = *(const uint4*)(qp + sg * 8);
        *(uint4*)&Qh[sr][(sg + 4) * 8] = *(const uint4*)(qp + (sg + 4) * 8);
        *(uint4*)&Ql[sr][sg * 8]       = *(const uint4*)(qp2 + sg * 8);
        *(uint4*)&Ql[sr][(sg + 4) * 8] = *(const uint4*)(qp2 + (sg + 4) * 8);
    }
    f32x4 o[4] = {};
    float mrow[4], lrow[4];
    #pragma unroll
    for (int i = 0; i < 4; i++) { mrow[i] = -1e30f; lrow[i] = 0.f; }
    int key0 = (tid & 31) * 2, ds = tid >> 5;
    __syncthreads();

    for (int kt = t0; kt < t1; kt++) {
        int kbase = kt * 64;
        {
            const __hip_bfloat16* kp  = kh + (size_t)(b * SEQ + kbase + sr) * HS + hoff;
            const __hip_bfloat16* kp2 = kl + (size_t)(b * SEQ + kbase + sr) * HS + hoff;
            *(uint4*)&KPh[sr][sg * 8]       = *(const uint4*)(kp + sg * 8);
            *(uint4*)&KPh[sr][(sg + 4) * 8] = *(const uint4*)(kp + (sg + 4) * 8);
            *(uint4*)&KPl[sr][sg * 8]       = *(const uint4*)(kp2 + sg * 8);
            *(uint4*)&KPl[sr][(sg + 4) * 8] = *(const uint4*)(kp2 + (sg + 4) * 8);
        }
        {
            const __hip_bfloat16* v0 = vh + (size_t)(b * SEQ + kbase + key0) * HS + hoff + ds * 8;
            uint4 A = *(const uint4*)v0;
            uint4 Bv = *(const uint4*)(v0 + HS);
            const unsigned short* ap = (const unsigned short*)&A;
            const unsigned short* bp = (const unsigned short*)&Bv;
            #pragma unroll
            for (int j = 0; j < 8; j++)
                *(unsigned*)&Vhs[ds * 8 + j][key0] = (unsigned)ap[j] | ((unsigned)bp[j] << 16);
            const __hip_bfloat16* v2 = vl + (size_t)(b * SEQ + kbase + key0) * HS + hoff + ds * 8;
            uint4 A2 = *(const uint4*)v2;
            uint4 B2 = *(const uint4*)(v2 + HS);
            const unsigned short* ap2 = (const unsigned short*)&A2;
            const unsigned short* bp2 = (const unsigned short*)&B2;
            #pragma unroll
            for (int j = 0; j < 8; j++)
                *(unsigned*)&Vls[ds * 8 + j][key0] = (unsigned)ap2[j] | ((unsigned)bp2[j] << 16);
        }
        __syncthreads();

        f32x4 s[4] = {};
        #pragma unroll
        for (int ks = 0; ks < 2; ks++) {
            bf16x8 a_h = *(const bf16x8*)&Qh[w16 + fr][quad * 8 + ks * 32];
            bf16x8 a_l = *(const bf16x8*)&Ql[w16 + fr][quad * 8 + ks * 32];
            #pragma unroll
            for (int ni = 0; ni < 4; ni++) {
                bf16x8 b_h = *(const bf16x8*)&KPh[ni * 16 + fr][quad * 8 + ks * 32];
                bf16x8 b_l = *(const bf16x8*)&KPl[ni * 16 + fr][quad * 8 + ks * 32];
                s[ni] = __builtin_amdgcn_mfma_f32_16x16x32_bf16(a_h, b_h, s[ni], 0, 0, 0);
                s[ni] = __builtin_amdgcn_mfma_f32_16x16x32_bf16(a_h, b_l, s[ni], 0, 0, 0);
                s[ni] = __builtin_amdgcn_mfma_f32_16x16x32_bf16(a_l, b_h, s[ni], 0, 0, 0);
            }
        }
        int qg = qt * 64 + w16 + quad * 4;
        #pragma unroll
        for (int ni = 0; ni < 4; ni++) {
            int kg = kbase + ni * 16 + fr;
            #pragma unroll
            for (int r = 0; r < 4; r++)
                s[ni][r] = (kg > qg + r) ? -1e9f : s[ni][r] * 0.125f;
        }
        #pragma unroll
        for (int r = 0; r < 4; r++) {
            float mx = fmaxf(fmaxf(s[0][r], s[1][r]), fmaxf(s[2][r], s[3][r]));
            #pragma unroll
            for (int wd = 1; wd < 16; wd <<= 1) mx = fmaxf(mx, __shfl_xor(mx, wd));
            float nm = fmaxf(mrow[r], mx);
            float alpha = __expf(mrow[r] - nm);
            float rs = 0.f;
            #pragma unroll
            for (int ni = 0; ni < 4; ni++) { float e = __expf(s[ni][r] - nm); s[ni][r] = e; rs += e; }
            #pragma unroll
            for (int wd = 1; wd < 16; wd <<= 1) rs += __shfl_xor(rs, wd);
            lrow[r] = lrow[r] * alpha + rs;
            mrow[r] = nm;
            o[0][r] *= alpha; o[1][r] *= alpha; o[2][r] *= alpha; o[3][r] *= alpha;
        }
        __syncthreads();
        #pragma unroll
        for (int ni = 0; ni < 4; ni++)
            #pragma unroll
            for (int r = 0; r < 4; r++) {
                float pv = s[ni][r];
                __hip_bfloat16 hi = __float2bfloat16(pv);
                __hip_bfloat16 lo = __float2bfloat16(pv - __bfloat162float(hi));
                KPh[w16 + quad * 4 + r][ni * 16 + fr] = *(short*)&hi;
                KPl[w16 + quad * 4 + r][ni * 16 + fr] = *(short*)&lo;
            }
        #pragma unroll
        for (int ks = 0; ks < 2; ks++) {
            bf16x8 p_h = *(const bf16x8*)&KPh[w16 + fr][quad * 8 + ks * 32];
            bf16x8 p_l = *(const bf16x8*)&KPl[w16 + fr][quad * 8 + ks * 32];
            #pragma unroll
            for (int ni = 0; ni < 4; ni++) {
                bf16x8 v_h = *(const bf16x8*)&Vhs[ni * 16 + fr][quad * 8 + ks * 32];
                bf16x8 v_l = *(const bf16x8*)&Vls[ni * 16 + fr][quad * 8 + ks * 32];
                o[ni] = __builtin_amdgcn_mfma_f32_16x16x32_bf16(p_h, v_h, o[ni], 0, 0, 0);
                o[ni] = __builtin_amdgcn_mfma_f32_16x16x32_bf16(p_h, v_l, o[ni], 0, 0, 0);
                o[ni] = __builtin_amdgcn_mfma_f32_16x16x32_bf16(p_l, v_h, o[ni], 0, 0, 0);
            }
        }
        __syncthreads();
    }
    int pidx = (bh * 16 + qt) * 4 + c;
    float* pob = po + (size_t)pidx * 4096;
    #pragma unroll
    for (int ni = 0; ni < 4; ni++)
        #pragma unroll
        for (int r = 0; r < 4; r++)
            pob[(w16 + quad * 4 + r) * 64 + ni * 16 + fr] = o[ni][r];
    if (fr == 0) {
        #pragma unroll
        for (int r = 0; r < 4; r++) {
            pm_g[pidx * 64 + w16 + quad * 4 + r] = mrow[r];
            pl_g[pidx * 64 + w16 + quad * 4 + r] = lrow[r];
        }
    }
}

// ---------------------------------------------------------------- merge partials -> ctx as split bf16
__global__ void attn_merge(const float* __restrict__ po, const float* __restrict__ pm,
                           const float* __restrict__ pl,
                           __hip_bfloat16* __restrict__ ch, __hip_bfloat16* __restrict__ cl) {
    int qt = blockIdx.x, h = blockIdx.y, b = blockIdx.z;
    int bh = b * 16 + h;
    int nc = (qt + 4) >> 2;
    int base = (bh * 16 + qt) * 4;
    int tid = threadIdx.x;
    int r  = tid >> 2;
    int d0 = (tid & 3) * 16;
    float mstar = -1e30f;
    for (int c = 0; c < nc; c++) mstar = fmaxf(mstar, pm[(base + c) * 64 + r]);
    float a[4];
    float lsum = 0.f;
    for (int c = 0; c < nc; c++) {
        a[c] = __expf(pm[(base + c) * 64 + r] - mstar);
        lsum += a[c] * pl[(base + c) * 64 + r];
    }
    float inv = 1.f / lsum;
    size_t crow = (size_t)(b * SEQ + qt * 64 + r) * HS + h * HDIM;
    for (int dd = 0; dd < 16; dd += 4) {
        float4 acc = make_float4(0.f, 0.f, 0.f, 0.f);
        for (int c = 0; c < nc; c++) {
            float4 v = *(const float4*)(po + (size_t)(base + c) * 4096 + r * 64 + d0 + dd);
            acc.x += a[c] * v.x; acc.y += a[c] * v.y;
            acc.z += a[c] * v.z; acc.w += a[c] * v.w;
        }
        float vs[4] = {acc.x * inv, acc.y * inv, acc.z * inv, acc.w * inv};
        #pragma unroll
        for (int j = 0; j < 4; j++) {
            __hip_bfloat16 hi = __float2bfloat16(vs[j]);
            ch[crow + d0 + dd + j] = hi;
            cl[crow + d0 + dd + j] = __float2bfloat16(vs[j] - __bfloat162float(hi));
        }
    }
}

// ---------------------------------------------------------------- router (per-token top2)
__global__ void router_kernel(const float* __restrict__ hn, const float* __restrict__ rw,
                              int* __restrict__ cnt, int* __restrict__ topEk,
                              float* __restrict__ topW) {
    int t = blockIdx.x;
    int lane = threadIdx.x;
    float acc[NEXP];
    #pragma unroll
    for (int e = 0; e < NEXP; e++) acc[e] = 0.f;
    const float* row = hn + (size_t)t * HS;
    for (int kk = lane; kk < HS; kk += 64) {
        float xv = row[kk];
        const float* r = rw + (size_t)kk * NEXP;
        #pragma unroll
        for (int e = 0; e < NEXP; e++) acc[e] += xv * r[e];
    }
    #pragma unroll
    for (int e = 0; e < NEXP; e++)
        for (int off = 32; off > 0; off >>= 1) acc[e] += __shfl_down(acc[e], off);
    if (lane == 0) {
        float mx = acc[0];
        #pragma unroll
        for (int e = 1; e < NEXP; e++) mx = fmaxf(mx, acc[e]);
        float p[NEXP]; float s = 0.f;
        #pragma unroll
        for (int e = 0; e < NEXP; e++) { p[e] = __expf(acc[e] - mx); s += p[e]; }
        int i0 = 0;
        #pragma unroll
        for (int e = 1; e < NEXP; e++) if (p[e] > p[i0]) i0 = e;
        int i1 = (i0 == 0) ? 1 : 0;
        #pragma unroll
        for (int e = 0; e < NEXP; e++) if (e != i0 && p[e] > p[i1]) i1 = e;
        float v0 = p[i0], v1 = p[i1], sn = v0 + v1;
        topEk[2 * t]     = i0; topW[2 * t]     = v0 / sn;
        topEk[2 * t + 1] = i1; topW[2 * t + 1] = v1 / sn;
        atomicAdd(&cnt[i0], 1);
        atomicAdd(&cnt[i1], 1);
    }
}

// ---------------------------------------------------------------- offsets + block table
__global__ void offsets_kernel(const int* __restrict__ cnt, int* __restrict__ off,
                               int* __restrict__ blk_e, int* __restrict__ blk_r) {
    if (threadIdx.x == 0) {
        int o = 0, n = 0;
        for (int e = 0; e < NEXP; e++) {
            off[e] = o;
            for (int bm = 0; bm < cnt[e]; bm += 128) { blk_e[n] = e; blk_r[n] = bm; n++; }
            o += cnt[e];
        }
        for (; n < MAXBLK; n++) { blk_e[n] = -1; blk_r[n] = 0; }
    }
}

__global__ void scatter_kernel(const int* __restrict__ topEk, int* __restrict__ fill,
                               const int* __restrict__ off, const float* __restrict__ topW,
                               int* __restrict__ tok_list, float* __restrict__ wA) {
    int idx = blockIdx.x * 256 + threadIdx.x;
    int e = topEk[idx];
    int slot = atomicAdd(&fill[e], 1);
    int gidx = off[e] + slot;
    tok_list[gidx] = idx >> 1;
    wA[gidx] = topW[idx];
}

// ---------------------------------------------------------------- MoE up-proj, 128x64 tile, dbuf DMA
__global__ __launch_bounds__(256) void moe_up_mfma(const __hip_bfloat16* __restrict__ Abf,
                                                   const __hip_bfloat16* __restrict__ B1T,
                                                   const __hip_bfloat16* __restrict__ B3T,
                                                   __hip_bfloat16* __restrict__ g,
                                                   const int* __restrict__ cnt,
                                                   const int* __restrict__ off,
                                                   const int* __restrict__ tok_list,
                                                   const int* __restrict__ blk_e,
                                                   const int* __restrict__ blk_r) {
    int e = blk_e[blockIdx.y];
    if (e < 0) return;
    int bm = blk_r[blockIdx.y];
    int ce = cnt[e], oe = off[e];
    int bn = blockIdx.x * 64;
    const __hip_bfloat16* b1 = B1T + (size_t)e * IS * HS;   // [IS][HS]
    const __hip_bfloat16* b3 = B3T + (size_t)e * IS * HS;

    __shared__ __align__(16) short As[2][128][32];    // 16 KB
    __shared__ __align__(16) short B1s[2][64][32];    // 8 KB
    __shared__ __align__(16) short B3s[2][64][32];    // 8 KB -> 32 KB

    int t = threadIdx.x;
    int wave = t >> 6, lane = t & 63;
    int wm = (wave & 1) * 64, wn = (wave >> 1) * 32;
    int fr = lane & 15, quad = lane >> 4;
    int rA = wave * 32, rB = wave * 16;
    int srow = lane >> 2;
    int schunk = (lane & 3) ^ ((lane >> 3) & 3);
    int tokA0 = tok_list[oe + min(bm + rA + srow, ce - 1)];
    int tokA1 = tok_list[oe + min(bm + rA + 16 + srow, ce - 1)];
    const __hip_bfloat16* pA0 = Abf + (size_t)tokA0 * HS + schunk * 8;
    const __hip_bfloat16* pA1 = Abf + (size_t)tokA1 * HS + schunk * 8;
    const __hip_bfloat16* pB1 = b1 + (size_t)(bn + rB + srow) * HS + schunk * 8;
    const __hip_bfloat16* pB3 = b3 + (size_t)(bn + rB + srow) * HS + schunk * 8;
    int ca = (quad ^ ((fr >> 1) & 3)) * 8;

    ldsdma16(&As[0][rA][0],      pA0);
    ldsdma16(&As[0][rA + 16][0], pA1);
    ldsdma16(&B1s[0][rB][0],     pB1);
    ldsdma16(&B3s[0][rB][0],     pB3);

    f32x4 acc1[4][2] = {};
    f32x4 acc3[4][2] = {};
    const int NIT = HS >> 5;
    for (int it = 0; it < NIT; it++) {
        int cur = it & 1;
        __syncthreads();
        if (it + 1 < NIT) {
            int k1 = (it + 1) << 5;
            int nxt = cur ^ 1;
            ldsdma16(&As[nxt][rA][0],      pA0 + k1);
            ldsdma16(&As[nxt][rA + 16][0], pA1 + k1);
            ldsdma16(&B1s[nxt][rB][0],     pB1 + k1);
            ldsdma16(&B3s[nxt][rB][0],     pB3 + k1);
        }
        bf16x8 a[4], f1[2], f3[2];
        #pragma unroll
        for (int i = 0; i < 4; i++) a[i] = *(const bf16x8*)&As[cur][wm + i * 16 + fr][ca];
        #pragma unroll
        for (int i = 0; i < 2; i++) {
            f1[i] = *(const bf16x8*)&B1s[cur][wn + i * 16 + fr][ca];
            f3[i] = *(const bf16x8*)&B3s[cur][wn + i * 16 + fr][ca];
        }
        #pragma unroll
        for (int mi = 0; mi < 4; mi++)
            #pragma unroll
            for (int ni = 0; ni < 2; ni++) {
                acc1[mi][ni] = __builtin_amdgcn_mfma_f32_16x16x32_bf16(a[mi], f1[ni], acc1[mi][ni], 0, 0, 0);
                acc3[mi][ni] = __builtin_amdgcn_mfma_f32_16x16x32_bf16(a[mi], f3[ni], acc3[mi][ni], 0, 0, 0);
            }
    }
    int rq = quad * 4;
    #pragma unroll
    for (int mi = 0; mi < 4; mi++) {
        #pragma unroll
        for (int r = 0; r < 4; r++) {
            int slot = bm + wm + mi * 16 + rq + r;
            if (slot < ce) {
                size_t rowo = (size_t)(oe + slot) * IS + bn + wn;
                #pragma unroll
                for (int ni = 0; ni < 2; ni++) {
                    float x1 = acc1[mi][ni][r];
                    float x3 = acc3[mi][ni][r];
                    float sv = (x1 / (1.f + __expf(-x1))) * x3;
                    g[rowo + ni * 16 + fr] = __float2bfloat16(sv);
                }
            }
        }
    }
}

// ---------------------------------------------------------------- MoE down-proj, 128x64 tile, split-K=2, dbuf DMA
__global__ __launch_bounds__(256) void moe_down_mfma(const __hip_bfloat16* __restrict__ g,
                                                     const __hip_bfloat16* __restrict__ B2T,
                                                     float* __restrict__ out,
                                                     const int* __restrict__ cnt,
                                                     const int* __restrict__ off,
                                                     const int* __restrict__ tok_list,
                                                     const float* __restrict__ wA,
                                                     const int* __restrict__ blk_e,
                                                     const int* __restrict__ blk_r) {
    int e = blk_e[blockIdx.y];
    if (e < 0) return;
    int bm = blk_r[blockIdx.y];
    int ce = cnt[e], oe = off[e];
    int bn = blockIdx.x * 64;
    int kz = blockIdx.z * (IS / 2);           // split-K half
    const __hip_bfloat16* b2 = B2T + (size_t)e * HS * IS;   // [HS][IS]

    __shared__ __align__(16) short As[2][128][32];   // 16 KB
    __shared__ __align__(16) short Bs[2][64][32];    // 8 KB -> 24 KB

    int t = threadIdx.x;
    int wave = t >> 6, lane = t & 63;
    int wm = (wave & 1) * 64, wn = (wave >> 1) * 32;
    int fr = lane & 15, quad = lane >> 4;
    int rA = wave * 32, rB = wave * 16;
    int srow = lane >> 2;
    int schunk = (lane & 3) ^ ((lane >> 3) & 3);
    int ga0 = oe + min(bm + rA + srow, ce - 1);
    int ga1 = oe + min(bm + rA + 16 + srow, ce - 1);
    const __hip_bfloat16* pA0 = g + (size_t)ga0 * IS + kz + schunk * 8;
    const __hip_bfloat16* pA1 = g + (size_t)ga1 * IS + kz + schunk * 8;
    const __hip_bfloat16* pB  = b2 + (size_t)(bn + rB + srow) * IS + kz + schunk * 8;
    int ca = (quad ^ ((fr >> 1) & 3)) * 8;

    ldsdma16(&As[0][rA][0],      pA0);
    ldsdma16(&As[0][rA + 16][0], pA1);
    ldsdma16(&Bs[0][rB][0],      pB);

    f32x4 acc[4][2] = {};
    const int NIT = (IS / 2) >> 5;
    for (int it = 0; it < NIT; it++) {
        int cur = it & 1;
        __syncthreads();
        if (it + 1 < NIT) {
            int k1 = (it + 1) << 5;
            int nxt = cur ^ 1;
            ldsdma16(&As[nxt][rA][0],      pA0 + k1);
            ldsdma16(&As[nxt][rA + 16][0], pA1 + k1);
            ldsdma16(&Bs[nxt][rB][0],      pB + k1);
        }
        bf16x8 a[4], f[2];
        #pragma unroll
        for (int i = 0; i < 4; i++) a[i] = *(const bf16x8*)&As[cur][wm + i * 16 + fr][ca];
        #pragma unroll
        for (int i = 0; i < 2; i++) f[i] = *(const bf16x8*)&Bs[cur][wn + i * 16 + fr][ca];
        #pragma unroll
        for (int mi = 0; mi < 4; mi++)
            #pragma unroll
            for (int ni = 0; ni < 2; ni++)
                acc[mi][ni] = __builtin_amdgcn_mfma_f32_16x16x32_bf16(a[mi], f[ni], acc[mi][ni], 0, 0, 0);
    }
    int rq = quad * 4;
    #pragma unroll
    for (int mi = 0; mi < 4; mi++) {
        #pragma unroll
        for (int r = 0; r < 4; r++) {
            int slot = bm + wm + mi * 16 + rq + r;
            if (slot < ce) {
                int gidx = oe + slot;
                int tok = tok_list[gidx];
                float wgt = wA[gidx];
                size_t rowo = (size_t)tok * HS + bn + wn;
                #pragma unroll
                for (int ni = 0; ni < 2; ni++)
                    atomicAdd(out + rowo + ni * 16 + fr, wgt * acc[mi][ni][r]);
            }
        }
    }
}

// ---------------------------------------------------------------- launch
extern "C" void kernel_launch(void* const* d_in, const int* in_sizes, int n_in,
                              void* d_out, int out_size, void* d_ws, size_t ws_size,
                              hipStream_t stream) {
    const float* x   = (const float*)d_in[0];
    const float* anw = (const float*)d_in[1];
    const float* fnw = (const float*)d_in[2];
    const float* wq  = (const float*)d_in[3];
    const float* wk  = (const float*)d_in[4];
    const float* wv  = (const float*)d_in[5];
    const float* wo  = (const float*)d_in[6];
    const float* rw  = (const float*)d_in[7];
    const float* w1  = (const float*)d_in[8];
    const float* w3  = (const float*)d_in[9];
    const float* w2  = (const float*)d_in[10];
    const float* fc  = (const float*)d_in[11];
    float* out = (float*)d_out;

    char* ws = (char*)d_ws;
    const size_t MB = 1024 * 1024;
    __hip_bfloat16* xn_h  = (__hip_bfloat16*)(ws + 0 * MB);
    __hip_bfloat16* xn_l  = (__hip_bfloat16*)(ws + 4 * MB);
    float*          qkv   = (float*)(ws + 8 * MB);
    __hip_bfloat16* WqT_h = (__hip_bfloat16*)(ws + 32 * MB);
    __hip_bfloat16* WqT_l = (__hip_bfloat16*)(ws + 38 * MB);
    __hip_bfloat16* woT_h = (__hip_bfloat16*)(ws + 44 * MB);
    __hip_bfloat16* woT_l = (__hip_bfloat16*)(ws + 46 * MB);
    float*          po    = (float*)(ws + 48 * MB);
    float*          pm    = (float*)(ws + 82 * MB);
    float*          plb   = (float*)(ws + 83 * MB);
    __hip_bfloat16* ctx_h = (__hip_bfloat16*)(ws + 84 * MB);
    __hip_bfloat16* ctx_l = (__hip_bfloat16*)(ws + 88 * MB);
    __hip_bfloat16* qhb   = (__hip_bfloat16*)(ws + 92 * MB);
    __hip_bfloat16* qlb   = (__hip_bfloat16*)(ws + 96 * MB);
    __hip_bfloat16* khb   = (__hip_bfloat16*)(ws + 100 * MB);
    __hip_bfloat16* klb   = (__hip_bfloat16*)(ws + 104 * MB);
    __hip_bfloat16* vhb   = (__hip_bfloat16*)(ws + 108 * MB);
    __hip_bfloat16* vlb   = (__hip_bfloat16*)(ws + 112 * MB);
    float*          hn    = (float*)(ws + 0 * MB);
    __hip_bfloat16* hn_bf = (__hip_bfloat16*)(ws + 8 * MB);
    __hip_bfloat16* w1T   = (__hip_bfloat16*)(ws + 12 * MB);
    __hip_bfloat16* w3T   = (__hip_bfloat16*)(ws + 44 * MB);
    __hip_bfloat16* w2T   = (__hip_bfloat16*)(ws + 76 * MB);
    __hip_bfloat16* gact  = (__hip_bfloat16*)(ws + 108 * MB);
    int* ibase    = (int*)(ws + 124 * MB);
    int* cnt      = ibase;                 // 8
    int* fill     = ibase + 8;             // 8
    int* off      = ibase + 16;            // 8
    int* blk_e    = ibase + 24;            // 40
    int* blk_r    = ibase + 64;            // 40
    int* topEk    = ibase + 128;           // 4096
    int* tok_list = ibase + 128 + NASSIGN; // 4096
    float* topW   = (float*)(ibase + 128 + 2 * NASSIGN);
    float* wA     = (float*)(ibase + 128 + 3 * NASSIGN);

    // ---- attention half ----
    dim3 tg(HS / 32, HS / 32);
    transpose_split<<<tg, 256, 0, stream>>>(wq, WqT_h, WqT_l, HS, HS, 0);
    transpose_split<<<tg, 256, 0, stream>>>(wk, WqT_h, WqT_l, HS, HS, 1024);
    transpose_split<<<tg, 256, 0, stream>>>(wv, WqT_h, WqT_l, HS, HS, 2048);
    transpose_split<<<tg, 256, 0, stream>>>(wo, woT_h, woT_l, HS, HS, 0);
    rmsnorm_split<<<NTOK, 256, 0, stream>>>(x, anw, xn_h, xn_l);

    gemm_bf16x3<<<dim3(QKVW / 64, NTOK / 128), 256, 0, stream>>>(
        xn_h, xn_l, WqT_h, WqT_l, nullptr, qkv, NTOK, QKVW, HS);
    rope_convert<<<NTOK, 256, 0, stream>>>(qkv, fc, qhb, qlb, khb, klb, vhb, vlb);

    attn_partial<<<dim3(4, 16, 32), 256, 0, stream>>>(qhb, qlb, khb, klb, vhb, vlb, po, pm, plb);
    attn_merge<<<dim3(16, 16, 2), 256, 0, stream>>>(po, pm, plb, ctx_h, ctx_l);

    gemm_bf16x3<<<dim3(HS / 64, NTOK / 128), 256, 0, stream>>>(
        ctx_h, ctx_l, woT_h, woT_l, x, out, NTOK, HS, HS);   // out = h = x + ctx@wo

    // ---- MoE half (routed top-2, bf16 MFMA experts) ----
    rmsnorm_dual<<<NTOK, 256, 0, stream>>>(out, fnw, hn, hn_bf);
    transpose_bf16<<<dim3(IS / 32, HS / 32, NEXP), 256, 0, stream>>>(w1, w1T, HS, IS);
    transpose_bf16<<<dim3(IS / 32, HS / 32, NEXP), 256, 0, stream>>>(w3, w3T, HS, IS);
    transpose_bf16<<<dim3(HS / 32, IS / 32, NEXP), 256, 0, stream>>>(w2, w2T, IS, HS);

    hipMemsetAsync(cnt, 0, 16 * sizeof(int), stream);   // cnt + fill
    router_kernel<<<NTOK, 64, 0, stream>>>(hn, rw, cnt, topEk, topW);
    offsets_kernel<<<1, 64, 0, stream>>>(cnt, off, blk_e, blk_r);
    scatter_kernel<<<NASSIGN / 256, 256, 0, stream>>>(topEk, fill, off, topW, tok_list, wA);

    moe_up_mfma<<<dim3(IS / 64, MAXBLK), 256, 0, stream>>>(
        hn_bf, w1T, w3T, gact, cnt, off, tok_list, blk_e, blk_r);
    moe_down_mfma<<<dim3(HS / 64, MAXBLK, 2), 256, 0, stream>>>(
        gact, w2T, out, cnt, off, tok_list, wA, blk_e, blk_r);
}